// Round 1
// baseline (1602.189 us; speedup 1.0000x reference)
//
#include <hip/hip_runtime.h>
#include <math.h>

#define NP 4096      // N = M
#define NCP 512      // NC = MC
#define HD 256       // H and CF
#define CCD 1024     // CC
#define SPOTK 16
#define DOWNK 8
#define SEEDN 128

// ---------------------------------------------------------------------------
// Tiled f32 GEMM: C[M,N] = A[M,K] @ B[K,N] (+bias).  BT: B stored as [N,K]
// (i.e. C = A @ B^T).  128x128 tile, 256 threads, 8x8 microtile, BK=16.
// blockIdx.z selects (A0,B0,C0) vs (A1,B1,C1) for batching two GEMMs.
// ---------------------------------------------------------------------------
template<bool BT, bool BIAS>
__global__ __launch_bounds__(256) void gemm128(
    const float* __restrict__ A0, const float* __restrict__ A1,
    const float* __restrict__ B0, const float* __restrict__ B1,
    const float* __restrict__ bias, float* __restrict__ C0, float* __restrict__ C1,
    int M, int N, int K)
{
    const float* A = blockIdx.z ? A1 : A0;
    const float* B = blockIdx.z ? B1 : B0;
    float* C = blockIdx.z ? C1 : C0;

    __shared__ float As[16][128];
    __shared__ float Bs[16][128];

    const int bm = blockIdx.y * 128, bn = blockIdx.x * 128;
    const int t = threadIdx.x;
    const int tx = t & 15, ty = t >> 4;

    float acc[8][8];
#pragma unroll
    for (int i = 0; i < 8; i++)
#pragma unroll
        for (int j = 0; j < 8; j++) acc[i][j] = 0.f;

    for (int k0 = 0; k0 < K; k0 += 16) {
#pragma unroll
        for (int i = 0; i < 8; i++) {            // A tile: 128 rows x 16 k
            int idx = t + i * 256;
            int m = idx >> 4, k = idx & 15;
            As[k][m] = A[(size_t)(bm + m) * K + k0 + k];
        }
        if (BT) {
#pragma unroll
            for (int i = 0; i < 8; i++) {        // B tile from [N,K]
                int idx = t + i * 256;
                int n = idx >> 4, k = idx & 15;
                Bs[k][n] = B[(size_t)(bn + n) * K + k0 + k];
            }
        } else {
#pragma unroll
            for (int i = 0; i < 8; i++) {        // B tile from [K,N]
                int idx = t + i * 256;
                int k = idx >> 7, n = idx & 127;
                Bs[k][n] = B[(size_t)(k0 + k) * N + bn + n];
            }
        }
        __syncthreads();
#pragma unroll
        for (int kk = 0; kk < 16; kk++) {
            float a[8], b[8];
#pragma unroll
            for (int i = 0; i < 8; i++) a[i] = As[kk][ty * 8 + i];
#pragma unroll
            for (int j = 0; j < 8; j++) b[j] = Bs[kk][tx * 8 + j];
#pragma unroll
            for (int i = 0; i < 8; i++)
#pragma unroll
                for (int j = 0; j < 8; j++) acc[i][j] = fmaf(a[i], b[j], acc[i][j]);
        }
        __syncthreads();
    }
#pragma unroll
    for (int i = 0; i < 8; i++) {
        int m = bm + ty * 8 + i;
#pragma unroll
        for (int j = 0; j < 8; j++) {
            int n = bn + tx * 8 + j;
            float v = acc[i][j];
            if (BIAS) v += bias[n];
            C[(size_t)m * N + n] = v;
        }
    }
}

// ---------------------------------------------------------------------------
// Row softmax stats (two-pass, matching jax.nn.softmax)
// ---------------------------------------------------------------------------
__global__ __launch_bounds__(256) void row_stats(const float* __restrict__ s,
                                                 float* rmax, float* rsum)
{
    int n = blockIdx.x;
    const float* row = s + (size_t)n * NP;
    __shared__ float red[256];
    float m = -INFINITY;
    for (int j = threadIdx.x; j < NP; j += 256) m = fmaxf(m, row[j]);
    red[threadIdx.x] = m; __syncthreads();
    for (int off = 128; off; off >>= 1) {
        if (threadIdx.x < off) red[threadIdx.x] = fmaxf(red[threadIdx.x], red[threadIdx.x + off]);
        __syncthreads();
    }
    m = red[0]; __syncthreads();
    float sum = 0.f;
    for (int j = threadIdx.x; j < NP; j += 256) sum += expf(row[j] - m);
    red[threadIdx.x] = sum; __syncthreads();
    for (int off = 128; off; off >>= 1) {
        if (threadIdx.x < off) red[threadIdx.x] += red[threadIdx.x + off];
        __syncthreads();
    }
    if (threadIdx.x == 0) { rmax[n] = m; rsum[n] = red[0]; }
}

// Column softmax stats: partial over 128-row chunks (coalesced), then combine.
__global__ __launch_bounds__(256) void col_stats_partial(const float* __restrict__ s,
                                                         float* pmax, float* psum)
{
    int m = blockIdx.x * 256 + threadIdx.x;
    int n0 = blockIdx.y * 128;
    float mx = -INFINITY;
    for (int n = n0; n < n0 + 128; n++) mx = fmaxf(mx, s[(size_t)n * NP + m]);
    float sum = 0.f;
    for (int n = n0; n < n0 + 128; n++) sum += expf(s[(size_t)n * NP + m] - mx);
    pmax[(size_t)blockIdx.y * NP + m] = mx;
    psum[(size_t)blockIdx.y * NP + m] = sum;
}

__global__ __launch_bounds__(256) void col_stats_combine(const float* __restrict__ pmax,
                                                         const float* __restrict__ psum,
                                                         float* cmax, float* csum)
{
    int m = blockIdx.x * 256 + threadIdx.x;
    float mx = -INFINITY;
    for (int c = 0; c < 32; c++) mx = fmaxf(mx, pmax[(size_t)c * NP + m]);
    float sum = 0.f;
    for (int c = 0; c < 32; c++) sum += psum[(size_t)c * NP + m] * expf(pmax[(size_t)c * NP + m] - mx);
    cmax[m] = mx; csum[m] = sum;
}

// Final scores (in place) + per-row max/argmax (first-occurrence semantics)
__global__ __launch_bounds__(256) void finalize_rows(float* __restrict__ s,
    const float* __restrict__ rmax, const float* __restrict__ rsum,
    const float* __restrict__ cmax, const float* __restrict__ csum,
    float* __restrict__ confr, int* __restrict__ mir)
{
    int n = blockIdx.x;
    float rm = rmax[n], rs = rsum[n];
    size_t base = (size_t)n * NP;
    float best = -INFINITY; int bi = 0x7fffffff;
    for (int m1 = threadIdx.x; m1 < NP; m1 += 256) {
        float v = s[base + m1];
        float a = expf(v - rm) / rs;
        float b = expf(v - cmax[m1]) / csum[m1];
        float sc = a * b;
        s[base + m1] = sc;
        if (sc > best) { best = sc; bi = m1; }   // strict > keeps first occurrence
    }
    __shared__ float rv[256]; __shared__ int ri[256];
    rv[threadIdx.x] = best; ri[threadIdx.x] = bi; __syncthreads();
    for (int off = 128; off; off >>= 1) {
        if (threadIdx.x < off) {
            float v2 = rv[threadIdx.x + off]; int i2 = ri[threadIdx.x + off];
            if (v2 > rv[threadIdx.x] || (v2 == rv[threadIdx.x] && i2 < ri[threadIdx.x])) {
                rv[threadIdx.x] = v2; ri[threadIdx.x] = i2;
            }
        }
        __syncthreads();
    }
    if (threadIdx.x == 0) { confr[n] = rv[0]; mir[n] = ri[0]; }
}

// Column max/argmax over final scores (chunked)
__global__ __launch_bounds__(256) void col_argmax_partial(const float* __restrict__ s,
                                                          float* pconf, int* pmi)
{
    int m = blockIdx.x * 256 + threadIdx.x;
    int n0 = blockIdx.y * 128;
    float best = -INFINITY; int bi = 0;
    for (int n = n0; n < n0 + 128; n++) {
        float v = s[(size_t)n * NP + m];
        if (v > best) { best = v; bi = n; }
    }
    pconf[(size_t)blockIdx.y * NP + m] = best;
    pmi[(size_t)blockIdx.y * NP + m] = bi;
}

__global__ __launch_bounds__(256) void col_argmax_combine(const float* __restrict__ pconf,
                                                          const int* __restrict__ pmi,
                                                          float* confs, int* mis)
{
    int m = blockIdx.x * 256 + threadIdx.x;
    float best = -INFINITY; int bi = 0;
    for (int c = 0; c < 32; c++) {              // ascending chunks -> first max wins
        float v = pconf[(size_t)c * NP + m];
        if (v > best) { best = v; bi = pmi[(size_t)c * NP + m]; }
    }
    confs[m] = best; mis[m] = bi;
}

// Gather matched points + squared norm: q[j] = (x,y,z,|p|^2) of pts[mi[j]]
__global__ void gather_pts(const float* __restrict__ pts, const int* __restrict__ mi,
                           float4* __restrict__ q)
{
    int j = blockIdx.x * 256 + threadIdx.x;
    if (j >= NP) return;
    int idx = mi[j];
    float x = pts[idx * 3], y = pts[idx * 3 + 1], z = pts[idx * 3 + 2];
    q[j] = make_float4(x, y, z, x * x + y * y + z * z);
}

// compat[n] = mean_j relu(1 - |d(base_n, base_j) - d(q_n, q_j)| / 3)
__global__ __launch_bounds__(256) void compat_kernel(const float* __restrict__ base_pts,
    const float4* __restrict__ q, float* __restrict__ out1, float* __restrict__ out2)
{
    int n = blockIdx.x;
    float bx = base_pts[n * 3], by = base_pts[n * 3 + 1], bz = base_pts[n * 3 + 2];
    float bxx = bx * bx + by * by + bz * bz;
    float4 a = q[n];
    float sum = 0.f;
    for (int j = threadIdx.x; j < NP; j += 256) {
        float px = base_pts[j * 3], py = base_pts[j * 3 + 1], pz = base_pts[j * 3 + 2];
        float rd = (bxx - 2.f * (bx * px + by * py + bz * pz)) + (px * px + py * py + pz * pz);
        float4 qj = q[j];
        float sd = (a.w - 2.f * (a.x * qj.x + a.y * qj.y + a.z * qj.z)) + qj.w;
        float c = 1.f - fabsf(rd - sd) / 3.0f;
        sum += fmaxf(c, 0.f);
    }
    __shared__ float red[256];
    red[threadIdx.x] = sum; __syncthreads();
    for (int off = 128; off; off >>= 1) {
        if (threadIdx.x < off) red[threadIdx.x] += red[threadIdx.x + off];
        __syncthreads();
    }
    if (threadIdx.x == 0) { float c = red[0] * (1.0f / NP); out1[n] = c; out2[n] = c; }
}

// Iterative top-SEEDN of (compat < max(compat)*0.5 ? conf*compat : 0),
// jax.lax.top_k tie semantics (equal values -> lower index first).
__global__ __launch_bounds__(256) void seed_kernel(const float* __restrict__ compat,
    const float* __restrict__ conf, float* __restrict__ outp)
{
    __shared__ float w[NP];
    __shared__ float rv[256]; __shared__ int ri[256];
    int tid = threadIdx.x;
    float mx = -INFINITY;
    for (int j = tid; j < NP; j += 256) mx = fmaxf(mx, compat[j]);
    rv[tid] = mx; __syncthreads();
    for (int off = 128; off; off >>= 1) {
        if (tid < off) rv[tid] = fmaxf(rv[tid], rv[tid + off]);
        __syncthreads();
    }
    float thr = rv[0] * 0.5f; __syncthreads();
    for (int j = tid; j < NP; j += 256) {
        float c = compat[j];
        w[j] = (c < thr) ? conf[j] * c : 0.0f;   // non-selected stay 0 (pickable as zero-fill)
    }
    __syncthreads();
    for (int s = 0; s < SEEDN; s++) {
        float best = -INFINITY; int bi = 0x7fffffff;
        for (int j = tid; j < NP; j += 256) {
            float v = w[j];
            if (v > best || (v == best && j < bi)) { best = v; bi = j; }
        }
        rv[tid] = best; ri[tid] = bi; __syncthreads();
        for (int off = 128; off; off >>= 1) {
            if (tid < off) {
                float v2 = rv[tid + off]; int i2 = ri[tid + off];
                if (v2 > rv[tid] || (v2 == rv[tid] && i2 < ri[tid])) { rv[tid] = v2; ri[tid] = i2; }
            }
            __syncthreads();
        }
        if (tid == 0) { outp[s] = (float)ri[0]; w[ri[0]] = -2.0f; }
        __syncthreads();
    }
}

// KNN: per row of row_pts, top-KSEL smallest distances to col_pts (index tiebreak).
template<int KSEL>
__global__ __launch_bounds__(256) void knn_select(const float* __restrict__ row_pts,
    const float* __restrict__ col_pts, int ncols, int* out_i, float* out_f)
{
    int r = blockIdx.x;
    __shared__ float dist[NP];
    float px = row_pts[r * 3], py = row_pts[r * 3 + 1], pz = row_pts[r * 3 + 2];
    float pxx = px * px + py * py + pz * pz;
    for (int j = threadIdx.x; j < ncols; j += 256) {
        float cx = col_pts[j * 3], cy = col_pts[j * 3 + 1], cz = col_pts[j * 3 + 2];
        dist[j] = (pxx - 2.f * (px * cx + py * cy + pz * cz)) + (cx * cx + cy * cy + cz * cz);
    }
    __syncthreads();
    __shared__ float rv[256]; __shared__ int ri[256];
    int tid = threadIdx.x;
    for (int s = 0; s < KSEL; s++) {
        float best = INFINITY; int bi = 0x7fffffff;
        for (int j = tid; j < ncols; j += 256) {
            float d = dist[j];
            if (d < best || (d == best && j < bi)) { best = d; bi = j; }
        }
        rv[tid] = best; ri[tid] = bi; __syncthreads();
        for (int off = 128; off; off >>= 1) {
            if (tid < off) {
                float v2 = rv[tid + off]; int i2 = ri[tid + off];
                if (v2 < rv[tid] || (v2 == rv[tid] && i2 < ri[tid])) { rv[tid] = v2; ri[tid] = i2; }
            }
            __syncthreads();
        }
        if (tid == 0) {
            int wsel = ri[0];
            if (out_i) out_i[(size_t)r * KSEL + s] = wsel;
            else       out_f[(size_t)r * KSEL + s] = (float)wsel;
            dist[wsel] = INFINITY;
        }
        __syncthreads();
    }
}

// argmin over the 512 coarse points per fine point (first-min index)
__global__ __launch_bounds__(256) void up_argmin(const float* __restrict__ pts,
    const float* __restrict__ pts_c, float* __restrict__ out_f)
{
    __shared__ float4 cp[NCP];
    for (int c = threadIdx.x; c < NCP; c += 256) {
        float x = pts_c[c * 3], y = pts_c[c * 3 + 1], z = pts_c[c * 3 + 2];
        cp[c] = make_float4(x, y, z, x * x + y * y + z * z);
    }
    __syncthreads();
    int n = blockIdx.x * 256 + threadIdx.x;
    float px = pts[n * 3], py = pts[n * 3 + 1], pz = pts[n * 3 + 2];
    float pxx = px * px + py * py + pz * pz;
    float best = INFINITY; int bi = 0;
    for (int c = 0; c < NCP; c++) {
        float4 q = cp[c];
        float d = (pxx - 2.f * (px * q.x + py * q.y + pz * q.z)) + q.w;
        if (d < best) { best = d; bi = c; }
    }
    out_f[n] = (float)bi;
}

// spot[n,k] = idx16[mi[n]][k]
__global__ void spot_gather(const int* __restrict__ idx16, const int* __restrict__ mi,
                            float* __restrict__ outp)
{
    int t = blockIdx.x * 256 + threadIdx.x;     // 65536
    int n = t >> 4, k = t & 15;
    outp[t] = (float)idx16[(size_t)mi[n] * SPOTK + k];
}

// ---------------------------------------------------------------------------
extern "C" void kernel_launch(void* const* d_in, const int* in_sizes, int n_in,
                              void* d_out, int out_size, void* d_ws, size_t ws_size,
                              hipStream_t stream)
{
    const float* ref_points   = (const float*)d_in[0];
    const float* src_points   = (const float*)d_in[1];
    const float* ref_feats    = (const float*)d_in[2];
    const float* src_feats    = (const float*)d_in[3];
    const float* ref_points_c = (const float*)d_in[4];
    const float* src_points_c = (const float*)d_in[5];
    const float* ref_feats_c  = (const float*)d_in[6];
    const float* src_feats_c  = (const float*)d_in[7];
    const float* W1 = (const float*)d_in[8];
    const float* b1 = (const float*)d_in[9];
    const float* W2 = (const float*)d_in[10];
    const float* b2 = (const float*)d_in[11];

    // ---- d_out layout (all float32; indices written as float) ----
    float* out = (float*)d_out;
    float* o_scores = out;                       // 4096*4096
    float* o_compr  = o_scores + (size_t)NP * NP;
    float* o_comps  = o_compr + NP;
    float* o_seedr  = o_comps + NP;
    float* o_seeds  = o_seedr + SEEDN;
    float* o_spotr  = o_seeds + SEEDN;           // 4096*16
    float* o_spots  = o_spotr + (size_t)NP * SPOTK;
    float* o_hcr    = o_spots + (size_t)NP * SPOTK;   // 512*256
    float* o_hcs    = o_hcr + (size_t)NCP * HD;
    float* o_rup    = o_hcs + (size_t)NCP * HD;  // 4096
    float* o_sup    = o_rup + NP;
    float* o_rdown  = o_sup + NP;                // 512*8
    float* o_sdown  = o_rdown + (size_t)NCP * DOWNK;

    // ---- workspace layout ----
    float* ws = (float*)d_ws;
    float* hfr   = ws;                           // 4096*256
    float* hfs   = hfr + (size_t)NP * HD;
    float* rmax  = hfs + (size_t)NP * HD;        // 4096 each
    float* rsum  = rmax + NP;
    float* cmax  = rsum + NP;
    float* csum  = cmax + NP;
    float* confr = csum + NP;
    float* confs = confr + NP;
    float* compr = confs + NP;
    float* comps = compr + NP;
    int*   mir   = (int*)(comps + NP);
    int*   mis   = mir + NP;
    float* pmax  = (float*)(mis + NP);           // 32*4096 each
    float* psum  = pmax + 32 * NP;
    float* pconf = psum + 32 * NP;
    int*   pmi   = (int*)(pconf + 32 * NP);
    float4* qr   = (float4*)(pmi + 32 * NP);     // 4096 float4 each
    float4* qs   = qr + NP;
    int* ridx16  = (int*)(qs + NP);              // 4096*16 each
    int* sidx16  = ridx16 + (size_t)NP * SPOTK;
    size_t ws_need = (size_t)((float*)(sidx16 + (size_t)NP * SPOTK) - ws) * 4;
    if (ws_size < ws_need) return;               // insufficient scratch -> fail loudly

    dim3 b256(256);

    // projections
    gemm128<false, true><<<dim3(2, 32, 2), b256, 0, stream>>>(
        ref_feats, src_feats, W2, W2, b2, hfr, hfs, NP, HD, HD);
    gemm128<false, true><<<dim3(2, 4, 2), b256, 0, stream>>>(
        ref_feats_c, src_feats_c, W1, W1, b1, o_hcr, o_hcs, NCP, HD, CCD);

    // raw scores s = hfr @ hfs^T  (into d_out scores region, finalized in place)
    gemm128<true, false><<<dim3(32, 32, 1), b256, 0, stream>>>(
        hfr, nullptr, hfs, nullptr, nullptr, o_scores, nullptr, NP, NP, HD);

    // KNN family (independent of scores)
    knn_select<SPOTK><<<NP, b256, 0, stream>>>(ref_points, ref_points, NP, ridx16, nullptr);
    knn_select<SPOTK><<<NP, b256, 0, stream>>>(src_points, src_points, NP, sidx16, nullptr);
    knn_select<DOWNK><<<NCP, b256, 0, stream>>>(ref_points_c, ref_points, NP, nullptr, o_rdown);
    knn_select<DOWNK><<<NCP, b256, 0, stream>>>(src_points_c, src_points, NP, nullptr, o_sdown);
    up_argmin<<<NP / 256, b256, 0, stream>>>(ref_points, ref_points_c, o_rup);
    up_argmin<<<NP / 256, b256, 0, stream>>>(src_points, src_points_c, o_sup);

    // dual softmax
    row_stats<<<NP, b256, 0, stream>>>(o_scores, rmax, rsum);
    col_stats_partial<<<dim3(16, 32), b256, 0, stream>>>(o_scores, pmax, psum);
    col_stats_combine<<<16, b256, 0, stream>>>(pmax, psum, cmax, csum);
    finalize_rows<<<NP, b256, 0, stream>>>(o_scores, rmax, rsum, cmax, csum, confr, mir);
    col_argmax_partial<<<dim3(16, 32), b256, 0, stream>>>(o_scores, pconf, pmi);
    col_argmax_combine<<<16, b256, 0, stream>>>(pconf, pmi, confs, mis);

    // compatibility (recompute distances from points; gather matched points once)
    gather_pts<<<NP / 256, b256, 0, stream>>>(src_points, mir, qr);
    gather_pts<<<NP / 256, b256, 0, stream>>>(ref_points, mis, qs);
    compat_kernel<<<NP, b256, 0, stream>>>(ref_points, qr, o_compr, compr);
    compat_kernel<<<NP, b256, 0, stream>>>(src_points, qs, o_comps, comps);

    // seeding
    seed_kernel<<<1, b256, 0, stream>>>(compr, confr, o_seedr);
    seed_kernel<<<1, b256, 0, stream>>>(comps, confs, o_seeds);

    // spot gathers
    spot_gather<<<(NP * SPOTK) / 256, b256, 0, stream>>>(sidx16, mir, o_spotr);
    spot_gather<<<(NP * SPOTK) / 256, b256, 0, stream>>>(ridx16, mis, o_spots);
}

// Round 2
// 1445.506 us; speedup vs baseline: 1.1084x; 1.1084x over previous
//
#include <hip/hip_runtime.h>
#include <math.h>

#define NP 4096      // N = M
#define NCP 512      // NC = MC
#define HD 256       // H and CF
#define CCD 1024     // CC
#define SPOTK 16
#define DOWNK 8
#define SEEDN 128

// ---------------------------------------------------------------------------
// Tiled f32 GEMM: C[M,N] = A[M,K] @ B[K,N] (+bias).  BT: B stored as [N,K]
// (i.e. C = A @ B^T).  128x128 tile, 256 threads, 8x8 microtile, BK=16.
// blockIdx.z selects (A0,B0,C0) vs (A1,B1,C1) for batching two GEMMs.
// ---------------------------------------------------------------------------
template<bool BT, bool BIAS>
__global__ __launch_bounds__(256) void gemm128(
    const float* __restrict__ A0, const float* __restrict__ A1,
    const float* __restrict__ B0, const float* __restrict__ B1,
    const float* __restrict__ bias, float* __restrict__ C0, float* __restrict__ C1,
    int M, int N, int K)
{
    const float* A = blockIdx.z ? A1 : A0;
    const float* B = blockIdx.z ? B1 : B0;
    float* C = blockIdx.z ? C1 : C0;

    __shared__ float As[16][128];
    __shared__ float Bs[16][128];

    const int bm = blockIdx.y * 128, bn = blockIdx.x * 128;
    const int t = threadIdx.x;
    const int tx = t & 15, ty = t >> 4;

    float acc[8][8];
#pragma unroll
    for (int i = 0; i < 8; i++)
#pragma unroll
        for (int j = 0; j < 8; j++) acc[i][j] = 0.f;

    for (int k0 = 0; k0 < K; k0 += 16) {
#pragma unroll
        for (int i = 0; i < 8; i++) {            // A tile: 128 rows x 16 k
            int idx = t + i * 256;
            int m = idx >> 4, k = idx & 15;
            As[k][m] = A[(size_t)(bm + m) * K + k0 + k];
        }
        if (BT) {
#pragma unroll
            for (int i = 0; i < 8; i++) {        // B tile from [N,K]
                int idx = t + i * 256;
                int n = idx >> 4, k = idx & 15;
                Bs[k][n] = B[(size_t)(bn + n) * K + k0 + k];
            }
        } else {
#pragma unroll
            for (int i = 0; i < 8; i++) {        // B tile from [K,N]
                int idx = t + i * 256;
                int k = idx >> 7, n = idx & 127;
                Bs[k][n] = B[(size_t)(k0 + k) * N + bn + n];
            }
        }
        __syncthreads();
#pragma unroll
        for (int kk = 0; kk < 16; kk++) {
            float a[8], b[8];
#pragma unroll
            for (int i = 0; i < 8; i++) a[i] = As[kk][ty * 8 + i];
#pragma unroll
            for (int j = 0; j < 8; j++) b[j] = Bs[kk][tx * 8 + j];
#pragma unroll
            for (int i = 0; i < 8; i++)
#pragma unroll
                for (int j = 0; j < 8; j++) acc[i][j] = fmaf(a[i], b[j], acc[i][j]);
        }
        __syncthreads();
    }
#pragma unroll
    for (int i = 0; i < 8; i++) {
        int m = bm + ty * 8 + i;
#pragma unroll
        for (int j = 0; j < 8; j++) {
            int n = bn + tx * 8 + j;
            float v = acc[i][j];
            if (BIAS) v += bias[n];
            C[(size_t)m * N + n] = v;
        }
    }
}

// ---------------------------------------------------------------------------
// Row softmax stats (two-pass, matching jax.nn.softmax)
// ---------------------------------------------------------------------------
__global__ __launch_bounds__(256) void row_stats(const float* __restrict__ s,
                                                 float* rmax, float* rsum)
{
    int n = blockIdx.x;
    const float* row = s + (size_t)n * NP;
    __shared__ float red[256];
    float m = -INFINITY;
    for (int j = threadIdx.x; j < NP; j += 256) m = fmaxf(m, row[j]);
    red[threadIdx.x] = m; __syncthreads();
    for (int off = 128; off; off >>= 1) {
        if (threadIdx.x < off) red[threadIdx.x] = fmaxf(red[threadIdx.x], red[threadIdx.x + off]);
        __syncthreads();
    }
    m = red[0]; __syncthreads();
    float sum = 0.f;
    for (int j = threadIdx.x; j < NP; j += 256) sum += expf(row[j] - m);
    red[threadIdx.x] = sum; __syncthreads();
    for (int off = 128; off; off >>= 1) {
        if (threadIdx.x < off) red[threadIdx.x] += red[threadIdx.x + off];
        __syncthreads();
    }
    if (threadIdx.x == 0) { rmax[n] = m; rsum[n] = red[0]; }
}

// Column softmax stats: partial over 128-row chunks (coalesced), then combine.
__global__ __launch_bounds__(256) void col_stats_partial(const float* __restrict__ s,
                                                         float* pmax, float* psum)
{
    int m = blockIdx.x * 256 + threadIdx.x;
    int n0 = blockIdx.y * 128;
    float mx = -INFINITY;
    for (int n = n0; n < n0 + 128; n++) mx = fmaxf(mx, s[(size_t)n * NP + m]);
    float sum = 0.f;
    for (int n = n0; n < n0 + 128; n++) sum += expf(s[(size_t)n * NP + m] - mx);
    pmax[(size_t)blockIdx.y * NP + m] = mx;
    psum[(size_t)blockIdx.y * NP + m] = sum;
}

__global__ __launch_bounds__(256) void col_stats_combine(const float* __restrict__ pmax,
                                                         const float* __restrict__ psum,
                                                         float* cmax, float* csum)
{
    int m = blockIdx.x * 256 + threadIdx.x;
    float mx = -INFINITY;
    for (int c = 0; c < 32; c++) mx = fmaxf(mx, pmax[(size_t)c * NP + m]);
    float sum = 0.f;
    for (int c = 0; c < 32; c++) sum += psum[(size_t)c * NP + m] * expf(pmax[(size_t)c * NP + m] - mx);
    cmax[m] = mx; csum[m] = sum;
}

// Final scores (in place) + per-row max/argmax (first-occurrence semantics)
__global__ __launch_bounds__(256) void finalize_rows(float* __restrict__ s,
    const float* __restrict__ rmax, const float* __restrict__ rsum,
    const float* __restrict__ cmax, const float* __restrict__ csum,
    float* __restrict__ confr, int* __restrict__ mir)
{
    int n = blockIdx.x;
    float rm = rmax[n], rs = rsum[n];
    size_t base = (size_t)n * NP;
    float best = -INFINITY; int bi = 0x7fffffff;
    for (int m1 = threadIdx.x; m1 < NP; m1 += 256) {
        float v = s[base + m1];
        float a = expf(v - rm) / rs;
        float b = expf(v - cmax[m1]) / csum[m1];
        float sc = a * b;
        s[base + m1] = sc;
        if (sc > best) { best = sc; bi = m1; }   // strict > keeps first occurrence
    }
    __shared__ float rv[256]; __shared__ int ri[256];
    rv[threadIdx.x] = best; ri[threadIdx.x] = bi; __syncthreads();
    for (int off = 128; off; off >>= 1) {
        if (threadIdx.x < off) {
            float v2 = rv[threadIdx.x + off]; int i2 = ri[threadIdx.x + off];
            if (v2 > rv[threadIdx.x] || (v2 == rv[threadIdx.x] && i2 < ri[threadIdx.x])) {
                rv[threadIdx.x] = v2; ri[threadIdx.x] = i2;
            }
        }
        __syncthreads();
    }
    if (threadIdx.x == 0) { confr[n] = rv[0]; mir[n] = ri[0]; }
}

// Column max/argmax over final scores (chunked)
__global__ __launch_bounds__(256) void col_argmax_partial(const float* __restrict__ s,
                                                          float* pconf, int* pmi)
{
    int m = blockIdx.x * 256 + threadIdx.x;
    int n0 = blockIdx.y * 128;
    float best = -INFINITY; int bi = 0;
    for (int n = n0; n < n0 + 128; n++) {
        float v = s[(size_t)n * NP + m];
        if (v > best) { best = v; bi = n; }
    }
    pconf[(size_t)blockIdx.y * NP + m] = best;
    pmi[(size_t)blockIdx.y * NP + m] = bi;
}

__global__ __launch_bounds__(256) void col_argmax_combine(const float* __restrict__ pconf,
                                                          const int* __restrict__ pmi,
                                                          float* confs, int* mis)
{
    int m = blockIdx.x * 256 + threadIdx.x;
    float best = -INFINITY; int bi = 0;
    for (int c = 0; c < 32; c++) {              // ascending chunks -> first max wins
        float v = pconf[(size_t)c * NP + m];
        if (v > best) { best = v; bi = pmi[(size_t)c * NP + m]; }
    }
    confs[m] = best; mis[m] = bi;
}

// Gather matched points + squared norm: q[j] = (x,y,z,|p|^2) of pts[mi[j]]
// z-batched: z=0 (srcA pts, miA)->qA ; z=1 (srcB pts, miB)->qB
__global__ void gather_pts(const float* __restrict__ ptsA, const float* __restrict__ ptsB,
                           const int* __restrict__ miA, const int* __restrict__ miB,
                           float4* __restrict__ qA, float4* __restrict__ qB)
{
    const float* pts = blockIdx.z ? ptsB : ptsA;
    const int*   mi  = blockIdx.z ? miB : miA;
    float4*      q   = blockIdx.z ? qB : qA;
    int j = blockIdx.x * 256 + threadIdx.x;
    if (j >= NP) return;
    int idx = mi[j];
    float x = pts[idx * 3], y = pts[idx * 3 + 1], z = pts[idx * 3 + 2];
    q[j] = make_float4(x, y, z, x * x + y * y + z * z);
}

// compat[n] = mean_j relu(1 - |d(base_n, base_j) - d(q_n, q_j)| / 3)   (z-batched)
__global__ __launch_bounds__(256) void compat_kernel(
    const float* __restrict__ baseA, const float* __restrict__ baseB,
    const float4* __restrict__ qA, const float4* __restrict__ qB,
    float* __restrict__ o1A, float* __restrict__ o1B,
    float* __restrict__ o2A, float* __restrict__ o2B)
{
    const float* base_pts = blockIdx.z ? baseB : baseA;
    const float4* q       = blockIdx.z ? qB : qA;
    float* out1           = blockIdx.z ? o1B : o1A;
    float* out2           = blockIdx.z ? o2B : o2A;
    int n = blockIdx.x;
    float bx = base_pts[n * 3], by = base_pts[n * 3 + 1], bz = base_pts[n * 3 + 2];
    float bxx = bx * bx + by * by + bz * bz;
    float4 a = q[n];
    float sum = 0.f;
    for (int j = threadIdx.x; j < NP; j += 256) {
        float px = base_pts[j * 3], py = base_pts[j * 3 + 1], pz = base_pts[j * 3 + 2];
        float rd = (bxx - 2.f * (bx * px + by * py + bz * pz)) + (px * px + py * py + pz * pz);
        float4 qj = q[j];
        float sd = (a.w - 2.f * (a.x * qj.x + a.y * qj.y + a.z * qj.z)) + qj.w;
        float c = 1.f - fabsf(rd - sd) / 3.0f;
        sum += fmaxf(c, 0.f);
    }
    __shared__ float red[256];
    red[threadIdx.x] = sum; __syncthreads();
    for (int off = 128; off; off >>= 1) {
        if (threadIdx.x < off) red[threadIdx.x] += red[threadIdx.x + off];
        __syncthreads();
    }
    if (threadIdx.x == 0) { float c = red[0] * (1.0f / NP); out1[n] = c; out2[n] = c; }
}

// ---------------------------------------------------------------------------
// Seeding: top-SEEDN of (compat < max(compat)*0.5 ? conf*compat : 0).
// ONE WAVE (64 lanes), wave-synchronous, zero barriers. Lane l owns the
// interleaved chunk {j : j % 64 == l}; per-round lex-argmax via shfl_xor
// butterfly; only the winning lane rescans its 64-element chunk.
// jax.lax.top_k tie semantics: (value desc, index asc).
// z-batched: z=0 ref, z=1 src.
// ---------------------------------------------------------------------------
__global__ __launch_bounds__(64) void seed_kernel(
    const float* __restrict__ compatA, const float* __restrict__ compatB,
    const float* __restrict__ confA, const float* __restrict__ confB,
    float* __restrict__ outA, float* __restrict__ outB)
{
    const float* compat = blockIdx.z ? compatB : compatA;
    const float* conf   = blockIdx.z ? confB : confA;
    float* outp         = blockIdx.z ? outB : outA;

    __shared__ float w[NP];
    int lane = threadIdx.x;

    // max(compat)
    float mx = -INFINITY;
    for (int t = 0; t < NP / 64; t++) mx = fmaxf(mx, compat[lane + t * 64]);
#pragma unroll
    for (int off = 32; off; off >>= 1) mx = fmaxf(mx, __shfl_xor(mx, off));
    float thr = mx * 0.5f;

    // weights (lane fills its own chunk; no cross-lane LDS anywhere)
    for (int t = 0; t < NP / 64; t++) {
        int j = lane + t * 64;
        float c = compat[j];
        w[j] = (c < thr) ? conf[j] * c : 0.0f;
    }

    // per-lane running best over own chunk
    float bv = w[lane]; int bi = lane;
    for (int t = 1; t < NP / 64; t++) {
        int j = lane + t * 64;
        float v = w[j];
        if (v > bv) { bv = v; bi = j; }          // ascending j -> strict > keeps first
    }

    for (int s = 0; s < SEEDN; s++) {
        float gv = bv; int gi = bi;
#pragma unroll
        for (int off = 32; off; off >>= 1) {
            float ov = __shfl_xor(gv, off); int oi = __shfl_xor(gi, off);
            if (ov > gv || (ov == gv && oi < gi)) { gv = ov; gi = oi; }
        }
        if (lane == 0) outp[s] = (float)gi;
        if (bi == gi) {                          // unique winner (indices unique)
            w[gi] = -1.0f;                       // below any valid weight (>= 0)
            bv = -1.0f; bi = 0x7fffffff;
            for (int t = 0; t < NP / 64; t++) {
                int j = lane + t * 64;
                float v = w[j];
                if (v > bv || (v == bv && j < bi)) { bv = v; bi = j; }
            }
        }
    }
}

// ---------------------------------------------------------------------------
// KNN top-K: one wave per row, 4 rows/block. Per-lane register top-K (sorted
// bubble insert, compile-time indices) over its 64-strided candidates, then
// barrier-free 64-way merge via LDS heads + shfl_xor lex-min butterfly.
// Exact jax.lax.top_k tie semantics: (dist asc, index asc).
// z-batched: z=0 (rowA,colA)->outA ; z=1 (rowB,colB)->outB.
// ---------------------------------------------------------------------------
template<int KSEL>
__global__ __launch_bounds__(256) void knn_topk(
    const float* __restrict__ rowA, const float* __restrict__ rowB,
    const float* __restrict__ colA, const float* __restrict__ colB,
    int nrows, int ncols,
    int* __restrict__ outiA, int* __restrict__ outiB,
    float* __restrict__ outfA, float* __restrict__ outfB)
{
    const float* rowp = blockIdx.z ? rowB : rowA;
    const float* colp = blockIdx.z ? colB : colA;
    int* outi = blockIdx.z ? outiB : outiA;
    float* outf = blockIdx.z ? outfB : outfA;

    int wid = threadIdx.x >> 6, lane = threadIdx.x & 63;
    int r = blockIdx.x * 4 + wid;

    float px = rowp[r * 3], py = rowp[r * 3 + 1], pz = rowp[r * 3 + 2];
    float pxx = px * px + py * py + pz * pz;

    float v[KSEL]; int ix[KSEL];
#pragma unroll
    for (int k = 0; k < KSEL; k++) { v[k] = INFINITY; ix[k] = 0x7fffffff; }

    for (int j0 = 0; j0 < ncols; j0 += 64) {
        int j = j0 + lane;
        float cx = colp[j * 3], cy = colp[j * 3 + 1], cz = colp[j * 3 + 2];
        float d = (pxx - 2.f * (px * cx + py * cy + pz * cz)) + (cx * cx + cy * cy + cz * cz);
        if (d < v[KSEL - 1] || (d == v[KSEL - 1] && j < ix[KSEL - 1])) {
            float cv = d; int ci = j;
#pragma unroll
            for (int k = 0; k < KSEL; k++) {     // bubble insert, keeps sorted asc
                bool sw = (cv < v[k]) || (cv == v[k] && ci < ix[k]);
                float tv = sw ? cv : v[k]; int ti = sw ? ci : ix[k];
                cv = sw ? v[k] : cv; ci = sw ? ix[k] : ci;
                v[k] = tv; ix[k] = ti;
            }
        }
    }

    // spill sorted lists to LDS (own-lane indexable scratch; no cross-lane use)
    __shared__ float lv[4][64 * KSEL];
    __shared__ int   li[4][64 * KSEL];
#pragma unroll
    for (int k = 0; k < KSEL; k++) {
        lv[wid][lane * KSEL + k] = v[k];
        li[wid][lane * KSEL + k] = ix[k];
    }

    int p = 0; float cv = v[0]; int ci = ix[0];
    for (int s = 0; s < KSEL; s++) {
        float gv = cv; int gi = ci;
#pragma unroll
        for (int off = 32; off; off >>= 1) {
            float ov = __shfl_xor(gv, off); int oi = __shfl_xor(gi, off);
            if (ov < gv || (ov == gv && oi < gi)) { gv = ov; gi = oi; }
        }
        if (lane == 0) {
            if (outi) outi[(size_t)r * KSEL + s] = gi;
            else      outf[(size_t)r * KSEL + s] = (float)gi;
        }
        if (ci == gi) {                          // unique winner advances
            p++;
            cv = (p < KSEL) ? lv[wid][lane * KSEL + p] : INFINITY;
            ci = (p < KSEL) ? li[wid][lane * KSEL + p] : 0x7fffffff;
        }
    }
}

// argmin over the 512 coarse points per fine point (first-min index), z-batched
__global__ __launch_bounds__(256) void up_argmin(
    const float* __restrict__ ptsA, const float* __restrict__ ptsB,
    const float* __restrict__ ptscA, const float* __restrict__ ptscB,
    float* __restrict__ outA, float* __restrict__ outB)
{
    const float* pts   = blockIdx.z ? ptsB : ptsA;
    const float* pts_c = blockIdx.z ? ptscB : ptscA;
    float* out_f       = blockIdx.z ? outB : outA;
    __shared__ float4 cp[NCP];
    for (int c = threadIdx.x; c < NCP; c += 256) {
        float x = pts_c[c * 3], y = pts_c[c * 3 + 1], z = pts_c[c * 3 + 2];
        cp[c] = make_float4(x, y, z, x * x + y * y + z * z);
    }
    __syncthreads();
    int n = blockIdx.x * 256 + threadIdx.x;
    float px = pts[n * 3], py = pts[n * 3 + 1], pz = pts[n * 3 + 2];
    float pxx = px * px + py * py + pz * pz;
    float best = INFINITY; int bi = 0;
    for (int c = 0; c < NCP; c++) {
        float4 q = cp[c];
        float d = (pxx - 2.f * (px * q.x + py * q.y + pz * q.z)) + q.w;
        if (d < best) { best = d; bi = c; }
    }
    out_f[n] = (float)bi;
}

// spot[n,k] = idx16[mi[n]][k]   (z-batched)
__global__ void spot_gather(const int* __restrict__ idxA, const int* __restrict__ idxB,
                            const int* __restrict__ miA, const int* __restrict__ miB,
                            float* __restrict__ outA, float* __restrict__ outB)
{
    const int* idx16 = blockIdx.z ? idxB : idxA;
    const int* mi    = blockIdx.z ? miB : miA;
    float* outp      = blockIdx.z ? outB : outA;
    int t = blockIdx.x * 256 + threadIdx.x;     // 65536
    int n = t >> 4, k = t & 15;
    outp[t] = (float)idx16[(size_t)mi[n] * SPOTK + k];
}

// ---------------------------------------------------------------------------
extern "C" void kernel_launch(void* const* d_in, const int* in_sizes, int n_in,
                              void* d_out, int out_size, void* d_ws, size_t ws_size,
                              hipStream_t stream)
{
    const float* ref_points   = (const float*)d_in[0];
    const float* src_points   = (const float*)d_in[1];
    const float* ref_feats    = (const float*)d_in[2];
    const float* src_feats    = (const float*)d_in[3];
    const float* ref_points_c = (const float*)d_in[4];
    const float* src_points_c = (const float*)d_in[5];
    const float* ref_feats_c  = (const float*)d_in[6];
    const float* src_feats_c  = (const float*)d_in[7];
    const float* W1 = (const float*)d_in[8];
    const float* b1 = (const float*)d_in[9];
    const float* W2 = (const float*)d_in[10];
    const float* b2 = (const float*)d_in[11];

    // ---- d_out layout (all float32; indices written as float) ----
    float* out = (float*)d_out;
    float* o_scores = out;                       // 4096*4096
    float* o_compr  = o_scores + (size_t)NP * NP;
    float* o_comps  = o_compr + NP;
    float* o_seedr  = o_comps + NP;
    float* o_seeds  = o_seedr + SEEDN;
    float* o_spotr  = o_seeds + SEEDN;           // 4096*16
    float* o_spots  = o_spotr + (size_t)NP * SPOTK;
    float* o_hcr    = o_spots + (size_t)NP * SPOTK;   // 512*256
    float* o_hcs    = o_hcr + (size_t)NCP * HD;
    float* o_rup    = o_hcs + (size_t)NCP * HD;  // 4096
    float* o_sup    = o_rup + NP;
    float* o_rdown  = o_sup + NP;                // 512*8
    float* o_sdown  = o_rdown + (size_t)NCP * DOWNK;

    // ---- workspace layout ----
    float* ws = (float*)d_ws;
    float* hfr   = ws;                           // 4096*256
    float* hfs   = hfr + (size_t)NP * HD;
    float* rmax  = hfs + (size_t)NP * HD;        // 4096 each
    float* rsum  = rmax + NP;
    float* cmax  = rsum + NP;
    float* csum  = cmax + NP;
    float* confr = csum + NP;
    float* confs = confr + NP;
    float* compr = confs + NP;
    float* comps = compr + NP;
    int*   mir   = (int*)(comps + NP);
    int*   mis   = mir + NP;
    float* pmax  = (float*)(mis + NP);           // 32*4096 each
    float* psum  = pmax + 32 * NP;
    float* pconf = psum + 32 * NP;
    int*   pmi   = (int*)(pconf + 32 * NP);
    float4* qr   = (float4*)(pmi + 32 * NP);     // 4096 float4 each
    float4* qs   = qr + NP;
    int* ridx16  = (int*)(qs + NP);              // 4096*16 each
    int* sidx16  = ridx16 + (size_t)NP * SPOTK;
    size_t ws_need = (size_t)((float*)(sidx16 + (size_t)NP * SPOTK) - ws) * 4;
    if (ws_size < ws_need) return;               // insufficient scratch -> fail loudly

    dim3 b256(256);

    // projections
    gemm128<false, true><<<dim3(2, 32, 2), b256, 0, stream>>>(
        ref_feats, src_feats, W2, W2, b2, hfr, hfs, NP, HD, HD);
    gemm128<false, true><<<dim3(2, 4, 2), b256, 0, stream>>>(
        ref_feats_c, src_feats_c, W1, W1, b1, o_hcr, o_hcs, NCP, HD, CCD);

    // raw scores s = hfr @ hfs^T  (into d_out scores region, finalized in place)
    gemm128<true, false><<<dim3(32, 32, 1), b256, 0, stream>>>(
        hfr, nullptr, hfs, nullptr, nullptr, o_scores, nullptr, NP, NP, HD);

    // KNN family (independent of scores)
    knn_topk<SPOTK><<<dim3(NP / 4, 1, 2), b256, 0, stream>>>(
        ref_points, src_points, ref_points, src_points, NP, NP,
        ridx16, sidx16, nullptr, nullptr);
    knn_topk<DOWNK><<<dim3(NCP / 4, 1, 2), b256, 0, stream>>>(
        ref_points_c, src_points_c, ref_points, src_points, NCP, NP,
        nullptr, nullptr, o_rdown, o_sdown);
    up_argmin<<<dim3(NP / 256, 1, 2), b256, 0, stream>>>(
        ref_points, src_points, ref_points_c, src_points_c, o_rup, o_sup);

    // dual softmax
    row_stats<<<NP, b256, 0, stream>>>(o_scores, rmax, rsum);
    col_stats_partial<<<dim3(16, 32), b256, 0, stream>>>(o_scores, pmax, psum);
    col_stats_combine<<<16, b256, 0, stream>>>(pmax, psum, cmax, csum);
    finalize_rows<<<NP, b256, 0, stream>>>(o_scores, rmax, rsum, cmax, csum, confr, mir);
    col_argmax_partial<<<dim3(16, 32), b256, 0, stream>>>(o_scores, pconf, pmi);
    col_argmax_combine<<<16, b256, 0, stream>>>(pconf, pmi, confs, mis);

    // compatibility (recompute distances from points; gather matched points once)
    gather_pts<<<dim3(NP / 256, 1, 2), b256, 0, stream>>>(
        src_points, ref_points, mir, mis, qr, qs);
    compat_kernel<<<dim3(NP, 1, 2), b256, 0, stream>>>(
        ref_points, src_points, qr, qs, o_compr, o_comps, compr, comps);

    // seeding (two single-wave blocks, concurrent via z)
    seed_kernel<<<dim3(1, 1, 2), dim3(64), 0, stream>>>(
        compr, comps, confr, confs, o_seedr, o_seeds);

    // spot gathers
    spot_gather<<<dim3((NP * SPOTK) / 256, 1, 2), b256, 0, stream>>>(
        sidx16, ridx16, mir, mis, o_spotr, o_spots);
}

// Round 3
// 956.058 us; speedup vs baseline: 1.6758x; 1.5119x over previous
//
#include <hip/hip_runtime.h>
#include <math.h>

#define NP 4096      // N = M
#define NCP 512      // NC = MC
#define HD 256       // H and CF
#define CCD 1024     // CC
#define SPOTK 16
#define DOWNK 8
#define SEEDN 128

// ---------------------------------------------------------------------------
// Tiled f32 GEMM: C[M,N] = A[M,K] @ B[K,N] (+bias).  BT: B stored as [N,K]
// (i.e. C = A @ B^T).  128x128 tile, 256 threads, 8x8 microtile, BK=16.
// blockIdx.z selects (A0,B0,C0) vs (A1,B1,C1) for batching two GEMMs.
// ---------------------------------------------------------------------------
template<bool BT, bool BIAS>
__global__ __launch_bounds__(256) void gemm128(
    const float* __restrict__ A0, const float* __restrict__ A1,
    const float* __restrict__ B0, const float* __restrict__ B1,
    const float* __restrict__ bias, float* __restrict__ C0, float* __restrict__ C1,
    int M, int N, int K)
{
    const float* A = blockIdx.z ? A1 : A0;
    const float* B = blockIdx.z ? B1 : B0;
    float* C = blockIdx.z ? C1 : C0;

    __shared__ float As[16][128];
    __shared__ float Bs[16][128];

    const int bm = blockIdx.y * 128, bn = blockIdx.x * 128;
    const int t = threadIdx.x;
    const int tx = t & 15, ty = t >> 4;

    float acc[8][8];
#pragma unroll
    for (int i = 0; i < 8; i++)
#pragma unroll
        for (int j = 0; j < 8; j++) acc[i][j] = 0.f;

    for (int k0 = 0; k0 < K; k0 += 16) {
#pragma unroll
        for (int i = 0; i < 8; i++) {            // A tile: 128 rows x 16 k
            int idx = t + i * 256;
            int m = idx >> 4, k = idx & 15;
            As[k][m] = A[(size_t)(bm + m) * K + k0 + k];
        }
        if (BT) {
#pragma unroll
            for (int i = 0; i < 8; i++) {        // B tile from [N,K]
                int idx = t + i * 256;
                int n = idx >> 4, k = idx & 15;
                Bs[k][n] = B[(size_t)(bn + n) * K + k0 + k];
            }
        } else {
#pragma unroll
            for (int i = 0; i < 8; i++) {        // B tile from [K,N]
                int idx = t + i * 256;
                int k = idx >> 7, n = idx & 127;
                Bs[k][n] = B[(size_t)(k0 + k) * N + bn + n];
            }
        }
        __syncthreads();
#pragma unroll
        for (int kk = 0; kk < 16; kk++) {
            float a[8], b[8];
#pragma unroll
            for (int i = 0; i < 8; i++) a[i] = As[kk][ty * 8 + i];
#pragma unroll
            for (int j = 0; j < 8; j++) b[j] = Bs[kk][tx * 8 + j];
#pragma unroll
            for (int i = 0; i < 8; i++)
#pragma unroll
                for (int j = 0; j < 8; j++) acc[i][j] = fmaf(a[i], b[j], acc[i][j]);
        }
        __syncthreads();
    }
#pragma unroll
    for (int i = 0; i < 8; i++) {
        int m = bm + ty * 8 + i;
#pragma unroll
        for (int j = 0; j < 8; j++) {
            int n = bn + tx * 8 + j;
            float v = acc[i][j];
            if (BIAS) v += bias[n];
            C[(size_t)m * N + n] = v;
        }
    }
}

// ---------------------------------------------------------------------------
// Row softmax stats (two-pass, matching jax.nn.softmax)
// ---------------------------------------------------------------------------
__global__ __launch_bounds__(256) void row_stats(const float* __restrict__ s,
                                                 float* rmax, float* rsum)
{
    int n = blockIdx.x;
    const float* row = s + (size_t)n * NP;
    __shared__ float red[256];
    float m = -INFINITY;
    for (int j = threadIdx.x; j < NP; j += 256) m = fmaxf(m, row[j]);
    red[threadIdx.x] = m; __syncthreads();
    for (int off = 128; off; off >>= 1) {
        if (threadIdx.x < off) red[threadIdx.x] = fmaxf(red[threadIdx.x], red[threadIdx.x + off]);
        __syncthreads();
    }
    m = red[0]; __syncthreads();
    float sum = 0.f;
    for (int j = threadIdx.x; j < NP; j += 256) sum += expf(row[j] - m);
    red[threadIdx.x] = sum; __syncthreads();
    for (int off = 128; off; off >>= 1) {
        if (threadIdx.x < off) red[threadIdx.x] += red[threadIdx.x + off];
        __syncthreads();
    }
    if (threadIdx.x == 0) { rmax[n] = m; rsum[n] = red[0]; }
}

// Column softmax stats: partial over 128-row chunks (coalesced), then combine.
__global__ __launch_bounds__(256) void col_stats_partial(const float* __restrict__ s,
                                                         float* pmax, float* psum)
{
    int m = blockIdx.x * 256 + threadIdx.x;
    int n0 = blockIdx.y * 128;
    float mx = -INFINITY;
    for (int n = n0; n < n0 + 128; n++) mx = fmaxf(mx, s[(size_t)n * NP + m]);
    float sum = 0.f;
    for (int n = n0; n < n0 + 128; n++) sum += expf(s[(size_t)n * NP + m] - mx);
    pmax[(size_t)blockIdx.y * NP + m] = mx;
    psum[(size_t)blockIdx.y * NP + m] = sum;
}

__global__ __launch_bounds__(256) void col_stats_combine(const float* __restrict__ pmax,
                                                         const float* __restrict__ psum,
                                                         float* cmax, float* csum)
{
    int m = blockIdx.x * 256 + threadIdx.x;
    float mx = -INFINITY;
    for (int c = 0; c < 32; c++) mx = fmaxf(mx, pmax[(size_t)c * NP + m]);
    float sum = 0.f;
    for (int c = 0; c < 32; c++) sum += psum[(size_t)c * NP + m] * expf(pmax[(size_t)c * NP + m] - mx);
    cmax[m] = mx; csum[m] = sum;
}

// Final scores (in place) + per-row max/argmax (first-occurrence semantics)
__global__ __launch_bounds__(256) void finalize_rows(float* __restrict__ s,
    const float* __restrict__ rmax, const float* __restrict__ rsum,
    const float* __restrict__ cmax, const float* __restrict__ csum,
    float* __restrict__ confr, int* __restrict__ mir)
{
    int n = blockIdx.x;
    float rm = rmax[n], rs = rsum[n];
    size_t base = (size_t)n * NP;
    float best = -INFINITY; int bi = 0x7fffffff;
    for (int m1 = threadIdx.x; m1 < NP; m1 += 256) {
        float v = s[base + m1];
        float a = expf(v - rm) / rs;
        float b = expf(v - cmax[m1]) / csum[m1];
        float sc = a * b;
        s[base + m1] = sc;
        if (sc > best) { best = sc; bi = m1; }   // strict > keeps first occurrence
    }
    __shared__ float rv[256]; __shared__ int ri[256];
    rv[threadIdx.x] = best; ri[threadIdx.x] = bi; __syncthreads();
    for (int off = 128; off; off >>= 1) {
        if (threadIdx.x < off) {
            float v2 = rv[threadIdx.x + off]; int i2 = ri[threadIdx.x + off];
            if (v2 > rv[threadIdx.x] || (v2 == rv[threadIdx.x] && i2 < ri[threadIdx.x])) {
                rv[threadIdx.x] = v2; ri[threadIdx.x] = i2;
            }
        }
        __syncthreads();
    }
    if (threadIdx.x == 0) { confr[n] = rv[0]; mir[n] = ri[0]; }
}

// Column max/argmax over final scores (chunked)
__global__ __launch_bounds__(256) void col_argmax_partial(const float* __restrict__ s,
                                                          float* pconf, int* pmi)
{
    int m = blockIdx.x * 256 + threadIdx.x;
    int n0 = blockIdx.y * 128;
    float best = -INFINITY; int bi = 0;
    for (int n = n0; n < n0 + 128; n++) {
        float v = s[(size_t)n * NP + m];
        if (v > best) { best = v; bi = n; }
    }
    pconf[(size_t)blockIdx.y * NP + m] = best;
    pmi[(size_t)blockIdx.y * NP + m] = bi;
}

__global__ __launch_bounds__(256) void col_argmax_combine(const float* __restrict__ pconf,
                                                          const int* __restrict__ pmi,
                                                          float* confs, int* mis)
{
    int m = blockIdx.x * 256 + threadIdx.x;
    float best = -INFINITY; int bi = 0;
    for (int c = 0; c < 32; c++) {              // ascending chunks -> first max wins
        float v = pconf[(size_t)c * NP + m];
        if (v > best) { best = v; bi = pmi[(size_t)c * NP + m]; }
    }
    confs[m] = best; mis[m] = bi;
}

// Gather matched points + squared norm: q[j] = (x,y,z,|p|^2) of pts[mi[j]]
// z-batched: z=0 (srcA pts, miA)->qA ; z=1 (srcB pts, miB)->qB
__global__ void gather_pts(const float* __restrict__ ptsA, const float* __restrict__ ptsB,
                           const int* __restrict__ miA, const int* __restrict__ miB,
                           float4* __restrict__ qA, float4* __restrict__ qB)
{
    const float* pts = blockIdx.z ? ptsB : ptsA;
    const int*   mi  = blockIdx.z ? miB : miA;
    float4*      q   = blockIdx.z ? qB : qA;
    int j = blockIdx.x * 256 + threadIdx.x;
    if (j >= NP) return;
    int idx = mi[j];
    float x = pts[idx * 3], y = pts[idx * 3 + 1], z = pts[idx * 3 + 2];
    q[j] = make_float4(x, y, z, x * x + y * y + z * z);
}

// compat[n] = mean_j relu(1 - |d(base_n, base_j) - d(q_n, q_j)| / 3)   (z-batched)
__global__ __launch_bounds__(256) void compat_kernel(
    const float* __restrict__ baseA, const float* __restrict__ baseB,
    const float4* __restrict__ qA, const float4* __restrict__ qB,
    float* __restrict__ o1A, float* __restrict__ o1B,
    float* __restrict__ o2A, float* __restrict__ o2B)
{
    const float* base_pts = blockIdx.z ? baseB : baseA;
    const float4* q       = blockIdx.z ? qB : qA;
    float* out1           = blockIdx.z ? o1B : o1A;
    float* out2           = blockIdx.z ? o2B : o2A;
    int n = blockIdx.x;
    float bx = base_pts[n * 3], by = base_pts[n * 3 + 1], bz = base_pts[n * 3 + 2];
    float bxx = bx * bx + by * by + bz * bz;
    float4 a = q[n];
    float sum = 0.f;
    for (int j = threadIdx.x; j < NP; j += 256) {
        float px = base_pts[j * 3], py = base_pts[j * 3 + 1], pz = base_pts[j * 3 + 2];
        float rd = (bxx - 2.f * (bx * px + by * py + bz * pz)) + (px * px + py * py + pz * pz);
        float4 qj = q[j];
        float sd = (a.w - 2.f * (a.x * qj.x + a.y * qj.y + a.z * qj.z)) + qj.w;
        float c = 1.f - fabsf(rd - sd) / 3.0f;
        sum += fmaxf(c, 0.f);
    }
    __shared__ float red[256];
    red[threadIdx.x] = sum; __syncthreads();
    for (int off = 128; off; off >>= 1) {
        if (threadIdx.x < off) red[threadIdx.x] += red[threadIdx.x + off];
        __syncthreads();
    }
    if (threadIdx.x == 0) { float c = red[0] * (1.0f / NP); out1[n] = c; out2[n] = c; }
}

// ---------------------------------------------------------------------------
// Seeding via rank computation (fully parallel, no sequential rounds).
// w[i] = (compat[i] < max(compat)*0.5) ? conf[i]*compat[i] : 0
// rank(i) = #{ j : w[j] > w[i] || (w[j]==w[i] && j<i) }   (strict total order)
// rank < SEEDN  ->  out[rank] = i.   Exact jax.lax.top_k ordering/ties.
// Grid: (NP/256, 1, 2); each block stages full w[] in LDS and ranks its
// 256 elements by scanning LDS with broadcast float4 reads.
// ---------------------------------------------------------------------------
__global__ __launch_bounds__(256) void seed_rank(
    const float* __restrict__ compatA, const float* __restrict__ compatB,
    const float* __restrict__ confA, const float* __restrict__ confB,
    float* __restrict__ outA, float* __restrict__ outB)
{
    const float* compat = blockIdx.z ? compatB : compatA;
    const float* conf   = blockIdx.z ? confB : confA;
    float* outp         = blockIdx.z ? outB : outA;

    __shared__ float w[NP];
    __shared__ float red[256];
    int tid = threadIdx.x;

    // block-wide max(compat)
    float mx = -INFINITY;
    for (int j = tid; j < NP; j += 256) mx = fmaxf(mx, compat[j]);
    red[tid] = mx; __syncthreads();
    for (int off = 128; off; off >>= 1) {
        if (tid < off) red[tid] = fmaxf(red[tid], red[tid + off]);
        __syncthreads();
    }
    float thr = red[0] * 0.5f;
    __syncthreads();

    // weights into LDS
    for (int j = tid; j < NP; j += 256) {
        float c = compat[j];
        w[j] = (c < thr) ? conf[j] * c : 0.0f;   // both factors >= 0 -> w >= +0
    }
    __syncthreads();

    // rank my element i
    int i = blockIdx.x * 256 + tid;
    float wi = w[i];
    int rank = 0;
    const float4* w4 = (const float4*)w;
#pragma unroll 4
    for (int j4 = 0; j4 < NP / 4; j4++) {
        float4 v = w4[j4];                       // broadcast across the wave
        int j = j4 * 4;
        rank += (v.x > wi || (v.x == wi && (j    ) < i));
        rank += (v.y > wi || (v.y == wi && (j + 1) < i));
        rank += (v.z > wi || (v.z == wi && (j + 2) < i));
        rank += (v.w > wi || (v.w == wi && (j + 3) < i));
    }
    if (rank < SEEDN) outp[rank] = (float)i;     // ranks are unique -> all slots filled
}

// ---------------------------------------------------------------------------
// KNN top-K: one wave per row, 4 rows/block. Per-lane register top-K (sorted
// bubble insert, compile-time indices) over its 64-strided candidates, then
// barrier-free 64-way merge via LDS heads + shfl_xor lex-min butterfly.
// Exact jax.lax.top_k tie semantics: (dist asc, index asc).
// z-batched: z=0 (rowA,colA)->outA ; z=1 (rowB,colB)->outB.
// ---------------------------------------------------------------------------
template<int KSEL>
__global__ __launch_bounds__(256) void knn_topk(
    const float* __restrict__ rowA, const float* __restrict__ rowB,
    const float* __restrict__ colA, const float* __restrict__ colB,
    int nrows, int ncols,
    int* __restrict__ outiA, int* __restrict__ outiB,
    float* __restrict__ outfA, float* __restrict__ outfB)
{
    const float* rowp = blockIdx.z ? rowB : rowA;
    const float* colp = blockIdx.z ? colB : colA;
    int* outi = blockIdx.z ? outiB : outiA;
    float* outf = blockIdx.z ? outfB : outfA;

    int wid = threadIdx.x >> 6, lane = threadIdx.x & 63;
    int r = blockIdx.x * 4 + wid;

    float px = rowp[r * 3], py = rowp[r * 3 + 1], pz = rowp[r * 3 + 2];
    float pxx = px * px + py * py + pz * pz;

    float v[KSEL]; int ix[KSEL];
#pragma unroll
    for (int k = 0; k < KSEL; k++) { v[k] = INFINITY; ix[k] = 0x7fffffff; }

    for (int j0 = 0; j0 < ncols; j0 += 64) {
        int j = j0 + lane;
        float cx = colp[j * 3], cy = colp[j * 3 + 1], cz = colp[j * 3 + 2];
        float d = (pxx - 2.f * (px * cx + py * cy + pz * cz)) + (cx * cx + cy * cy + cz * cz);
        if (d < v[KSEL - 1] || (d == v[KSEL - 1] && j < ix[KSEL - 1])) {
            float cv = d; int ci = j;
#pragma unroll
            for (int k = 0; k < KSEL; k++) {     // bubble insert, keeps sorted asc
                bool sw = (cv < v[k]) || (cv == v[k] && ci < ix[k]);
                float tv = sw ? cv : v[k]; int ti = sw ? ci : ix[k];
                cv = sw ? v[k] : cv; ci = sw ? ix[k] : ci;
                v[k] = tv; ix[k] = ti;
            }
        }
    }

    // spill sorted lists to LDS (own-lane indexable scratch; no cross-lane use)
    __shared__ float lv[4][64 * KSEL];
    __shared__ int   li[4][64 * KSEL];
#pragma unroll
    for (int k = 0; k < KSEL; k++) {
        lv[wid][lane * KSEL + k] = v[k];
        li[wid][lane * KSEL + k] = ix[k];
    }

    int p = 0; float cv = v[0]; int ci = ix[0];
    for (int s = 0; s < KSEL; s++) {
        float gv = cv; int gi = ci;
#pragma unroll
        for (int off = 32; off; off >>= 1) {
            float ov = __shfl_xor(gv, off); int oi = __shfl_xor(gi, off);
            if (ov < gv || (ov == gv && oi < gi)) { gv = ov; gi = oi; }
        }
        if (lane == 0) {
            if (outi) outi[(size_t)r * KSEL + s] = gi;
            else      outf[(size_t)r * KSEL + s] = (float)gi;
        }
        if (ci == gi) {                          // unique winner advances
            p++;
            cv = (p < KSEL) ? lv[wid][lane * KSEL + p] : INFINITY;
            ci = (p < KSEL) ? li[wid][lane * KSEL + p] : 0x7fffffff;
        }
    }
}

// argmin over the 512 coarse points per fine point (first-min index), z-batched
__global__ __launch_bounds__(256) void up_argmin(
    const float* __restrict__ ptsA, const float* __restrict__ ptsB,
    const float* __restrict__ ptscA, const float* __restrict__ ptscB,
    float* __restrict__ outA, float* __restrict__ outB)
{
    const float* pts   = blockIdx.z ? ptsB : ptsA;
    const float* pts_c = blockIdx.z ? ptscB : ptscA;
    float* out_f       = blockIdx.z ? outB : outA;
    __shared__ float4 cp[NCP];
    for (int c = threadIdx.x; c < NCP; c += 256) {
        float x = pts_c[c * 3], y = pts_c[c * 3 + 1], z = pts_c[c * 3 + 2];
        cp[c] = make_float4(x, y, z, x * x + y * y + z * z);
    }
    __syncthreads();
    int n = blockIdx.x * 256 + threadIdx.x;
    float px = pts[n * 3], py = pts[n * 3 + 1], pz = pts[n * 3 + 2];
    float pxx = px * px + py * py + pz * pz;
    float best = INFINITY; int bi = 0;
    for (int c = 0; c < NCP; c++) {
        float4 q = cp[c];
        float d = (pxx - 2.f * (px * q.x + py * q.y + pz * q.z)) + q.w;
        if (d < best) { best = d; bi = c; }
    }
    out_f[n] = (float)bi;
}

// spot[n,k] = idx16[mi[n]][k]   (z-batched)
__global__ void spot_gather(const int* __restrict__ idxA, const int* __restrict__ idxB,
                            const int* __restrict__ miA, const int* __restrict__ miB,
                            float* __restrict__ outA, float* __restrict__ outB)
{
    const int* idx16 = blockIdx.z ? idxB : idxA;
    const int* mi    = blockIdx.z ? miB : miA;
    float* outp      = blockIdx.z ? outB : outA;
    int t = blockIdx.x * 256 + threadIdx.x;     // 65536
    int n = t >> 4, k = t & 15;
    outp[t] = (float)idx16[(size_t)mi[n] * SPOTK + k];
}

// ---------------------------------------------------------------------------
extern "C" void kernel_launch(void* const* d_in, const int* in_sizes, int n_in,
                              void* d_out, int out_size, void* d_ws, size_t ws_size,
                              hipStream_t stream)
{
    const float* ref_points   = (const float*)d_in[0];
    const float* src_points   = (const float*)d_in[1];
    const float* ref_feats    = (const float*)d_in[2];
    const float* src_feats    = (const float*)d_in[3];
    const float* ref_points_c = (const float*)d_in[4];
    const float* src_points_c = (const float*)d_in[5];
    const float* ref_feats_c  = (const float*)d_in[6];
    const float* src_feats_c  = (const float*)d_in[7];
    const float* W1 = (const float*)d_in[8];
    const float* b1 = (const float*)d_in[9];
    const float* W2 = (const float*)d_in[10];
    const float* b2 = (const float*)d_in[11];

    // ---- d_out layout (all float32; indices written as float) ----
    float* out = (float*)d_out;
    float* o_scores = out;                       // 4096*4096
    float* o_compr  = o_scores + (size_t)NP * NP;
    float* o_comps  = o_compr + NP;
    float* o_seedr  = o_comps + NP;
    float* o_seeds  = o_seedr + SEEDN;
    float* o_spotr  = o_seeds + SEEDN;           // 4096*16
    float* o_spots  = o_spotr + (size_t)NP * SPOTK;
    float* o_hcr    = o_spots + (size_t)NP * SPOTK;   // 512*256
    float* o_hcs    = o_hcr + (size_t)NCP * HD;
    float* o_rup    = o_hcs + (size_t)NCP * HD;  // 4096
    float* o_sup    = o_rup + NP;
    float* o_rdown  = o_sup + NP;                // 512*8
    float* o_sdown  = o_rdown + (size_t)NCP * DOWNK;

    // ---- workspace layout ----
    float* ws = (float*)d_ws;
    float* hfr   = ws;                           // 4096*256
    float* hfs   = hfr + (size_t)NP * HD;
    float* rmax  = hfs + (size_t)NP * HD;        // 4096 each
    float* rsum  = rmax + NP;
    float* cmax  = rsum + NP;
    float* csum  = cmax + NP;
    float* confr = csum + NP;
    float* confs = confr + NP;
    float* compr = confs + NP;
    float* comps = compr + NP;
    int*   mir   = (int*)(comps + NP);
    int*   mis   = mir + NP;
    float* pmax  = (float*)(mis + NP);           // 32*4096 each
    float* psum  = pmax + 32 * NP;
    float* pconf = psum + 32 * NP;
    int*   pmi   = (int*)(pconf + 32 * NP);
    float4* qr   = (float4*)(pmi + 32 * NP);     // 4096 float4 each
    float4* qs   = qr + NP;
    int* ridx16  = (int*)(qs + NP);              // 4096*16 each
    int* sidx16  = ridx16 + (size_t)NP * SPOTK;
    size_t ws_need = (size_t)((float*)(sidx16 + (size_t)NP * SPOTK) - ws) * 4;
    if (ws_size < ws_need) return;               // insufficient scratch -> fail loudly

    dim3 b256(256);

    // projections
    gemm128<false, true><<<dim3(2, 32, 2), b256, 0, stream>>>(
        ref_feats, src_feats, W2, W2, b2, hfr, hfs, NP, HD, HD);
    gemm128<false, true><<<dim3(2, 4, 2), b256, 0, stream>>>(
        ref_feats_c, src_feats_c, W1, W1, b1, o_hcr, o_hcs, NCP, HD, CCD);

    // raw scores s = hfr @ hfs^T  (into d_out scores region, finalized in place)
    gemm128<true, false><<<dim3(32, 32, 1), b256, 0, stream>>>(
        hfr, nullptr, hfs, nullptr, nullptr, o_scores, nullptr, NP, NP, HD);

    // KNN family (independent of scores)
    knn_topk<SPOTK><<<dim3(NP / 4, 1, 2), b256, 0, stream>>>(
        ref_points, src_points, ref_points, src_points, NP, NP,
        ridx16, sidx16, nullptr, nullptr);
    knn_topk<DOWNK><<<dim3(NCP / 4, 1, 2), b256, 0, stream>>>(
        ref_points_c, src_points_c, ref_points, src_points, NCP, NP,
        nullptr, nullptr, o_rdown, o_sdown);
    up_argmin<<<dim3(NP / 256, 1, 2), b256, 0, stream>>>(
        ref_points, src_points, ref_points_c, src_points_c, o_rup, o_sup);

    // dual softmax
    row_stats<<<NP, b256, 0, stream>>>(o_scores, rmax, rsum);
    col_stats_partial<<<dim3(16, 32), b256, 0, stream>>>(o_scores, pmax, psum);
    col_stats_combine<<<16, b256, 0, stream>>>(pmax, psum, cmax, csum);
    finalize_rows<<<NP, b256, 0, stream>>>(o_scores, rmax, rsum, cmax, csum, confr, mir);
    col_argmax_partial<<<dim3(16, 32), b256, 0, stream>>>(o_scores, pconf, pmi);
    col_argmax_combine<<<16, b256, 0, stream>>>(pconf, pmi, confs, mis);

    // compatibility (recompute distances from points; gather matched points once)
    gather_pts<<<dim3(NP / 256, 1, 2), b256, 0, stream>>>(
        src_points, ref_points, mir, mis, qr, qs);
    compat_kernel<<<dim3(NP, 1, 2), b256, 0, stream>>>(
        ref_points, src_points, qr, qs, o_compr, o_comps, compr, comps);

    // seeding (rank-based, fully parallel)
    seed_rank<<<dim3(NP / 256, 1, 2), b256, 0, stream>>>(
        compr, comps, confr, confs, o_seedr, o_seeds);

    // spot gathers
    spot_gather<<<dim3((NP * SPOTK) / 256, 1, 2), b256, 0, stream>>>(
        sidx16, ridx16, mir, mis, o_spotr, o_spots);
}

// Round 4
// 819.942 us; speedup vs baseline: 1.9540x; 1.1660x over previous
//
#include <hip/hip_runtime.h>
#include <math.h>

#define NP 4096      // N = M
#define NCP 512      // NC = MC
#define HD 256       // H and CF
#define CCD 1024     // CC
#define SPOTK 16
#define DOWNK 8
#define SEEDN 128

// ---------------------------------------------------------------------------
// Tiled f32 GEMM: C[M,N] = A[M,K] @ B[K,N] (+bias).  BT: B stored as [N,K]
// (i.e. C = A @ B^T).  128x128 tile, 256 threads, 8x8 microtile, BK=16.
// blockIdx.z selects (A0,B0,C0) vs (A1,B1,C1) for batching two GEMMs.
// ---------------------------------------------------------------------------
template<bool BT, bool BIAS>
__global__ __launch_bounds__(256) void gemm128(
    const float* __restrict__ A0, const float* __restrict__ A1,
    const float* __restrict__ B0, const float* __restrict__ B1,
    const float* __restrict__ bias, float* __restrict__ C0, float* __restrict__ C1,
    int M, int N, int K)
{
    const float* A = blockIdx.z ? A1 : A0;
    const float* B = blockIdx.z ? B1 : B0;
    float* C = blockIdx.z ? C1 : C0;

    __shared__ float As[16][128];
    __shared__ float Bs[16][128];

    const int bm = blockIdx.y * 128, bn = blockIdx.x * 128;
    const int t = threadIdx.x;
    const int tx = t & 15, ty = t >> 4;

    float acc[8][8];
#pragma unroll
    for (int i = 0; i < 8; i++)
#pragma unroll
        for (int j = 0; j < 8; j++) acc[i][j] = 0.f;

    for (int k0 = 0; k0 < K; k0 += 16) {
#pragma unroll
        for (int i = 0; i < 8; i++) {            // A tile: 128 rows x 16 k
            int idx = t + i * 256;
            int m = idx >> 4, k = idx & 15;
            As[k][m] = A[(size_t)(bm + m) * K + k0 + k];
        }
        if (BT) {
#pragma unroll
            for (int i = 0; i < 8; i++) {        // B tile from [N,K]
                int idx = t + i * 256;
                int n = idx >> 4, k = idx & 15;
                Bs[k][n] = B[(size_t)(bn + n) * K + k0 + k];
            }
        } else {
#pragma unroll
            for (int i = 0; i < 8; i++) {        // B tile from [K,N]
                int idx = t + i * 256;
                int k = idx >> 7, n = idx & 127;
                Bs[k][n] = B[(size_t)(k0 + k) * N + bn + n];
            }
        }
        __syncthreads();
#pragma unroll
        for (int kk = 0; kk < 16; kk++) {
            float a[8], b[8];
#pragma unroll
            for (int i = 0; i < 8; i++) a[i] = As[kk][ty * 8 + i];
#pragma unroll
            for (int j = 0; j < 8; j++) b[j] = Bs[kk][tx * 8 + j];
#pragma unroll
            for (int i = 0; i < 8; i++)
#pragma unroll
                for (int j = 0; j < 8; j++) acc[i][j] = fmaf(a[i], b[j], acc[i][j]);
        }
        __syncthreads();
    }
#pragma unroll
    for (int i = 0; i < 8; i++) {
        int m = bm + ty * 8 + i;
#pragma unroll
        for (int j = 0; j < 8; j++) {
            int n = bn + tx * 8 + j;
            float v = acc[i][j];
            if (BIAS) v += bias[n];
            C[(size_t)m * N + n] = v;
        }
    }
}

// ---------------------------------------------------------------------------
// Row softmax stats (two-pass, matching jax.nn.softmax)
// ---------------------------------------------------------------------------
__global__ __launch_bounds__(256) void row_stats(const float* __restrict__ s,
                                                 float* rmax, float* rsum)
{
    int n = blockIdx.x;
    const float* row = s + (size_t)n * NP;
    __shared__ float red[256];
    float m = -INFINITY;
    for (int j = threadIdx.x; j < NP; j += 256) m = fmaxf(m, row[j]);
    red[threadIdx.x] = m; __syncthreads();
    for (int off = 128; off; off >>= 1) {
        if (threadIdx.x < off) red[threadIdx.x] = fmaxf(red[threadIdx.x], red[threadIdx.x + off]);
        __syncthreads();
    }
    m = red[0]; __syncthreads();
    float sum = 0.f;
    for (int j = threadIdx.x; j < NP; j += 256) sum += expf(row[j] - m);
    red[threadIdx.x] = sum; __syncthreads();
    for (int off = 128; off; off >>= 1) {
        if (threadIdx.x < off) red[threadIdx.x] += red[threadIdx.x + off];
        __syncthreads();
    }
    if (threadIdx.x == 0) { rmax[n] = m; rsum[n] = red[0]; }
}

// Column softmax stats: partial over 128-row chunks (coalesced), then combine.
__global__ __launch_bounds__(256) void col_stats_partial(const float* __restrict__ s,
                                                         float* pmax, float* psum)
{
    int m = blockIdx.x * 256 + threadIdx.x;
    int n0 = blockIdx.y * 128;
    float mx = -INFINITY;
    for (int n = n0; n < n0 + 128; n++) mx = fmaxf(mx, s[(size_t)n * NP + m]);
    float sum = 0.f;
    for (int n = n0; n < n0 + 128; n++) sum += expf(s[(size_t)n * NP + m] - mx);
    pmax[(size_t)blockIdx.y * NP + m] = mx;
    psum[(size_t)blockIdx.y * NP + m] = sum;
}

__global__ __launch_bounds__(256) void col_stats_combine(const float* __restrict__ pmax,
                                                         const float* __restrict__ psum,
                                                         float* cmax, float* csum)
{
    int m = blockIdx.x * 256 + threadIdx.x;
    float mx = -INFINITY;
    for (int c = 0; c < 32; c++) mx = fmaxf(mx, pmax[(size_t)c * NP + m]);
    float sum = 0.f;
    for (int c = 0; c < 32; c++) sum += psum[(size_t)c * NP + m] * expf(pmax[(size_t)c * NP + m] - mx);
    cmax[m] = mx; csum[m] = sum;
}

// Final scores (in place) + per-row max/argmax (first-occurrence semantics)
__global__ __launch_bounds__(256) void finalize_rows(float* __restrict__ s,
    const float* __restrict__ rmax, const float* __restrict__ rsum,
    const float* __restrict__ cmax, const float* __restrict__ csum,
    float* __restrict__ confr, int* __restrict__ mir)
{
    int n = blockIdx.x;
    float rm = rmax[n], rs = rsum[n];
    size_t base = (size_t)n * NP;
    float best = -INFINITY; int bi = 0x7fffffff;
    for (int m1 = threadIdx.x; m1 < NP; m1 += 256) {
        float v = s[base + m1];
        float a = expf(v - rm) / rs;
        float b = expf(v - cmax[m1]) / csum[m1];
        float sc = a * b;
        s[base + m1] = sc;
        if (sc > best) { best = sc; bi = m1; }   // strict > keeps first occurrence
    }
    __shared__ float rv[256]; __shared__ int ri[256];
    rv[threadIdx.x] = best; ri[threadIdx.x] = bi; __syncthreads();
    for (int off = 128; off; off >>= 1) {
        if (threadIdx.x < off) {
            float v2 = rv[threadIdx.x + off]; int i2 = ri[threadIdx.x + off];
            if (v2 > rv[threadIdx.x] || (v2 == rv[threadIdx.x] && i2 < ri[threadIdx.x])) {
                rv[threadIdx.x] = v2; ri[threadIdx.x] = i2;
            }
        }
        __syncthreads();
    }
    if (threadIdx.x == 0) { confr[n] = rv[0]; mir[n] = ri[0]; }
}

// Column max/argmax over final scores (chunked)
__global__ __launch_bounds__(256) void col_argmax_partial(const float* __restrict__ s,
                                                          float* pconf, int* pmi)
{
    int m = blockIdx.x * 256 + threadIdx.x;
    int n0 = blockIdx.y * 128;
    float best = -INFINITY; int bi = 0;
    for (int n = n0; n < n0 + 128; n++) {
        float v = s[(size_t)n * NP + m];
        if (v > best) { best = v; bi = n; }
    }
    pconf[(size_t)blockIdx.y * NP + m] = best;
    pmi[(size_t)blockIdx.y * NP + m] = bi;
}

__global__ __launch_bounds__(256) void col_argmax_combine(const float* __restrict__ pconf,
                                                          const int* __restrict__ pmi,
                                                          float* confs, int* mis)
{
    int m = blockIdx.x * 256 + threadIdx.x;
    float best = -INFINITY; int bi = 0;
    for (int c = 0; c < 32; c++) {              // ascending chunks -> first max wins
        float v = pconf[(size_t)c * NP + m];
        if (v > best) { best = v; bi = pmi[(size_t)c * NP + m]; }
    }
    confs[m] = best; mis[m] = bi;
}

// Gather matched points + squared norm: q[j] = (x,y,z,|p|^2) of pts[mi[j]]
// z-batched: z=0 (srcA pts, miA)->qA ; z=1 (srcB pts, miB)->qB
__global__ void gather_pts(const float* __restrict__ ptsA, const float* __restrict__ ptsB,
                           const int* __restrict__ miA, const int* __restrict__ miB,
                           float4* __restrict__ qA, float4* __restrict__ qB)
{
    const float* pts = blockIdx.z ? ptsB : ptsA;
    const int*   mi  = blockIdx.z ? miB : miA;
    float4*      q   = blockIdx.z ? qB : qA;
    int j = blockIdx.x * 256 + threadIdx.x;
    if (j >= NP) return;
    int idx = mi[j];
    float x = pts[idx * 3], y = pts[idx * 3 + 1], z = pts[idx * 3 + 2];
    q[j] = make_float4(x, y, z, x * x + y * y + z * z);
}

// compat[n] = mean_j relu(1 - |d(base_n, base_j) - d(q_n, q_j)| / 3)   (z-batched)
__global__ __launch_bounds__(256) void compat_kernel(
    const float* __restrict__ baseA, const float* __restrict__ baseB,
    const float4* __restrict__ qA, const float4* __restrict__ qB,
    float* __restrict__ o1A, float* __restrict__ o1B,
    float* __restrict__ o2A, float* __restrict__ o2B)
{
    const float* base_pts = blockIdx.z ? baseB : baseA;
    const float4* q       = blockIdx.z ? qB : qA;
    float* out1           = blockIdx.z ? o1B : o1A;
    float* out2           = blockIdx.z ? o2B : o2A;
    int n = blockIdx.x;
    float bx = base_pts[n * 3], by = base_pts[n * 3 + 1], bz = base_pts[n * 3 + 2];
    float bxx = bx * bx + by * by + bz * bz;
    float4 a = q[n];
    float sum = 0.f;
    for (int j = threadIdx.x; j < NP; j += 256) {
        float px = base_pts[j * 3], py = base_pts[j * 3 + 1], pz = base_pts[j * 3 + 2];
        float rd = (bxx - 2.f * (bx * px + by * py + bz * pz)) + (px * px + py * py + pz * pz);
        float4 qj = q[j];
        float sd = (a.w - 2.f * (a.x * qj.x + a.y * qj.y + a.z * qj.z)) + qj.w;
        float c = 1.f - fabsf(rd - sd) / 3.0f;
        sum += fmaxf(c, 0.f);
    }
    __shared__ float red[256];
    red[threadIdx.x] = sum; __syncthreads();
    for (int off = 128; off; off >>= 1) {
        if (threadIdx.x < off) red[threadIdx.x] += red[threadIdx.x + off];
        __syncthreads();
    }
    if (threadIdx.x == 0) { float c = red[0] * (1.0f / NP); out1[n] = c; out2[n] = c; }
}

// ---------------------------------------------------------------------------
// Seeding via rank computation (fully parallel, no sequential rounds).
// ---------------------------------------------------------------------------
__global__ __launch_bounds__(256) void seed_rank(
    const float* __restrict__ compatA, const float* __restrict__ compatB,
    const float* __restrict__ confA, const float* __restrict__ confB,
    float* __restrict__ outA, float* __restrict__ outB)
{
    const float* compat = blockIdx.z ? compatB : compatA;
    const float* conf   = blockIdx.z ? confB : confA;
    float* outp         = blockIdx.z ? outB : outA;

    __shared__ float w[NP];
    __shared__ float red[256];
    int tid = threadIdx.x;

    float mx = -INFINITY;
    for (int j = tid; j < NP; j += 256) mx = fmaxf(mx, compat[j]);
    red[tid] = mx; __syncthreads();
    for (int off = 128; off; off >>= 1) {
        if (tid < off) red[tid] = fmaxf(red[tid], red[tid + off]);
        __syncthreads();
    }
    float thr = red[0] * 0.5f;
    __syncthreads();

    for (int j = tid; j < NP; j += 256) {
        float c = compat[j];
        w[j] = (c < thr) ? conf[j] * c : 0.0f;
    }
    __syncthreads();

    int i = blockIdx.x * 256 + tid;
    float wi = w[i];
    int rank = 0;
    const float4* w4 = (const float4*)w;
#pragma unroll 4
    for (int j4 = 0; j4 < NP / 4; j4++) {
        float4 v = w4[j4];
        int j = j4 * 4;
        rank += (v.x > wi || (v.x == wi && (j    ) < i));
        rank += (v.y > wi || (v.y == wi && (j + 1) < i));
        rank += (v.z > wi || (v.z == wi && (j + 2) < i));
        rank += (v.w > wi || (v.w == wi && (j + 3) < i));
    }
    if (rank < SEEDN) outp[rank] = (float)i;
}

// ---------------------------------------------------------------------------
// Wave-wide bitonic sorts via shfl_xor (64 lanes, zero barriers).
// ---------------------------------------------------------------------------
__device__ __forceinline__ void bitonic64_val(float& d, int lane)
{
#pragma unroll
    for (int k = 2; k <= 64; k <<= 1)
#pragma unroll
        for (int j = k >> 1; j > 0; j >>= 1) {
            float od = __shfl_xor(d, j);
            bool lower = ((lane & j) == 0);
            bool asc   = ((lane & k) == 0);
            bool take = (lower == asc) ? (od < d) : (d < od);
            d = take ? od : d;
        }
}

__device__ __forceinline__ void bitonic64_lex(float& d, int& i, int lane)
{
#pragma unroll
    for (int k = 2; k <= 64; k <<= 1)
#pragma unroll
        for (int j = k >> 1; j > 0; j >>= 1) {
            float od = __shfl_xor(d, j);
            int   oi = __shfl_xor(i, j);
            bool lower = ((lane & j) == 0);
            bool asc   = ((lane & k) == 0);
            bool less = (od < d) || (od == d && oi < i);   // other < mine
            bool gtr  = (d < od) || (d == od && i < oi);   // mine < other
            bool take = (lower == asc) ? less : gtr;
            d = take ? od : d;
            i = take ? oi : i;
        }
}

// Merge a 64-element chunk (cd,ci) into running sorted top-KSEL (run in lanes
// 0..KSEL-1, rest +inf). Only the chunk's KSEL smallest can matter.
template<int KSEL>
__device__ __forceinline__ void merge_chunk(float& run_d, int& run_i,
                                            float cd, int ci, int lane)
{
    bitonic64_lex(cd, ci, lane);
    int src = lane - KSEL;
    int s2 = (src >= 0 && src < KSEL) ? src : 0;
    float cd2 = __shfl(cd, s2);
    int   ci2 = __shfl(ci, s2);
    float nd = (lane < KSEL) ? run_d : ((lane < 2 * KSEL) ? cd2 : INFINITY);
    int   ni = (lane < KSEL) ? run_i : ((lane < 2 * KSEL) ? ci2 : 0x7fffffff);
    bitonic64_lex(nd, ni, lane);
    run_d = nd; run_i = ni;
}

// ---------------------------------------------------------------------------
// KNN top-K via threshold pre-filter. One wave per row, 4 rows/block.
// Pass 1: per-lane min over its 64-strided candidates; T = KSEL-th smallest of
//   the 64 lane minima (provable upper bound on the global KSEL-th distance).
// Pass 2: ballot-compact survivors (d <= T+eps) into an LDS queue (~2*KSEL
//   expected per ROW).
// Pass 3: exact lex (d asc, idx asc) top-KSEL of survivors via bitonic merge
//   == jax.lax.top_k tie semantics. Overflow (>256 survivors) -> full
//   chunked-merge fallback (correct for any input).
// ---------------------------------------------------------------------------
template<int KSEL>
__global__ __launch_bounds__(256) void knn_topk(
    const float* __restrict__ rowA, const float* __restrict__ rowB,
    const float* __restrict__ colA, const float* __restrict__ colB,
    int ncols,
    int* __restrict__ outiA, int* __restrict__ outiB,
    float* __restrict__ outfA, float* __restrict__ outfB)
{
    const float* rowp = blockIdx.z ? rowB : rowA;
    const float* colp = blockIdx.z ? colB : colA;
    int* outi = blockIdx.z ? outiB : outiA;
    float* outf = blockIdx.z ? outfB : outfA;

    int wid = threadIdx.x >> 6, lane = threadIdx.x & 63;
    int r = blockIdx.x * 4 + wid;

    float px = rowp[r * 3], py = rowp[r * 3 + 1], pz = rowp[r * 3 + 2];
    float pxx = px * px + py * py + pz * pz;

    // pass 1: per-lane min distance
    float mn = INFINITY;
    for (int j0 = 0; j0 < ncols; j0 += 64) {
        int j = j0 + lane;
        float cx = colp[j * 3], cy = colp[j * 3 + 1], cz = colp[j * 3 + 2];
        float d = (pxx - 2.f * (px * cx + py * cy + pz * cz)) + (cx * cx + cy * cy + cz * cz);
        mn = fminf(mn, d);
    }
    bitonic64_val(mn, lane);
    float T = __shfl(mn, KSEL - 1) + 1e-4f;      // slack >> fp recompute jitter

    // pass 2: compact survivors into LDS queue
    __shared__ float qd[4][256];
    __shared__ int   qi[4][256];
    int cnt = 0; bool ovf = false;
    for (int j0 = 0; j0 < ncols; j0 += 64) {
        int j = j0 + lane;
        float cx = colp[j * 3], cy = colp[j * 3 + 1], cz = colp[j * 3 + 2];
        float d = (pxx - 2.f * (px * cx + py * cy + pz * cz)) + (cx * cx + cy * cy + cz * cz);
        bool keep = (d <= T);
        unsigned long long mask = __ballot(keep);
        int nsel = __popcll(mask);
        if (cnt + nsel > 256) { ovf = true; break; }
        if (keep) {
            int pos = cnt + (int)__popcll(mask & ((1ull << lane) - 1ull));
            qd[wid][pos] = d; qi[wid][pos] = j;
        }
        cnt += nsel;
    }

    float run_d = INFINITY; int run_i = 0x7fffffff;
    if (!ovf) {
        for (int c = 0; c < cnt; c += 64) {
            int idx = c + lane;
            float cd = (idx < cnt) ? qd[wid][idx] : INFINITY;
            int   ci = (idx < cnt) ? qi[wid][idx] : 0x7fffffff;
            merge_chunk<KSEL>(run_d, run_i, cd, ci, lane);
        }
    } else {                                     // degenerate-input fallback
        for (int j0 = 0; j0 < ncols; j0 += 64) {
            int j = j0 + lane;
            float cx = colp[j * 3], cy = colp[j * 3 + 1], cz = colp[j * 3 + 2];
            float d = (pxx - 2.f * (px * cx + py * cy + pz * cz)) + (cx * cx + cy * cy + cz * cz);
            merge_chunk<KSEL>(run_d, run_i, d, j, lane);
        }
    }

    if (lane < KSEL) {
        if (outi) outi[(size_t)r * KSEL + lane] = run_i;
        else      outf[(size_t)r * KSEL + lane] = (float)run_i;
    }
}

// argmin over the 512 coarse points per fine point (first-min index), z-batched
__global__ __launch_bounds__(256) void up_argmin(
    const float* __restrict__ ptsA, const float* __restrict__ ptsB,
    const float* __restrict__ ptscA, const float* __restrict__ ptscB,
    float* __restrict__ outA, float* __restrict__ outB)
{
    const float* pts   = blockIdx.z ? ptsB : ptsA;
    const float* pts_c = blockIdx.z ? ptscB : ptscA;
    float* out_f       = blockIdx.z ? outB : outA;
    __shared__ float4 cp[NCP];
    for (int c = threadIdx.x; c < NCP; c += 256) {
        float x = pts_c[c * 3], y = pts_c[c * 3 + 1], z = pts_c[c * 3 + 2];
        cp[c] = make_float4(x, y, z, x * x + y * y + z * z);
    }
    __syncthreads();
    int n = blockIdx.x * 256 + threadIdx.x;
    float px = pts[n * 3], py = pts[n * 3 + 1], pz = pts[n * 3 + 2];
    float pxx = px * px + py * py + pz * pz;
    float best = INFINITY; int bi = 0;
    for (int c = 0; c < NCP; c++) {
        float4 q = cp[c];
        float d = (pxx - 2.f * (px * q.x + py * q.y + pz * q.z)) + q.w;
        if (d < best) { best = d; bi = c; }
    }
    out_f[n] = (float)bi;
}

// spot[n,k] = idx16[mi[n]][k]   (z-batched)
__global__ void spot_gather(const int* __restrict__ idxA, const int* __restrict__ idxB,
                            const int* __restrict__ miA, const int* __restrict__ miB,
                            float* __restrict__ outA, float* __restrict__ outB)
{
    const int* idx16 = blockIdx.z ? idxB : idxA;
    const int* mi    = blockIdx.z ? miB : miA;
    float* outp      = blockIdx.z ? outB : outA;
    int t = blockIdx.x * 256 + threadIdx.x;     // 65536
    int n = t >> 4, k = t & 15;
    outp[t] = (float)idx16[(size_t)mi[n] * SPOTK + k];
}

// ---------------------------------------------------------------------------
extern "C" void kernel_launch(void* const* d_in, const int* in_sizes, int n_in,
                              void* d_out, int out_size, void* d_ws, size_t ws_size,
                              hipStream_t stream)
{
    const float* ref_points   = (const float*)d_in[0];
    const float* src_points   = (const float*)d_in[1];
    const float* ref_feats    = (const float*)d_in[2];
    const float* src_feats    = (const float*)d_in[3];
    const float* ref_points_c = (const float*)d_in[4];
    const float* src_points_c = (const float*)d_in[5];
    const float* ref_feats_c  = (const float*)d_in[6];
    const float* src_feats_c  = (const float*)d_in[7];
    const float* W1 = (const float*)d_in[8];
    const float* b1 = (const float*)d_in[9];
    const float* W2 = (const float*)d_in[10];
    const float* b2 = (const float*)d_in[11];

    // ---- d_out layout (all float32; indices written as float) ----
    float* out = (float*)d_out;
    float* o_scores = out;                       // 4096*4096
    float* o_compr  = o_scores + (size_t)NP * NP;
    float* o_comps  = o_compr + NP;
    float* o_seedr  = o_comps + NP;
    float* o_seeds  = o_seedr + SEEDN;
    float* o_spotr  = o_seeds + SEEDN;           // 4096*16
    float* o_spots  = o_spotr + (size_t)NP * SPOTK;
    float* o_hcr    = o_spots + (size_t)NP * SPOTK;   // 512*256
    float* o_hcs    = o_hcr + (size_t)NCP * HD;
    float* o_rup    = o_hcs + (size_t)NCP * HD;  // 4096
    float* o_sup    = o_rup + NP;
    float* o_rdown  = o_sup + NP;                // 512*8
    float* o_sdown  = o_rdown + (size_t)NCP * DOWNK;

    // ---- workspace layout ----
    float* ws = (float*)d_ws;
    float* hfr   = ws;                           // 4096*256
    float* hfs   = hfr + (size_t)NP * HD;
    float* rmax  = hfs + (size_t)NP * HD;        // 4096 each
    float* rsum  = rmax + NP;
    float* cmax  = rsum + NP;
    float* csum  = cmax + NP;
    float* confr = csum + NP;
    float* confs = confr + NP;
    float* compr = confs + NP;
    float* comps = compr + NP;
    int*   mir   = (int*)(comps + NP);
    int*   mis   = mir + NP;
    float* pmax  = (float*)(mis + NP);           // 32*4096 each
    float* psum  = pmax + 32 * NP;
    float* pconf = psum + 32 * NP;
    int*   pmi   = (int*)(pconf + 32 * NP);
    float4* qr   = (float4*)(pmi + 32 * NP);     // 4096 float4 each
    float4* qs   = qr + NP;
    int* ridx16  = (int*)(qs + NP);              // 4096*16 each
    int* sidx16  = ridx16 + (size_t)NP * SPOTK;
    size_t ws_need = (size_t)((float*)(sidx16 + (size_t)NP * SPOTK) - ws) * 4;
    if (ws_size < ws_need) return;               // insufficient scratch -> fail loudly

    dim3 b256(256);

    // projections
    gemm128<false, true><<<dim3(2, 32, 2), b256, 0, stream>>>(
        ref_feats, src_feats, W2, W2, b2, hfr, hfs, NP, HD, HD);
    gemm128<false, true><<<dim3(2, 4, 2), b256, 0, stream>>>(
        ref_feats_c, src_feats_c, W1, W1, b1, o_hcr, o_hcs, NCP, HD, CCD);

    // raw scores s = hfr @ hfs^T  (into d_out scores region, finalized in place)
    gemm128<true, false><<<dim3(32, 32, 1), b256, 0, stream>>>(
        hfr, nullptr, hfs, nullptr, nullptr, o_scores, nullptr, NP, NP, HD);

    // KNN family (independent of scores)
    knn_topk<SPOTK><<<dim3(NP / 4, 1, 2), b256, 0, stream>>>(
        ref_points, src_points, ref_points, src_points, NP,
        ridx16, sidx16, nullptr, nullptr);
    knn_topk<DOWNK><<<dim3(NCP / 4, 1, 2), b256, 0, stream>>>(
        ref_points_c, src_points_c, ref_points, src_points, NP,
        nullptr, nullptr, o_rdown, o_sdown);
    up_argmin<<<dim3(NP / 256, 1, 2), b256, 0, stream>>>(
        ref_points, src_points, ref_points_c, src_points_c, o_rup, o_sup);

    // dual softmax
    row_stats<<<NP, b256, 0, stream>>>(o_scores, rmax, rsum);
    col_stats_partial<<<dim3(16, 32), b256, 0, stream>>>(o_scores, pmax, psum);
    col_stats_combine<<<16, b256, 0, stream>>>(pmax, psum, cmax, csum);
    finalize_rows<<<NP, b256, 0, stream>>>(o_scores, rmax, rsum, cmax, csum, confr, mir);
    col_argmax_partial<<<dim3(16, 32), b256, 0, stream>>>(o_scores, pconf, pmi);
    col_argmax_combine<<<16, b256, 0, stream>>>(pconf, pmi, confs, mis);

    // compatibility (recompute distances from points; gather matched points once)
    gather_pts<<<dim3(NP / 256, 1, 2), b256, 0, stream>>>(
        src_points, ref_points, mir, mis, qr, qs);
    compat_kernel<<<dim3(NP, 1, 2), b256, 0, stream>>>(
        ref_points, src_points, qr, qs, o_compr, o_comps, compr, comps);

    // seeding (rank-based, fully parallel)
    seed_rank<<<dim3(NP / 256, 1, 2), b256, 0, stream>>>(
        compr, comps, confr, confs, o_seedr, o_seeds);

    // spot gathers
    spot_gather<<<dim3((NP * SPOTK) / 256, 1, 2), b256, 0, stream>>>(
        sidx16, ridx16, mir, mis, o_spotr, o_spots);
}

// Round 5
// 726.659 us; speedup vs baseline: 2.2049x; 1.1284x over previous
//
#include <hip/hip_runtime.h>
#include <math.h>

#define NP 4096      // N = M
#define NCP 512      // NC = MC
#define HD 256       // H and CF
#define CCD 1024     // CC
#define SPOTK 16
#define DOWNK 8
#define SEEDN 128

// ---------------------------------------------------------------------------
// Tiled f32 GEMM: C[M,N] = A[M,K] @ B[K,N] (+bias).  BT: B stored as [N,K]
// (i.e. C = A @ B^T).  128x128 tile, 256 threads, 8x8 microtile as 2x2
// quadrants of 4x4 (conflict-free float4 LDS reads), BK=16, LDS pad 132.
// blockIdx.z selects (A0,B0,C0) vs (A1,B1,C1) for batching two GEMMs.
// ---------------------------------------------------------------------------
template<bool BT, bool BIAS>
__global__ __launch_bounds__(256) void gemm128(
    const float* __restrict__ A0, const float* __restrict__ A1,
    const float* __restrict__ B0, const float* __restrict__ B1,
    const float* __restrict__ bias, float* __restrict__ C0, float* __restrict__ C1,
    int M, int N, int K)
{
    const float* A = blockIdx.z ? A1 : A0;
    const float* B = blockIdx.z ? B1 : B0;
    float* C = blockIdx.z ? C1 : C0;

    const int PAD = 132;                         // mult of 4 (16B-aligned rows),
    __shared__ float As[16 * 132];               // k*132 mod 32 spreads banks
    __shared__ float Bs[16 * 132];

    const int bm = blockIdx.y * 128, bn = blockIdx.x * 128;
    const int t = threadIdx.x;
    const int tx = t & 15, ty = t >> 4;

    float acc[2][2][4][4] = {};

    for (int k0 = 0; k0 < K; k0 += 16) {
        // A tile: 128 rows x 16 k, float4 loads, transposed conflict-free store
#pragma unroll
        for (int it = 0; it < 2; it++) {
            int idx = t + it * 256;
            int row = idx >> 2, kc = (idx & 3) * 4;
            float4 v = *(const float4*)&A[(size_t)(bm + row) * K + k0 + kc];
            As[(kc + 0) * PAD + row] = v.x;
            As[(kc + 1) * PAD + row] = v.y;
            As[(kc + 2) * PAD + row] = v.z;
            As[(kc + 3) * PAD + row] = v.w;
        }
        if (BT) {
#pragma unroll
            for (int it = 0; it < 2; it++) {
                int idx = t + it * 256;
                int row = idx >> 2, kc = (idx & 3) * 4;
                float4 v = *(const float4*)&B[(size_t)(bn + row) * K + k0 + kc];
                Bs[(kc + 0) * PAD + row] = v.x;
                Bs[(kc + 1) * PAD + row] = v.y;
                Bs[(kc + 2) * PAD + row] = v.z;
                Bs[(kc + 3) * PAD + row] = v.w;
            }
        } else {
#pragma unroll
            for (int it = 0; it < 2; it++) {
                int idx = t + it * 256;
                int n4 = (idx & 31) * 4, k = idx >> 5;
                float4 v = *(const float4*)&B[(size_t)(k0 + k) * N + bn + n4];
                *(float4*)&Bs[k * PAD + n4] = v;
            }
        }
        __syncthreads();
#pragma unroll
        for (int kk = 0; kk < 16; kk++) {
            float4 a0 = *(const float4*)&As[kk * PAD + ty * 4];
            float4 a1 = *(const float4*)&As[kk * PAD + ty * 4 + 64];
            float4 b0 = *(const float4*)&Bs[kk * PAD + tx * 4];
            float4 b1 = *(const float4*)&Bs[kk * PAD + tx * 4 + 64];
            float ar[2][4] = {{a0.x, a0.y, a0.z, a0.w}, {a1.x, a1.y, a1.z, a1.w}};
            float br[2][4] = {{b0.x, b0.y, b0.z, b0.w}, {b1.x, b1.y, b1.z, b1.w}};
#pragma unroll
            for (int qr = 0; qr < 2; qr++)
#pragma unroll
                for (int qc = 0; qc < 2; qc++)
#pragma unroll
                    for (int i = 0; i < 4; i++)
#pragma unroll
                        for (int j = 0; j < 4; j++)
                            acc[qr][qc][i][j] = fmaf(ar[qr][i], br[qc][j], acc[qr][qc][i][j]);
        }
        __syncthreads();
    }
#pragma unroll
    for (int qr = 0; qr < 2; qr++)
#pragma unroll
        for (int i = 0; i < 4; i++) {
            int m = bm + qr * 64 + ty * 4 + i;
#pragma unroll
            for (int qc = 0; qc < 2; qc++) {
                int n = bn + qc * 64 + tx * 4;
                float4 v = make_float4(acc[qr][qc][i][0], acc[qr][qc][i][1],
                                       acc[qr][qc][i][2], acc[qr][qc][i][3]);
                if (BIAS) {
                    float4 b4 = *(const float4*)&bias[n];
                    v.x += b4.x; v.y += b4.y; v.z += b4.z; v.w += b4.w;
                }
                *(float4*)&C[(size_t)m * N + n] = v;
            }
        }
}

// ---------------------------------------------------------------------------
// Pack points to float4(x,y,z,|p|^2): z = 0..3 -> {refN, srcN, refC, srcC}
// ---------------------------------------------------------------------------
__global__ void pack_pts(const float* __restrict__ p0, const float* __restrict__ p1,
                         const float* __restrict__ p2, const float* __restrict__ p3,
                         float4* o0, float4* o1, float4* o2, float4* o3)
{
    int z = blockIdx.z;
    const float* p = (z == 0) ? p0 : (z == 1) ? p1 : (z == 2) ? p2 : p3;
    float4* o      = (z == 0) ? o0 : (z == 1) ? o1 : (z == 2) ? o2 : o3;
    int n = (z < 2) ? NP : NCP;
    int i = blockIdx.x * 256 + threadIdx.x;
    if (i >= n) return;
    float x = p[i * 3], y = p[i * 3 + 1], zz = p[i * 3 + 2];
    o[i] = make_float4(x, y, zz, x * x + y * y + zz * zz);
}

// ---------------------------------------------------------------------------
// Row softmax stats (two-pass, matching jax.nn.softmax)
// ---------------------------------------------------------------------------
__global__ __launch_bounds__(256) void row_stats(const float* __restrict__ s,
                                                 float* rmax, float* rsum)
{
    int n = blockIdx.x;
    const float* row = s + (size_t)n * NP;
    __shared__ float red[256];
    float m = -INFINITY;
    for (int j = threadIdx.x; j < NP; j += 256) m = fmaxf(m, row[j]);
    red[threadIdx.x] = m; __syncthreads();
    for (int off = 128; off; off >>= 1) {
        if (threadIdx.x < off) red[threadIdx.x] = fmaxf(red[threadIdx.x], red[threadIdx.x + off]);
        __syncthreads();
    }
    m = red[0]; __syncthreads();
    float sum = 0.f;
    for (int j = threadIdx.x; j < NP; j += 256) sum += expf(row[j] - m);
    red[threadIdx.x] = sum; __syncthreads();
    for (int off = 128; off; off >>= 1) {
        if (threadIdx.x < off) red[threadIdx.x] += red[threadIdx.x + off];
        __syncthreads();
    }
    if (threadIdx.x == 0) { rmax[n] = m; rsum[n] = red[0]; }
}

// Column softmax stats: partial over 128-row chunks (coalesced), then combine.
__global__ __launch_bounds__(256) void col_stats_partial(const float* __restrict__ s,
                                                         float* pmax, float* psum)
{
    int m = blockIdx.x * 256 + threadIdx.x;
    int n0 = blockIdx.y * 128;
    float mx = -INFINITY;
    for (int n = n0; n < n0 + 128; n++) mx = fmaxf(mx, s[(size_t)n * NP + m]);
    float sum = 0.f;
    for (int n = n0; n < n0 + 128; n++) sum += expf(s[(size_t)n * NP + m] - mx);
    pmax[(size_t)blockIdx.y * NP + m] = mx;
    psum[(size_t)blockIdx.y * NP + m] = sum;
}

__global__ __launch_bounds__(256) void col_stats_combine(const float* __restrict__ pmax,
                                                         const float* __restrict__ psum,
                                                         float* cmax, float* csum)
{
    int m = blockIdx.x * 256 + threadIdx.x;
    float mx = -INFINITY;
    for (int c = 0; c < 32; c++) mx = fmaxf(mx, pmax[(size_t)c * NP + m]);
    float sum = 0.f;
    for (int c = 0; c < 32; c++) sum += psum[(size_t)c * NP + m] * expf(pmax[(size_t)c * NP + m] - mx);
    cmax[m] = mx; csum[m] = sum;
}

// Final scores (in place) + per-row max/argmax (first-occurrence semantics)
__global__ __launch_bounds__(256) void finalize_rows(float* __restrict__ s,
    const float* __restrict__ rmax, const float* __restrict__ rsum,
    const float* __restrict__ cmax, const float* __restrict__ csum,
    float* __restrict__ confr, int* __restrict__ mir)
{
    int n = blockIdx.x;
    float rm = rmax[n], rs = rsum[n];
    size_t base = (size_t)n * NP;
    float best = -INFINITY; int bi = 0x7fffffff;
    for (int m1 = threadIdx.x; m1 < NP; m1 += 256) {
        float v = s[base + m1];
        float a = expf(v - rm) / rs;
        float b = expf(v - cmax[m1]) / csum[m1];
        float sc = a * b;
        s[base + m1] = sc;
        if (sc > best) { best = sc; bi = m1; }   // strict > keeps first occurrence
    }
    __shared__ float rv[256]; __shared__ int ri[256];
    rv[threadIdx.x] = best; ri[threadIdx.x] = bi; __syncthreads();
    for (int off = 128; off; off >>= 1) {
        if (threadIdx.x < off) {
            float v2 = rv[threadIdx.x + off]; int i2 = ri[threadIdx.x + off];
            if (v2 > rv[threadIdx.x] || (v2 == rv[threadIdx.x] && i2 < ri[threadIdx.x])) {
                rv[threadIdx.x] = v2; ri[threadIdx.x] = i2;
            }
        }
        __syncthreads();
    }
    if (threadIdx.x == 0) { confr[n] = rv[0]; mir[n] = ri[0]; }
}

// Column max/argmax over final scores (chunked)
__global__ __launch_bounds__(256) void col_argmax_partial(const float* __restrict__ s,
                                                          float* pconf, int* pmi)
{
    int m = blockIdx.x * 256 + threadIdx.x;
    int n0 = blockIdx.y * 128;
    float best = -INFINITY; int bi = 0;
    for (int n = n0; n < n0 + 128; n++) {
        float v = s[(size_t)n * NP + m];
        if (v > best) { best = v; bi = n; }
    }
    pconf[(size_t)blockIdx.y * NP + m] = best;
    pmi[(size_t)blockIdx.y * NP + m] = bi;
}

__global__ __launch_bounds__(256) void col_argmax_combine(const float* __restrict__ pconf,
                                                          const int* __restrict__ pmi,
                                                          float* confs, int* mis)
{
    int m = blockIdx.x * 256 + threadIdx.x;
    float best = -INFINITY; int bi = 0;
    for (int c = 0; c < 32; c++) {              // ascending chunks -> first max wins
        float v = pconf[(size_t)c * NP + m];
        if (v > best) { best = v; bi = pmi[(size_t)c * NP + m]; }
    }
    confs[m] = best; mis[m] = bi;
}

// Gather matched packed points: q[j] = p4[mi[j]]  (z-batched)
__global__ void gather_pts(const float4* __restrict__ p4A, const float4* __restrict__ p4B,
                           const int* __restrict__ miA, const int* __restrict__ miB,
                           float4* __restrict__ qA, float4* __restrict__ qB)
{
    const float4* p4 = blockIdx.z ? p4B : p4A;
    const int*    mi = blockIdx.z ? miB : miA;
    float4*       q  = blockIdx.z ? qB : qA;
    int j = blockIdx.x * 256 + threadIdx.x;
    if (j >= NP) return;
    q[j] = p4[mi[j]];
}

// compat[n] = mean_j relu(1 - |d(base_n, base_j) - d(q_n, q_j)| / 3)   (z-batched)
__global__ __launch_bounds__(256) void compat_kernel(
    const float4* __restrict__ baseA, const float4* __restrict__ baseB,
    const float4* __restrict__ qA, const float4* __restrict__ qB,
    float* __restrict__ o1A, float* __restrict__ o1B,
    float* __restrict__ o2A, float* __restrict__ o2B)
{
    const float4* base = blockIdx.z ? baseB : baseA;
    const float4* q    = blockIdx.z ? qB : qA;
    float* out1        = blockIdx.z ? o1B : o1A;
    float* out2        = blockIdx.z ? o2B : o2A;
    int n = blockIdx.x;
    float4 b = base[n];
    float4 a = q[n];
    float sum = 0.f;
    for (int j = threadIdx.x; j < NP; j += 256) {
        float4 p = base[j];
        float rt = b.x * p.x + b.y * p.y + b.z * p.z;
        float rd = (b.w - 2.f * rt) + p.w;
        float4 qj = q[j];
        float st = a.x * qj.x + a.y * qj.y + a.z * qj.z;
        float sd = (a.w - 2.f * st) + qj.w;
        float c = 1.f - fabsf(rd - sd) / 3.0f;
        sum += fmaxf(c, 0.f);
    }
    __shared__ float red[256];
    red[threadIdx.x] = sum; __syncthreads();
    for (int off = 128; off; off >>= 1) {
        if (threadIdx.x < off) red[threadIdx.x] += red[threadIdx.x + off];
        __syncthreads();
    }
    if (threadIdx.x == 0) { float c = red[0] * (1.0f / NP); out1[n] = c; out2[n] = c; }
}

// ---------------------------------------------------------------------------
// Seeding via rank computation (fully parallel, no sequential rounds).
// ---------------------------------------------------------------------------
__global__ __launch_bounds__(256) void seed_rank(
    const float* __restrict__ compatA, const float* __restrict__ compatB,
    const float* __restrict__ confA, const float* __restrict__ confB,
    float* __restrict__ outA, float* __restrict__ outB)
{
    const float* compat = blockIdx.z ? compatB : compatA;
    const float* conf   = blockIdx.z ? confB : confA;
    float* outp         = blockIdx.z ? outB : outA;

    __shared__ float w[NP];
    __shared__ float red[256];
    int tid = threadIdx.x;

    float mx = -INFINITY;
    for (int j = tid; j < NP; j += 256) mx = fmaxf(mx, compat[j]);
    red[tid] = mx; __syncthreads();
    for (int off = 128; off; off >>= 1) {
        if (tid < off) red[tid] = fmaxf(red[tid], red[tid + off]);
        __syncthreads();
    }
    float thr = red[0] * 0.5f;
    __syncthreads();

    for (int j = tid; j < NP; j += 256) {
        float c = compat[j];
        w[j] = (c < thr) ? conf[j] * c : 0.0f;
    }
    __syncthreads();

    int i = blockIdx.x * 256 + tid;
    float wi = w[i];
    int rank = 0;
    const float4* w4 = (const float4*)w;
#pragma unroll 4
    for (int j4 = 0; j4 < NP / 4; j4++) {
        float4 v = w4[j4];
        int j = j4 * 4;
        rank += (v.x > wi || (v.x == wi && (j    ) < i));
        rank += (v.y > wi || (v.y == wi && (j + 1) < i));
        rank += (v.z > wi || (v.z == wi && (j + 2) < i));
        rank += (v.w > wi || (v.w == wi && (j + 3) < i));
    }
    if (rank < SEEDN) outp[rank] = (float)i;
}

// ---------------------------------------------------------------------------
// Wave-wide bitonic sorts via shfl_xor (64 lanes, zero barriers).
// ---------------------------------------------------------------------------
__device__ __forceinline__ void bitonic64_val(float& d, int lane)
{
#pragma unroll
    for (int k = 2; k <= 64; k <<= 1)
#pragma unroll
        for (int j = k >> 1; j > 0; j >>= 1) {
            float od = __shfl_xor(d, j);
            bool lower = ((lane & j) == 0);
            bool asc   = ((lane & k) == 0);
            bool take = (lower == asc) ? (od < d) : (d < od);
            d = take ? od : d;
        }
}

__device__ __forceinline__ void bitonic64_lex(float& d, int& i, int lane)
{
#pragma unroll
    for (int k = 2; k <= 64; k <<= 1)
#pragma unroll
        for (int j = k >> 1; j > 0; j >>= 1) {
            float od = __shfl_xor(d, j);
            int   oi = __shfl_xor(i, j);
            bool lower = ((lane & j) == 0);
            bool asc   = ((lane & k) == 0);
            bool less = (od < d) || (od == d && oi < i);   // other < mine
            bool gtr  = (d < od) || (d == od && i < oi);   // mine < other
            bool take = (lower == asc) ? less : gtr;
            d = take ? od : d;
            i = take ? oi : i;
        }
}

// Merge a 64-element chunk (cd,ci) into running sorted top-KSEL (run in lanes
// 0..KSEL-1, rest +inf). Only the chunk's KSEL smallest can matter.
template<int KSEL>
__device__ __forceinline__ void merge_chunk(float& run_d, int& run_i,
                                            float cd, int ci, int lane)
{
    bitonic64_lex(cd, ci, lane);
    int src = lane - KSEL;
    int s2 = (src >= 0 && src < KSEL) ? src : 0;
    float cd2 = __shfl(cd, s2);
    int   ci2 = __shfl(ci, s2);
    float nd = (lane < KSEL) ? run_d : ((lane < 2 * KSEL) ? cd2 : INFINITY);
    int   ni = (lane < KSEL) ? run_i : ((lane < 2 * KSEL) ? ci2 : 0x7fffffff);
    bitonic64_lex(nd, ni, lane);
    run_d = nd; run_i = ni;
}

// ---------------------------------------------------------------------------
// KNN top-K via threshold pre-filter (packed float4 points).
// ---------------------------------------------------------------------------
template<int KSEL>
__global__ __launch_bounds__(256) void knn_topk(
    const float4* __restrict__ rowA, const float4* __restrict__ rowB,
    const float4* __restrict__ colA, const float4* __restrict__ colB,
    int ncols,
    int* __restrict__ outiA, int* __restrict__ outiB,
    float* __restrict__ outfA, float* __restrict__ outfB)
{
    const float4* rowp = blockIdx.z ? rowB : rowA;
    const float4* colp = blockIdx.z ? colB : colA;
    int* outi = blockIdx.z ? outiB : outiA;
    float* outf = blockIdx.z ? outfB : outfA;

    int wid = threadIdx.x >> 6, lane = threadIdx.x & 63;
    int r = blockIdx.x * 4 + wid;

    float4 p = rowp[r];

    // pass 1: per-lane min distance
    float mn = INFINITY;
    for (int j0 = 0; j0 < ncols; j0 += 64) {
        float4 c = colp[j0 + lane];
        float t = p.x * c.x + p.y * c.y + p.z * c.z;
        float d = (p.w - 2.f * t) + c.w;
        mn = fminf(mn, d);
    }
    bitonic64_val(mn, lane);
    float T = __shfl(mn, KSEL - 1) + 1e-4f;      // slack >> fp recompute jitter

    // pass 2: compact survivors into LDS queue
    __shared__ float qd[4][256];
    __shared__ int   qi[4][256];
    int cnt = 0; bool ovf = false;
    for (int j0 = 0; j0 < ncols; j0 += 64) {
        int j = j0 + lane;
        float4 c = colp[j];
        float t = p.x * c.x + p.y * c.y + p.z * c.z;
        float d = (p.w - 2.f * t) + c.w;
        bool keep = (d <= T);
        unsigned long long mask = __ballot(keep);
        int nsel = __popcll(mask);
        if (cnt + nsel > 256) { ovf = true; break; }
        if (keep) {
            int pos = cnt + (int)__popcll(mask & ((1ull << lane) - 1ull));
            qd[wid][pos] = d; qi[wid][pos] = j;
        }
        cnt += nsel;
    }

    float run_d = INFINITY; int run_i = 0x7fffffff;
    if (!ovf) {
        for (int c = 0; c < cnt; c += 64) {
            int idx = c + lane;
            float cd = (idx < cnt) ? qd[wid][idx] : INFINITY;
            int   ci = (idx < cnt) ? qi[wid][idx] : 0x7fffffff;
            merge_chunk<KSEL>(run_d, run_i, cd, ci, lane);
        }
    } else {                                     // degenerate-input fallback
        for (int j0 = 0; j0 < ncols; j0 += 64) {
            int j = j0 + lane;
            float4 c = colp[j];
            float t = p.x * c.x + p.y * c.y + p.z * c.z;
            float d = (p.w - 2.f * t) + c.w;
            merge_chunk<KSEL>(run_d, run_i, d, j, lane);
        }
    }

    if (lane < KSEL) {
        if (outi) outi[(size_t)r * KSEL + lane] = run_i;
        else      outf[(size_t)r * KSEL + lane] = (float)run_i;
    }
}

// argmin over the 512 coarse points per fine point (first-min index), z-batched
__global__ __launch_bounds__(256) void up_argmin(
    const float4* __restrict__ ptsA, const float4* __restrict__ ptsB,
    const float4* __restrict__ ptscA, const float4* __restrict__ ptscB,
    float* __restrict__ outA, float* __restrict__ outB)
{
    const float4* pts   = blockIdx.z ? ptsB : ptsA;
    const float4* pts_c = blockIdx.z ? ptscB : ptscA;
    float* out_f        = blockIdx.z ? outB : outA;
    __shared__ float4 cp[NCP];
    for (int c = threadIdx.x; c < NCP; c += 256) cp[c] = pts_c[c];
    __syncthreads();
    int n = blockIdx.x * 256 + threadIdx.x;
    float4 p = pts[n];
    float best = INFINITY; int bi = 0;
    for (int c = 0; c < NCP; c++) {
        float4 q = cp[c];
        float t = p.x * q.x + p.y * q.y + p.z * q.z;
        float d = (p.w - 2.f * t) + q.w;
        if (d < best) { best = d; bi = c; }
    }
    out_f[n] = (float)bi;
}

// spot[n,k] = idx16[mi[n]][k]   (z-batched)
__global__ void spot_gather(const int* __restrict__ idxA, const int* __restrict__ idxB,
                            const int* __restrict__ miA, const int* __restrict__ miB,
                            float* __restrict__ outA, float* __restrict__ outB)
{
    const int* idx16 = blockIdx.z ? idxB : idxA;
    const int* mi    = blockIdx.z ? miB : miA;
    float* outp      = blockIdx.z ? outB : outA;
    int t = blockIdx.x * 256 + threadIdx.x;     // 65536
    int n = t >> 4, k = t & 15;
    outp[t] = (float)idx16[(size_t)mi[n] * SPOTK + k];
}

// ---------------------------------------------------------------------------
extern "C" void kernel_launch(void* const* d_in, const int* in_sizes, int n_in,
                              void* d_out, int out_size, void* d_ws, size_t ws_size,
                              hipStream_t stream)
{
    const float* ref_points   = (const float*)d_in[0];
    const float* src_points   = (const float*)d_in[1];
    const float* ref_feats    = (const float*)d_in[2];
    const float* src_feats    = (const float*)d_in[3];
    const float* ref_points_c = (const float*)d_in[4];
    const float* src_points_c = (const float*)d_in[5];
    const float* ref_feats_c  = (const float*)d_in[6];
    const float* src_feats_c  = (const float*)d_in[7];
    const float* W1 = (const float*)d_in[8];
    const float* b1 = (const float*)d_in[9];
    const float* W2 = (const float*)d_in[10];
    const float* b2 = (const float*)d_in[11];

    // ---- d_out layout (all float32; indices written as float) ----
    float* out = (float*)d_out;
    float* o_scores = out;                       // 4096*4096
    float* o_compr  = o_scores + (size_t)NP * NP;
    float* o_comps  = o_compr + NP;
    float* o_seedr  = o_comps + NP;
    float* o_seeds  = o_seedr + SEEDN;
    float* o_spotr  = o_seeds + SEEDN;           // 4096*16
    float* o_spots  = o_spotr + (size_t)NP * SPOTK;
    float* o_hcr    = o_spots + (size_t)NP * SPOTK;   // 512*256
    float* o_hcs    = o_hcr + (size_t)NCP * HD;
    float* o_rup    = o_hcs + (size_t)NCP * HD;  // 4096
    float* o_sup    = o_rup + NP;
    float* o_rdown  = o_sup + NP;                // 512*8
    float* o_sdown  = o_rdown + (size_t)NCP * DOWNK;

    // ---- workspace layout ----
    float* ws = (float*)d_ws;
    float* hfr   = ws;                           // 4096*256
    float* hfs   = hfr + (size_t)NP * HD;
    float* rmax  = hfs + (size_t)NP * HD;        // 4096 each
    float* rsum  = rmax + NP;
    float* cmax  = rsum + NP;
    float* csum  = cmax + NP;
    float* confr = csum + NP;
    float* confs = confr + NP;
    float* compr = confs + NP;
    float* comps = compr + NP;
    int*   mir   = (int*)(comps + NP);
    int*   mis   = mir + NP;
    float* pmax  = (float*)(mis + NP);           // 32*4096 each
    float* psum  = pmax + 32 * NP;
    float* pconf = psum + 32 * NP;
    int*   pmi   = (int*)(pconf + 32 * NP);
    float4* qr   = (float4*)(pmi + 32 * NP);     // 4096 float4 each
    float4* qs   = qr + NP;
    int* ridx16  = (int*)(qs + NP);              // 4096*16 each
    int* sidx16  = ridx16 + (size_t)NP * SPOTK;
    float4* rp4  = (float4*)(sidx16 + (size_t)NP * SPOTK);  // packed points
    float4* sp4  = rp4 + NP;
    float4* rcp4 = sp4 + NP;
    float4* scp4 = rcp4 + NCP;
    size_t ws_need = (size_t)((float*)(scp4 + NCP) - ws) * 4;
    if (ws_size < ws_need) return;               // insufficient scratch -> fail loudly

    dim3 b256(256);

    // packed points (used by knn / up / compat / gather)
    pack_pts<<<dim3(NP / 256, 1, 4), b256, 0, stream>>>(
        ref_points, src_points, ref_points_c, src_points_c, rp4, sp4, rcp4, scp4);

    // projections
    gemm128<false, true><<<dim3(2, 32, 2), b256, 0, stream>>>(
        ref_feats, src_feats, W2, W2, b2, hfr, hfs, NP, HD, HD);
    gemm128<false, true><<<dim3(2, 4, 2), b256, 0, stream>>>(
        ref_feats_c, src_feats_c, W1, W1, b1, o_hcr, o_hcs, NCP, HD, CCD);

    // raw scores s = hfr @ hfs^T  (into d_out scores region, finalized in place)
    gemm128<true, false><<<dim3(32, 32, 1), b256, 0, stream>>>(
        hfr, nullptr, hfs, nullptr, nullptr, o_scores, nullptr, NP, NP, HD);

    // KNN family (independent of scores)
    knn_topk<SPOTK><<<dim3(NP / 4, 1, 2), b256, 0, stream>>>(
        rp4, sp4, rp4, sp4, NP, ridx16, sidx16, nullptr, nullptr);
    knn_topk<DOWNK><<<dim3(NCP / 4, 1, 2), b256, 0, stream>>>(
        rcp4, scp4, rp4, sp4, NP, nullptr, nullptr, o_rdown, o_sdown);
    up_argmin<<<dim3(NP / 256, 1, 2), b256, 0, stream>>>(
        rp4, sp4, rcp4, scp4, o_rup, o_sup);

    // dual softmax
    row_stats<<<NP, b256, 0, stream>>>(o_scores, rmax, rsum);
    col_stats_partial<<<dim3(16, 32), b256, 0, stream>>>(o_scores, pmax, psum);
    col_stats_combine<<<16, b256, 0, stream>>>(pmax, psum, cmax, csum);
    finalize_rows<<<NP, b256, 0, stream>>>(o_scores, rmax, rsum, cmax, csum, confr, mir);
    col_argmax_partial<<<dim3(16, 32), b256, 0, stream>>>(o_scores, pconf, pmi);
    col_argmax_combine<<<16, b256, 0, stream>>>(pconf, pmi, confs, mis);

    // compatibility (recompute distances from packed points)
    gather_pts<<<dim3(NP / 256, 1, 2), b256, 0, stream>>>(
        sp4, rp4, mir, mis, qr, qs);
    compat_kernel<<<dim3(NP, 1, 2), b256, 0, stream>>>(
        rp4, sp4, qr, qs, o_compr, o_comps, compr, comps);

    // seeding (rank-based, fully parallel)
    seed_rank<<<dim3(NP / 256, 1, 2), b256, 0, stream>>>(
        compr, comps, confr, confs, o_seedr, o_seeds);

    // spot gathers
    spot_gather<<<dim3((NP * SPOTK) / 256, 1, 2), b256, 0, stream>>>(
        sidx16, ridx16, mir, mis, o_spotr, o_spots);
}

// Round 6
// 629.148 us; speedup vs baseline: 2.5466x; 1.1550x over previous
//
#include <hip/hip_runtime.h>
#include <math.h>

#define NP 4096      // N = M
#define NCP 512      // NC = MC
#define HD 256       // H and CF
#define CCD 1024     // CC
#define SPOTK 16
#define DOWNK 8
#define SEEDN 128

// ---------------------------------------------------------------------------
// Scores GEMM: C[M,N] = A[M,K] @ B[N,K]^T.  128x128 tile, 256 threads, 8x8
// microtile as 2x2 quadrants of 4x4 (conflict-free float4 LDS reads), BK=16.
// ---------------------------------------------------------------------------
__global__ __launch_bounds__(256) void gemm128_bt(
    const float* __restrict__ A, const float* __restrict__ B,
    float* __restrict__ C, int M, int N, int K)
{
    const int PAD = 132;
    __shared__ float As[16 * 132];
    __shared__ float Bs[16 * 132];

    const int bm = blockIdx.y * 128, bn = blockIdx.x * 128;
    const int t = threadIdx.x;
    const int tx = t & 15, ty = t >> 4;

    float acc[2][2][4][4] = {};

    for (int k0 = 0; k0 < K; k0 += 16) {
#pragma unroll
        for (int it = 0; it < 2; it++) {
            int idx = t + it * 256;
            int row = idx >> 2, kc = (idx & 3) * 4;
            float4 v = *(const float4*)&A[(size_t)(bm + row) * K + k0 + kc];
            As[(kc + 0) * PAD + row] = v.x;
            As[(kc + 1) * PAD + row] = v.y;
            As[(kc + 2) * PAD + row] = v.z;
            As[(kc + 3) * PAD + row] = v.w;
        }
#pragma unroll
        for (int it = 0; it < 2; it++) {
            int idx = t + it * 256;
            int row = idx >> 2, kc = (idx & 3) * 4;
            float4 v = *(const float4*)&B[(size_t)(bn + row) * K + k0 + kc];
            Bs[(kc + 0) * PAD + row] = v.x;
            Bs[(kc + 1) * PAD + row] = v.y;
            Bs[(kc + 2) * PAD + row] = v.z;
            Bs[(kc + 3) * PAD + row] = v.w;
        }
        __syncthreads();
#pragma unroll
        for (int kk = 0; kk < 16; kk++) {
            float4 a0 = *(const float4*)&As[kk * PAD + ty * 4];
            float4 a1 = *(const float4*)&As[kk * PAD + ty * 4 + 64];
            float4 b0 = *(const float4*)&Bs[kk * PAD + tx * 4];
            float4 b1 = *(const float4*)&Bs[kk * PAD + tx * 4 + 64];
            float ar[2][4] = {{a0.x, a0.y, a0.z, a0.w}, {a1.x, a1.y, a1.z, a1.w}};
            float br[2][4] = {{b0.x, b0.y, b0.z, b0.w}, {b1.x, b1.y, b1.z, b1.w}};
#pragma unroll
            for (int qr = 0; qr < 2; qr++)
#pragma unroll
                for (int qc = 0; qc < 2; qc++)
#pragma unroll
                    for (int i = 0; i < 4; i++)
#pragma unroll
                        for (int j = 0; j < 4; j++)
                            acc[qr][qc][i][j] = fmaf(ar[qr][i], br[qc][j], acc[qr][qc][i][j]);
        }
        __syncthreads();
    }
#pragma unroll
    for (int qr = 0; qr < 2; qr++)
#pragma unroll
        for (int i = 0; i < 4; i++) {
            int m = bm + qr * 64 + ty * 4 + i;
#pragma unroll
            for (int qc = 0; qc < 2; qc++) {
                int n = bn + qc * 64 + tx * 4;
                float4 v = make_float4(acc[qr][qc][i][0], acc[qr][qc][i][1],
                                       acc[qr][qc][i][2], acc[qr][qc][i][3]);
                *(float4*)&C[(size_t)m * N + n] = v;
            }
        }
}

// ---------------------------------------------------------------------------
// Projection GEMM, 64x64 tile, 256 threads, 4x4 microtile: C = A @ B (+bias).
// B is [K,N] row-major (the weight). z selects (A0,C0)/(A1,C1); B shared.
// High-parallelism variant for skinny GEMMs. Same sequential-k fma order as
// gemm128 -> bitwise-identical outputs for the same math.
// ---------------------------------------------------------------------------
__global__ __launch_bounds__(256) void gemm64(
    const float* __restrict__ A0, const float* __restrict__ A1,
    const float* __restrict__ B, const float* __restrict__ bias,
    float* __restrict__ C0, float* __restrict__ C1,
    int M, int N, int K)
{
    const float* A = blockIdx.z ? A1 : A0;
    float* C = blockIdx.z ? C1 : C0;

    const int PAD = 68;
    __shared__ float As[16 * 68];
    __shared__ float Bs[16 * 68];

    const int bm = blockIdx.y * 64, bn = blockIdx.x * 64;
    const int t = threadIdx.x;
    const int tx = t & 15, ty = t >> 4;

    float acc[4][4] = {};

    for (int k0 = 0; k0 < K; k0 += 16) {
        {
            int row = t >> 2, kc = (t & 3) * 4;
            float4 v = *(const float4*)&A[(size_t)(bm + row) * K + k0 + kc];
            As[(kc + 0) * PAD + row] = v.x;
            As[(kc + 1) * PAD + row] = v.y;
            As[(kc + 2) * PAD + row] = v.z;
            As[(kc + 3) * PAD + row] = v.w;
        }
        {
            int k = t >> 4, n4 = (t & 15) * 4;
            float4 v = *(const float4*)&B[(size_t)(k0 + k) * N + bn + n4];
            *(float4*)&Bs[k * PAD + n4] = v;
        }
        __syncthreads();
#pragma unroll
        for (int kk = 0; kk < 16; kk++) {
            float4 a4 = *(const float4*)&As[kk * PAD + ty * 4];
            float4 b4 = *(const float4*)&Bs[kk * PAD + tx * 4];
            float ar[4] = {a4.x, a4.y, a4.z, a4.w};
            float br[4] = {b4.x, b4.y, b4.z, b4.w};
#pragma unroll
            for (int i = 0; i < 4; i++)
#pragma unroll
                for (int j = 0; j < 4; j++)
                    acc[i][j] = fmaf(ar[i], br[j], acc[i][j]);
        }
        __syncthreads();
    }
    float4 b4 = *(const float4*)&bias[bn + tx * 4];
#pragma unroll
    for (int i = 0; i < 4; i++) {
        int m = bm + ty * 4 + i;
        float4 v = make_float4(acc[i][0] + b4.x, acc[i][1] + b4.y,
                               acc[i][2] + b4.z, acc[i][3] + b4.w);
        *(float4*)&C[(size_t)m * N + bn + tx * 4] = v;
    }
}

// Split-K variant: z = pair*8 + ks; each block atomicAdds a 64x64 partial
// over K-chunk KCH into C (pre-initialized with bias by init_hc).
__global__ __launch_bounds__(256) void gemm64_atomic(
    const float* __restrict__ A0, const float* __restrict__ A1,
    const float* __restrict__ B,
    float* __restrict__ C0, float* __restrict__ C1,
    int M, int N, int K, int KCH)
{
    int pair = blockIdx.z >> 3, ks = blockIdx.z & 7;
    const float* A = pair ? A1 : A0;
    float* C = pair ? C1 : C0;

    const int PAD = 68;
    __shared__ float As[16 * 68];
    __shared__ float Bs[16 * 68];

    const int bm = blockIdx.y * 64, bn = blockIdx.x * 64;
    const int t = threadIdx.x;
    const int tx = t & 15, ty = t >> 4;
    const int kbeg = ks * KCH, kend = kbeg + KCH;

    float acc[4][4] = {};

    for (int k0 = kbeg; k0 < kend; k0 += 16) {
        {
            int row = t >> 2, kc = (t & 3) * 4;
            float4 v = *(const float4*)&A[(size_t)(bm + row) * K + k0 + kc];
            As[(kc + 0) * PAD + row] = v.x;
            As[(kc + 1) * PAD + row] = v.y;
            As[(kc + 2) * PAD + row] = v.z;
            As[(kc + 3) * PAD + row] = v.w;
        }
        {
            int k = t >> 4, n4 = (t & 15) * 4;
            float4 v = *(const float4*)&B[(size_t)(k0 + k) * N + bn + n4];
            *(float4*)&Bs[k * PAD + n4] = v;
        }
        __syncthreads();
#pragma unroll
        for (int kk = 0; kk < 16; kk++) {
            float4 a4 = *(const float4*)&As[kk * PAD + ty * 4];
            float4 b4 = *(const float4*)&Bs[kk * PAD + tx * 4];
            float ar[4] = {a4.x, a4.y, a4.z, a4.w};
            float br[4] = {b4.x, b4.y, b4.z, b4.w};
#pragma unroll
            for (int i = 0; i < 4; i++)
#pragma unroll
                for (int j = 0; j < 4; j++)
                    acc[i][j] = fmaf(ar[i], br[j], acc[i][j]);
        }
        __syncthreads();
    }
#pragma unroll
    for (int i = 0; i < 4; i++) {
        int m = bm + ty * 4 + i;
#pragma unroll
        for (int j = 0; j < 4; j++)
            atomicAdd(&C[(size_t)m * N + bn + tx * 4 + j], acc[i][j]);
    }
}

// Pre-fill hc outputs with bias (atomic split-K accumulates on top).
__global__ void init_hc(const float* __restrict__ b1,
                        float* __restrict__ o_hcr, float* __restrict__ o_hcs)
{
    int idx = blockIdx.x * 256 + threadIdx.x;     // 512*256
    float b = b1[idx & (HD - 1)];
    o_hcr[idx] = b; o_hcs[idx] = b;
}

// ---------------------------------------------------------------------------
// Pack points to float4(x,y,z,|p|^2): z = 0..3 -> {refN, srcN, refC, srcC}
// ---------------------------------------------------------------------------
__global__ void pack_pts(const float* __restrict__ p0, const float* __restrict__ p1,
                         const float* __restrict__ p2, const float* __restrict__ p3,
                         float4* o0, float4* o1, float4* o2, float4* o3)
{
    int z = blockIdx.z;
    const float* p = (z == 0) ? p0 : (z == 1) ? p1 : (z == 2) ? p2 : p3;
    float4* o      = (z == 0) ? o0 : (z == 1) ? o1 : (z == 2) ? o2 : o3;
    int n = (z < 2) ? NP : NCP;
    int i = blockIdx.x * 256 + threadIdx.x;
    if (i >= n) return;
    float x = p[i * 3], y = p[i * 3 + 1], zz = p[i * 3 + 2];
    o[i] = make_float4(x, y, zz, x * x + y * y + zz * zz);
}

// ---------------------------------------------------------------------------
// Row softmax stats (two-pass, matching jax.nn.softmax)
// ---------------------------------------------------------------------------
__global__ __launch_bounds__(256) void row_stats(const float* __restrict__ s,
                                                 float* rmax, float* rsum)
{
    int n = blockIdx.x;
    const float* row = s + (size_t)n * NP;
    __shared__ float red[256];
    float m = -INFINITY;
    for (int j = threadIdx.x; j < NP; j += 256) m = fmaxf(m, row[j]);
    red[threadIdx.x] = m; __syncthreads();
    for (int off = 128; off; off >>= 1) {
        if (threadIdx.x < off) red[threadIdx.x] = fmaxf(red[threadIdx.x], red[threadIdx.x + off]);
        __syncthreads();
    }
    m = red[0]; __syncthreads();
    float sum = 0.f;
    for (int j = threadIdx.x; j < NP; j += 256) sum += expf(row[j] - m);
    red[threadIdx.x] = sum; __syncthreads();
    for (int off = 128; off; off >>= 1) {
        if (threadIdx.x < off) red[threadIdx.x] += red[threadIdx.x + off];
        __syncthreads();
    }
    if (threadIdx.x == 0) { rmax[n] = m; rsum[n] = red[0]; }
}

// Column softmax stats: partial over 128-row chunks (coalesced), then combine.
__global__ __launch_bounds__(256) void col_stats_partial(const float* __restrict__ s,
                                                         float* pmax, float* psum)
{
    int m = blockIdx.x * 256 + threadIdx.x;
    int n0 = blockIdx.y * 128;
    float mx = -INFINITY;
    for (int n = n0; n < n0 + 128; n++) mx = fmaxf(mx, s[(size_t)n * NP + m]);
    float sum = 0.f;
    for (int n = n0; n < n0 + 128; n++) sum += expf(s[(size_t)n * NP + m] - mx);
    pmax[(size_t)blockIdx.y * NP + m] = mx;
    psum[(size_t)blockIdx.y * NP + m] = sum;
}

__global__ __launch_bounds__(256) void col_stats_combine(const float* __restrict__ pmax,
                                                         const float* __restrict__ psum,
                                                         float* cmax, float* csum)
{
    int m = blockIdx.x * 256 + threadIdx.x;
    float mx = -INFINITY;
    for (int c = 0; c < 32; c++) mx = fmaxf(mx, pmax[(size_t)c * NP + m]);
    float sum = 0.f;
    for (int c = 0; c < 32; c++) sum += psum[(size_t)c * NP + m] * expf(pmax[(size_t)c * NP + m] - mx);
    cmax[m] = mx; csum[m] = sum;
}

// Final scores (in place) + per-row max/argmax (first-occurrence semantics)
__global__ __launch_bounds__(256) void finalize_rows(float* __restrict__ s,
    const float* __restrict__ rmax, const float* __restrict__ rsum,
    const float* __restrict__ cmax, const float* __restrict__ csum,
    float* __restrict__ confr, int* __restrict__ mir)
{
    int n = blockIdx.x;
    float rm = rmax[n], rs = rsum[n];
    size_t base = (size_t)n * NP;
    float best = -INFINITY; int bi = 0x7fffffff;
    for (int m1 = threadIdx.x; m1 < NP; m1 += 256) {
        float v = s[base + m1];
        float a = expf(v - rm) / rs;
        float b = expf(v - cmax[m1]) / csum[m1];
        float sc = a * b;
        s[base + m1] = sc;
        if (sc > best) { best = sc; bi = m1; }   // strict > keeps first occurrence
    }
    __shared__ float rv[256]; __shared__ int ri[256];
    rv[threadIdx.x] = best; ri[threadIdx.x] = bi; __syncthreads();
    for (int off = 128; off; off >>= 1) {
        if (threadIdx.x < off) {
            float v2 = rv[threadIdx.x + off]; int i2 = ri[threadIdx.x + off];
            if (v2 > rv[threadIdx.x] || (v2 == rv[threadIdx.x] && i2 < ri[threadIdx.x])) {
                rv[threadIdx.x] = v2; ri[threadIdx.x] = i2;
            }
        }
        __syncthreads();
    }
    if (threadIdx.x == 0) { confr[n] = rv[0]; mir[n] = ri[0]; }
}

// Column max/argmax over final scores (chunked)
__global__ __launch_bounds__(256) void col_argmax_partial(const float* __restrict__ s,
                                                          float* pconf, int* pmi)
{
    int m = blockIdx.x * 256 + threadIdx.x;
    int n0 = blockIdx.y * 128;
    float best = -INFINITY; int bi = 0;
    for (int n = n0; n < n0 + 128; n++) {
        float v = s[(size_t)n * NP + m];
        if (v > best) { best = v; bi = n; }
    }
    pconf[(size_t)blockIdx.y * NP + m] = best;
    pmi[(size_t)blockIdx.y * NP + m] = bi;
}

__global__ __launch_bounds__(256) void col_argmax_combine(const float* __restrict__ pconf,
                                                          const int* __restrict__ pmi,
                                                          float* confs, int* mis)
{
    int m = blockIdx.x * 256 + threadIdx.x;
    float best = -INFINITY; int bi = 0;
    for (int c = 0; c < 32; c++) {              // ascending chunks -> first max wins
        float v = pconf[(size_t)c * NP + m];
        if (v > best) { best = v; bi = pmi[(size_t)c * NP + m]; }
    }
    confs[m] = best; mis[m] = bi;
}

// Gather matched packed points: q[j] = p4[mi[j]]  (z-batched)
__global__ void gather_pts(const float4* __restrict__ p4A, const float4* __restrict__ p4B,
                           const int* __restrict__ miA, const int* __restrict__ miB,
                           float4* __restrict__ qA, float4* __restrict__ qB)
{
    const float4* p4 = blockIdx.z ? p4B : p4A;
    const int*    mi = blockIdx.z ? miB : miA;
    float4*       q  = blockIdx.z ? qB : qA;
    int j = blockIdx.x * 256 + threadIdx.x;
    if (j >= NP) return;
    q[j] = p4[mi[j]];
}

// compat[n] = mean_j relu(1 - |d(base_n, base_j) - d(q_n, q_j)| / 3)   (z-batched)
__global__ __launch_bounds__(256) void compat_kernel(
    const float4* __restrict__ baseA, const float4* __restrict__ baseB,
    const float4* __restrict__ qA, const float4* __restrict__ qB,
    float* __restrict__ o1A, float* __restrict__ o1B,
    float* __restrict__ o2A, float* __restrict__ o2B)
{
    const float4* base = blockIdx.z ? baseB : baseA;
    const float4* q    = blockIdx.z ? qB : qA;
    float* out1        = blockIdx.z ? o1B : o1A;
    float* out2        = blockIdx.z ? o2B : o2A;
    int n = blockIdx.x;
    float4 b = base[n];
    float4 a = q[n];
    float sum = 0.f;
    for (int j = threadIdx.x; j < NP; j += 256) {
        float4 p = base[j];
        float rt = b.x * p.x + b.y * p.y + b.z * p.z;
        float rd = (b.w - 2.f * rt) + p.w;
        float4 qj = q[j];
        float st = a.x * qj.x + a.y * qj.y + a.z * qj.z;
        float sd = (a.w - 2.f * st) + qj.w;
        float c = 1.f - fabsf(rd - sd) / 3.0f;
        sum += fmaxf(c, 0.f);
    }
    __shared__ float red[256];
    red[threadIdx.x] = sum; __syncthreads();
    for (int off = 128; off; off >>= 1) {
        if (threadIdx.x < off) red[threadIdx.x] += red[threadIdx.x + off];
        __syncthreads();
    }
    if (threadIdx.x == 0) { float c = red[0] * (1.0f / NP); out1[n] = c; out2[n] = c; }
}

// ---------------------------------------------------------------------------
// Seeding via rank computation (fully parallel, no sequential rounds).
// ---------------------------------------------------------------------------
__global__ __launch_bounds__(256) void seed_rank(
    const float* __restrict__ compatA, const float* __restrict__ compatB,
    const float* __restrict__ confA, const float* __restrict__ confB,
    float* __restrict__ outA, float* __restrict__ outB)
{
    const float* compat = blockIdx.z ? compatB : compatA;
    const float* conf   = blockIdx.z ? confB : confA;
    float* outp         = blockIdx.z ? outB : outA;

    __shared__ float w[NP];
    __shared__ float red[256];
    int tid = threadIdx.x;

    float mx = -INFINITY;
    for (int j = tid; j < NP; j += 256) mx = fmaxf(mx, compat[j]);
    red[tid] = mx; __syncthreads();
    for (int off = 128; off; off >>= 1) {
        if (tid < off) red[tid] = fmaxf(red[tid], red[tid + off]);
        __syncthreads();
    }
    float thr = red[0] * 0.5f;
    __syncthreads();

    for (int j = tid; j < NP; j += 256) {
        float c = compat[j];
        w[j] = (c < thr) ? conf[j] * c : 0.0f;
    }
    __syncthreads();

    int i = blockIdx.x * 256 + tid;
    float wi = w[i];
    int rank = 0;
    const float4* w4 = (const float4*)w;
#pragma unroll 4
    for (int j4 = 0; j4 < NP / 4; j4++) {
        float4 v = w4[j4];
        int j = j4 * 4;
        rank += (v.x > wi || (v.x == wi && (j    ) < i));
        rank += (v.y > wi || (v.y == wi && (j + 1) < i));
        rank += (v.z > wi || (v.z == wi && (j + 2) < i));
        rank += (v.w > wi || (v.w == wi && (j + 3) < i));
    }
    if (rank < SEEDN) outp[rank] = (float)i;
}

// ---------------------------------------------------------------------------
// Wave-wide bitonic sorts via shfl_xor (64 lanes, zero barriers).
// ---------------------------------------------------------------------------
__device__ __forceinline__ void bitonic64_val(float& d, int lane)
{
#pragma unroll
    for (int k = 2; k <= 64; k <<= 1)
#pragma unroll
        for (int j = k >> 1; j > 0; j >>= 1) {
            float od = __shfl_xor(d, j);
            bool lower = ((lane & j) == 0);
            bool asc   = ((lane & k) == 0);
            bool take = (lower == asc) ? (od < d) : (d < od);
            d = take ? od : d;
        }
}

__device__ __forceinline__ void bitonic64_lex(float& d, int& i, int lane)
{
#pragma unroll
    for (int k = 2; k <= 64; k <<= 1)
#pragma unroll
        for (int j = k >> 1; j > 0; j >>= 1) {
            float od = __shfl_xor(d, j);
            int   oi = __shfl_xor(i, j);
            bool lower = ((lane & j) == 0);
            bool asc   = ((lane & k) == 0);
            bool less = (od < d) || (od == d && oi < i);   // other < mine
            bool gtr  = (d < od) || (d == od && i < oi);   // mine < other
            bool take = (lower == asc) ? less : gtr;
            d = take ? od : d;
            i = take ? oi : i;
        }
}

// Merge a 64-element chunk (cd,ci) into running sorted top-KSEL (run in lanes
// 0..KSEL-1, rest +inf). Only the chunk's KSEL smallest can matter.
template<int KSEL>
__device__ __forceinline__ void merge_chunk(float& run_d, int& run_i,
                                            float cd, int ci, int lane)
{
    bitonic64_lex(cd, ci, lane);
    int src = lane - KSEL;
    int s2 = (src >= 0 && src < KSEL) ? src : 0;
    float cd2 = __shfl(cd, s2);
    int   ci2 = __shfl(ci, s2);
    float nd = (lane < KSEL) ? run_d : ((lane < 2 * KSEL) ? cd2 : INFINITY);
    int   ni = (lane < KSEL) ? run_i : ((lane < 2 * KSEL) ? ci2 : 0x7fffffff);
    bitonic64_lex(nd, ni, lane);
    run_d = nd; run_i = ni;
}

// ---------------------------------------------------------------------------
// KNN top-K via threshold pre-filter (packed float4 points).
// ---------------------------------------------------------------------------
template<int KSEL>
__global__ __launch_bounds__(256) void knn_topk(
    const float4* __restrict__ rowA, const float4* __restrict__ rowB,
    const float4* __restrict__ colA, const float4* __restrict__ colB,
    int ncols,
    int* __restrict__ outiA, int* __restrict__ outiB,
    float* __restrict__ outfA, float* __restrict__ outfB)
{
    const float4* rowp = blockIdx.z ? rowB : rowA;
    const float4* colp = blockIdx.z ? colB : colA;
    int* outi = blockIdx.z ? outiB : outiA;
    float* outf = blockIdx.z ? outfB : outfA;

    int wid = threadIdx.x >> 6, lane = threadIdx.x & 63;
    int r = blockIdx.x * 4 + wid;

    float4 p = rowp[r];

    // pass 1: per-lane min distance
    float mn = INFINITY;
    for (int j0 = 0; j0 < ncols; j0 += 64) {
        float4 c = colp[j0 + lane];
        float t = p.x * c.x + p.y * c.y + p.z * c.z;
        float d = (p.w - 2.f * t) + c.w;
        mn = fminf(mn, d);
    }
    bitonic64_val(mn, lane);
    float T = __shfl(mn, KSEL - 1) + 1e-4f;      // slack >> fp recompute jitter

    // pass 2: compact survivors into LDS queue
    __shared__ float qd[4][256];
    __shared__ int   qi[4][256];
    int cnt = 0; bool ovf = false;
    for (int j0 = 0; j0 < ncols; j0 += 64) {
        int j = j0 + lane;
        float4 c = colp[j];
        float t = p.x * c.x + p.y * c.y + p.z * c.z;
        float d = (p.w - 2.f * t) + c.w;
        bool keep = (d <= T);
        unsigned long long mask = __ballot(keep);
        int nsel = __popcll(mask);
        if (cnt + nsel > 256) { ovf = true; break; }
        if (keep) {
            int pos = cnt + (int)__popcll(mask & ((1ull << lane) - 1ull));
            qd[wid][pos] = d; qi[wid][pos] = j;
        }
        cnt += nsel;
    }

    float run_d = INFINITY; int run_i = 0x7fffffff;
    if (!ovf) {
        for (int c = 0; c < cnt; c += 64) {
            int idx = c + lane;
            float cd = (idx < cnt) ? qd[wid][idx] : INFINITY;
            int   ci = (idx < cnt) ? qi[wid][idx] : 0x7fffffff;
            merge_chunk<KSEL>(run_d, run_i, cd, ci, lane);
        }
    } else {                                     // degenerate-input fallback
        for (int j0 = 0; j0 < ncols; j0 += 64) {
            int j = j0 + lane;
            float4 c = colp[j];
            float t = p.x * c.x + p.y * c.y + p.z * c.z;
            float d = (p.w - 2.f * t) + c.w;
            merge_chunk<KSEL>(run_d, run_i, d, j, lane);
        }
    }

    if (lane < KSEL) {
        if (outi) outi[(size_t)r * KSEL + lane] = run_i;
        else      outf[(size_t)r * KSEL + lane] = (float)run_i;
    }
}

// argmin over the 512 coarse points per fine point (first-min index), z-batched
__global__ __launch_bounds__(256) void up_argmin(
    const float4* __restrict__ ptsA, const float4* __restrict__ ptsB,
    const float4* __restrict__ ptscA, const float4* __restrict__ ptscB,
    float* __restrict__ outA, float* __restrict__ outB)
{
    const float4* pts   = blockIdx.z ? ptsB : ptsA;
    const float4* pts_c = blockIdx.z ? ptscB : ptscA;
    float* out_f        = blockIdx.z ? outB : outA;
    __shared__ float4 cp[NCP];
    for (int c = threadIdx.x; c < NCP; c += 256) cp[c] = pts_c[c];
    __syncthreads();
    int n = blockIdx.x * 256 + threadIdx.x;
    float4 p = pts[n];
    float best = INFINITY; int bi = 0;
    for (int c = 0; c < NCP; c++) {
        float4 q = cp[c];
        float t = p.x * q.x + p.y * q.y + p.z * q.z;
        float d = (p.w - 2.f * t) + q.w;
        if (d < best) { best = d; bi = c; }
    }
    out_f[n] = (float)bi;
}

// spot[n,k] = idx16[mi[n]][k]   (z-batched)
__global__ void spot_gather(const int* __restrict__ idxA, const int* __restrict__ idxB,
                            const int* __restrict__ miA, const int* __restrict__ miB,
                            float* __restrict__ outA, float* __restrict__ outB)
{
    const int* idx16 = blockIdx.z ? idxB : idxA;
    const int* mi    = blockIdx.z ? miB : miA;
    float* outp      = blockIdx.z ? outB : outA;
    int t = blockIdx.x * 256 + threadIdx.x;     // 65536
    int n = t >> 4, k = t & 15;
    outp[t] = (float)idx16[(size_t)mi[n] * SPOTK + k];
}

// ---------------------------------------------------------------------------
extern "C" void kernel_launch(void* const* d_in, const int* in_sizes, int n_in,
                              void* d_out, int out_size, void* d_ws, size_t ws_size,
                              hipStream_t stream)
{
    const float* ref_points   = (const float*)d_in[0];
    const float* src_points   = (const float*)d_in[1];
    const float* ref_feats    = (const float*)d_in[2];
    const float* src_feats    = (const float*)d_in[3];
    const float* ref_points_c = (const float*)d_in[4];
    const float* src_points_c = (const float*)d_in[5];
    const float* ref_feats_c  = (const float*)d_in[6];
    const float* src_feats_c  = (const float*)d_in[7];
    const float* W1 = (const float*)d_in[8];
    const float* b1 = (const float*)d_in[9];
    const float* W2 = (const float*)d_in[10];
    const float* b2 = (const float*)d_in[11];

    // ---- d_out layout (all float32; indices written as float) ----
    float* out = (float*)d_out;
    float* o_scores = out;                       // 4096*4096
    float* o_compr  = o_scores + (size_t)NP * NP;
    float* o_comps  = o_compr + NP;
    float* o_seedr  = o_comps + NP;
    float* o_seeds  = o_seedr + SEEDN;
    float* o_spotr  = o_seeds + SEEDN;           // 4096*16
    float* o_spots  = o_spotr + (size_t)NP * SPOTK;
    float* o_hcr    = o_spots + (size_t)NP * SPOTK;   // 512*256
    float* o_hcs    = o_hcr + (size_t)NCP * HD;
    float* o_rup    = o_hcs + (size_t)NCP * HD;  // 4096
    float* o_sup    = o_rup + NP;
    float* o_rdown  = o_sup + NP;                // 512*8
    float* o_sdown  = o_rdown + (size_t)NCP * DOWNK;

    // ---- workspace layout ----
    float* ws = (float*)d_ws;
    float* hfr   = ws;                           // 4096*256
    float* hfs   = hfr + (size_t)NP * HD;
    float* rmax  = hfs + (size_t)NP * HD;        // 4096 each
    float* rsum  = rmax + NP;
    float* cmax  = rsum + NP;
    float* csum  = cmax + NP;
    float* confr = csum + NP;
    float* confs = confr + NP;
    float* compr = confs + NP;
    float* comps = compr + NP;
    int*   mir   = (int*)(comps + NP);
    int*   mis   = mir + NP;
    float* pmax  = (float*)(mis + NP);           // 32*4096 each
    float* psum  = pmax + 32 * NP;
    float* pconf = psum + 32 * NP;
    int*   pmi   = (int*)(pconf + 32 * NP);
    float4* qr   = (float4*)(pmi + 32 * NP);     // 4096 float4 each
    float4* qs   = qr + NP;
    int* ridx16  = (int*)(qs + NP);              // 4096*16 each
    int* sidx16  = ridx16 + (size_t)NP * SPOTK;
    float4* rp4  = (float4*)(sidx16 + (size_t)NP * SPOTK);  // packed points
    float4* sp4  = rp4 + NP;
    float4* rcp4 = sp4 + NP;
    float4* scp4 = rcp4 + NCP;
    size_t ws_need = (size_t)((float*)(scp4 + NCP) - ws) * 4;
    if (ws_size < ws_need) return;               // insufficient scratch -> fail loudly

    dim3 b256(256);

    // packed points (used by knn / up / compat / gather)
    pack_pts<<<dim3(NP / 256, 1, 4), b256, 0, stream>>>(
        ref_points, src_points, ref_points_c, src_points_c, rp4, sp4, rcp4, scp4);

    // coarse hc init (bias) + split-K atomic proj: 512 blocks
    init_hc<<<dim3((NCP * HD) / 256), b256, 0, stream>>>(b1, o_hcr, o_hcs);
    gemm64_atomic<<<dim3(HD / 64, NCP / 64, 16), b256, 0, stream>>>(
        ref_feats_c, src_feats_c, W1, o_hcr, o_hcs, NCP, HD, CCD, CCD / 8);

    // fine projections: 512 blocks
    gemm64<<<dim3(HD / 64, NP / 64, 2), b256, 0, stream>>>(
        ref_feats, src_feats, W2, b2, hfr, hfs, NP, HD, HD);

    // raw scores s = hfr @ hfs^T  (into d_out scores region, finalized in place)
    gemm128_bt<<<dim3(32, 32, 1), b256, 0, stream>>>(
        hfr, hfs, o_scores, NP, NP, HD);

    // KNN family (independent of scores)
    knn_topk<SPOTK><<<dim3(NP / 4, 1, 2), b256, 0, stream>>>(
        rp4, sp4, rp4, sp4, NP, ridx16, sidx16, nullptr, nullptr);
    knn_topk<DOWNK><<<dim3(NCP / 4, 1, 2), b256, 0, stream>>>(
        rcp4, scp4, rp4, sp4, NP, nullptr, nullptr, o_rdown, o_sdown);
    up_argmin<<<dim3(NP / 256, 1, 2), b256, 0, stream>>>(
        rp4, sp4, rcp4, scp4, o_rup, o_sup);

    // dual softmax
    row_stats<<<NP, b256, 0, stream>>>(o_scores, rmax, rsum);
    col_stats_partial<<<dim3(16, 32), b256, 0, stream>>>(o_scores, pmax, psum);
    col_stats_combine<<<16, b256, 0, stream>>>(pmax, psum, cmax, csum);
    finalize_rows<<<NP, b256, 0, stream>>>(o_scores, rmax, rsum, cmax, csum, confr, mir);
    col_argmax_partial<<<dim3(16, 32), b256, 0, stream>>>(o_scores, pconf, pmi);
    col_argmax_combine<<<16, b256, 0, stream>>>(pconf, pmi, confs, mis);

    // compatibility (recompute distances from packed points)
    gather_pts<<<dim3(NP / 256, 1, 2), b256, 0, stream>>>(
        sp4, rp4, mir, mis, qr, qs);
    compat_kernel<<<dim3(NP, 1, 2), b256, 0, stream>>>(
        rp4, sp4, qr, qs, o_compr, o_comps, compr, comps);

    // seeding (rank-based, fully parallel)
    seed_rank<<<dim3(NP / 256, 1, 2), b256, 0, stream>>>(
        compr, comps, confr, confs, o_seedr, o_seeds);

    // spot gathers
    spot_gather<<<dim3((NP * SPOTK) / 256, 1, 2), b256, 0, stream>>>(
        sidx16, ridx16, mir, mis, o_spotr, o_spots);
}

// Round 7
// 570.055 us; speedup vs baseline: 2.8106x; 1.1037x over previous
//
#include <hip/hip_runtime.h>
#include <math.h>

#define NP 4096      // N = M
#define NCP 512      // NC = MC
#define HD 256       // H and CF
#define CCD 1024     // CC
#define SPOTK 16
#define DOWNK 8
#define SEEDN 128
#define JCH 512      // seed rank j-chunk
#define NJC (NP / JCH)

// ---------------------------------------------------------------------------
// Scores GEMM: C[M,N] = A[M,K] @ B[N,K]^T.  128x128 tile, 256 threads, 8x8
// microtile as 2x2 quadrants of 4x4 (conflict-free float4 LDS reads), BK=16.
// ---------------------------------------------------------------------------
__global__ __launch_bounds__(256) void gemm128_bt(
    const float* __restrict__ A, const float* __restrict__ B,
    float* __restrict__ C, int M, int N, int K)
{
    const int PAD = 132;
    __shared__ float As[16 * 132];
    __shared__ float Bs[16 * 132];

    const int bm = blockIdx.y * 128, bn = blockIdx.x * 128;
    const int t = threadIdx.x;
    const int tx = t & 15, ty = t >> 4;

    float acc[2][2][4][4] = {};

    for (int k0 = 0; k0 < K; k0 += 16) {
#pragma unroll
        for (int it = 0; it < 2; it++) {
            int idx = t + it * 256;
            int row = idx >> 2, kc = (idx & 3) * 4;
            float4 v = *(const float4*)&A[(size_t)(bm + row) * K + k0 + kc];
            As[(kc + 0) * PAD + row] = v.x;
            As[(kc + 1) * PAD + row] = v.y;
            As[(kc + 2) * PAD + row] = v.z;
            As[(kc + 3) * PAD + row] = v.w;
        }
#pragma unroll
        for (int it = 0; it < 2; it++) {
            int idx = t + it * 256;
            int row = idx >> 2, kc = (idx & 3) * 4;
            float4 v = *(const float4*)&B[(size_t)(bn + row) * K + k0 + kc];
            Bs[(kc + 0) * PAD + row] = v.x;
            Bs[(kc + 1) * PAD + row] = v.y;
            Bs[(kc + 2) * PAD + row] = v.z;
            Bs[(kc + 3) * PAD + row] = v.w;
        }
        __syncthreads();
#pragma unroll
        for (int kk = 0; kk < 16; kk++) {
            float4 a0 = *(const float4*)&As[kk * PAD + ty * 4];
            float4 a1 = *(const float4*)&As[kk * PAD + ty * 4 + 64];
            float4 b0 = *(const float4*)&Bs[kk * PAD + tx * 4];
            float4 b1 = *(const float4*)&Bs[kk * PAD + tx * 4 + 64];
            float ar[2][4] = {{a0.x, a0.y, a0.z, a0.w}, {a1.x, a1.y, a1.z, a1.w}};
            float br[2][4] = {{b0.x, b0.y, b0.z, b0.w}, {b1.x, b1.y, b1.z, b1.w}};
#pragma unroll
            for (int qr = 0; qr < 2; qr++)
#pragma unroll
                for (int qc = 0; qc < 2; qc++)
#pragma unroll
                    for (int i = 0; i < 4; i++)
#pragma unroll
                        for (int j = 0; j < 4; j++)
                            acc[qr][qc][i][j] = fmaf(ar[qr][i], br[qc][j], acc[qr][qc][i][j]);
        }
        __syncthreads();
    }
#pragma unroll
    for (int qr = 0; qr < 2; qr++)
#pragma unroll
        for (int i = 0; i < 4; i++) {
            int m = bm + qr * 64 + ty * 4 + i;
#pragma unroll
            for (int qc = 0; qc < 2; qc++) {
                int n = bn + qc * 64 + tx * 4;
                float4 v = make_float4(acc[qr][qc][i][0], acc[qr][qc][i][1],
                                       acc[qr][qc][i][2], acc[qr][qc][i][3]);
                *(float4*)&C[(size_t)m * N + n] = v;
            }
        }
}

// ---------------------------------------------------------------------------
// Projection GEMM, 64x64 tile, 256 threads, 4x4 microtile: C = A @ B (+bias).
// ---------------------------------------------------------------------------
__global__ __launch_bounds__(256) void gemm64(
    const float* __restrict__ A0, const float* __restrict__ A1,
    const float* __restrict__ B, const float* __restrict__ bias,
    float* __restrict__ C0, float* __restrict__ C1,
    int M, int N, int K)
{
    const float* A = blockIdx.z ? A1 : A0;
    float* C = blockIdx.z ? C1 : C0;

    const int PAD = 68;
    __shared__ float As[16 * 68];
    __shared__ float Bs[16 * 68];

    const int bm = blockIdx.y * 64, bn = blockIdx.x * 64;
    const int t = threadIdx.x;
    const int tx = t & 15, ty = t >> 4;

    float acc[4][4] = {};

    for (int k0 = 0; k0 < K; k0 += 16) {
        {
            int row = t >> 2, kc = (t & 3) * 4;
            float4 v = *(const float4*)&A[(size_t)(bm + row) * K + k0 + kc];
            As[(kc + 0) * PAD + row] = v.x;
            As[(kc + 1) * PAD + row] = v.y;
            As[(kc + 2) * PAD + row] = v.z;
            As[(kc + 3) * PAD + row] = v.w;
        }
        {
            int k = t >> 4, n4 = (t & 15) * 4;
            float4 v = *(const float4*)&B[(size_t)(k0 + k) * N + bn + n4];
            *(float4*)&Bs[k * PAD + n4] = v;
        }
        __syncthreads();
#pragma unroll
        for (int kk = 0; kk < 16; kk++) {
            float4 a4 = *(const float4*)&As[kk * PAD + ty * 4];
            float4 b4 = *(const float4*)&Bs[kk * PAD + tx * 4];
            float ar[4] = {a4.x, a4.y, a4.z, a4.w};
            float br[4] = {b4.x, b4.y, b4.z, b4.w};
#pragma unroll
            for (int i = 0; i < 4; i++)
#pragma unroll
                for (int j = 0; j < 4; j++)
                    acc[i][j] = fmaf(ar[i], br[j], acc[i][j]);
        }
        __syncthreads();
    }
    float4 b4 = *(const float4*)&bias[bn + tx * 4];
#pragma unroll
    for (int i = 0; i < 4; i++) {
        int m = bm + ty * 4 + i;
        float4 v = make_float4(acc[i][0] + b4.x, acc[i][1] + b4.y,
                               acc[i][2] + b4.z, acc[i][3] + b4.w);
        *(float4*)&C[(size_t)m * N + bn + tx * 4] = v;
    }
}

// Split-K variant: z = pair*8 + ks; each block atomicAdds a 64x64 partial
// over K-chunk KCH into C (pre-initialized with bias by init_hc).
__global__ __launch_bounds__(256) void gemm64_atomic(
    const float* __restrict__ A0, const float* __restrict__ A1,
    const float* __restrict__ B,
    float* __restrict__ C0, float* __restrict__ C1,
    int M, int N, int K, int KCH)
{
    int pair = blockIdx.z >> 3, ks = blockIdx.z & 7;
    const float* A = pair ? A1 : A0;
    float* C = pair ? C1 : C0;

    const int PAD = 68;
    __shared__ float As[16 * 68];
    __shared__ float Bs[16 * 68];

    const int bm = blockIdx.y * 64, bn = blockIdx.x * 64;
    const int t = threadIdx.x;
    const int tx = t & 15, ty = t >> 4;
    const int kbeg = ks * KCH, kend = kbeg + KCH;

    float acc[4][4] = {};

    for (int k0 = kbeg; k0 < kend; k0 += 16) {
        {
            int row = t >> 2, kc = (t & 3) * 4;
            float4 v = *(const float4*)&A[(size_t)(bm + row) * K + k0 + kc];
            As[(kc + 0) * PAD + row] = v.x;
            As[(kc + 1) * PAD + row] = v.y;
            As[(kc + 2) * PAD + row] = v.z;
            As[(kc + 3) * PAD + row] = v.w;
        }
        {
            int k = t >> 4, n4 = (t & 15) * 4;
            float4 v = *(const float4*)&B[(size_t)(k0 + k) * N + bn + n4];
            *(float4*)&Bs[k * PAD + n4] = v;
        }
        __syncthreads();
#pragma unroll
        for (int kk = 0; kk < 16; kk++) {
            float4 a4 = *(const float4*)&As[kk * PAD + ty * 4];
            float4 b4 = *(const float4*)&Bs[kk * PAD + tx * 4];
            float ar[4] = {a4.x, a4.y, a4.z, a4.w};
            float br[4] = {b4.x, b4.y, b4.z, b4.w};
#pragma unroll
            for (int i = 0; i < 4; i++)
#pragma unroll
                for (int j = 0; j < 4; j++)
                    acc[i][j] = fmaf(ar[i], br[j], acc[i][j]);
        }
        __syncthreads();
    }
#pragma unroll
    for (int i = 0; i < 4; i++) {
        int m = bm + ty * 4 + i;
#pragma unroll
        for (int j = 0; j < 4; j++)
            atomicAdd(&C[(size_t)m * N + bn + tx * 4 + j], acc[i][j]);
    }
}

// Pre-fill hc outputs with bias (atomic split-K accumulates on top).
__global__ void init_hc(const float* __restrict__ b1,
                        float* __restrict__ o_hcr, float* __restrict__ o_hcs)
{
    int idx = blockIdx.x * 256 + threadIdx.x;     // 512*256
    float b = b1[idx & (HD - 1)];
    o_hcr[idx] = b; o_hcs[idx] = b;
}

// ---------------------------------------------------------------------------
// Pack points to float4(x,y,z,|p|^2): z = 0..3 -> {refN, srcN, refC, srcC}
// ---------------------------------------------------------------------------
__global__ void pack_pts(const float* __restrict__ p0, const float* __restrict__ p1,
                         const float* __restrict__ p2, const float* __restrict__ p3,
                         float4* o0, float4* o1, float4* o2, float4* o3)
{
    int z = blockIdx.z;
    const float* p = (z == 0) ? p0 : (z == 1) ? p1 : (z == 2) ? p2 : p3;
    float4* o      = (z == 0) ? o0 : (z == 1) ? o1 : (z == 2) ? o2 : o3;
    int n = (z < 2) ? NP : NCP;
    int i = blockIdx.x * 256 + threadIdx.x;
    if (i >= n) return;
    float x = p[i * 3], y = p[i * 3 + 1], zz = p[i * 3 + 2];
    o[i] = make_float4(x, y, zz, x * x + y * y + zz * zz);
}

// ---------------------------------------------------------------------------
// Row softmax stats (two-pass, matching jax.nn.softmax)
// ---------------------------------------------------------------------------
__global__ __launch_bounds__(256) void row_stats(const float* __restrict__ s,
                                                 float* rmax, float* rsum)
{
    int n = blockIdx.x;
    const float* row = s + (size_t)n * NP;
    __shared__ float red[256];
    float m = -INFINITY;
    for (int j = threadIdx.x; j < NP; j += 256) m = fmaxf(m, row[j]);
    red[threadIdx.x] = m; __syncthreads();
    for (int off = 128; off; off >>= 1) {
        if (threadIdx.x < off) red[threadIdx.x] = fmaxf(red[threadIdx.x], red[threadIdx.x + off]);
        __syncthreads();
    }
    m = red[0]; __syncthreads();
    float sum = 0.f;
    for (int j = threadIdx.x; j < NP; j += 256) sum += expf(row[j] - m);
    red[threadIdx.x] = sum; __syncthreads();
    for (int off = 128; off; off >>= 1) {
        if (threadIdx.x < off) red[threadIdx.x] += red[threadIdx.x + off];
        __syncthreads();
    }
    if (threadIdx.x == 0) { rmax[n] = m; rsum[n] = red[0]; }
}

// Column softmax stats: partial over 128-row chunks (coalesced), then combine.
__global__ __launch_bounds__(256) void col_stats_partial(const float* __restrict__ s,
                                                         float* pmax, float* psum)
{
    int m = blockIdx.x * 256 + threadIdx.x;
    int n0 = blockIdx.y * 128;
    float mx = -INFINITY;
    for (int n = n0; n < n0 + 128; n++) mx = fmaxf(mx, s[(size_t)n * NP + m]);
    float sum = 0.f;
    for (int n = n0; n < n0 + 128; n++) sum += expf(s[(size_t)n * NP + m] - mx);
    pmax[(size_t)blockIdx.y * NP + m] = mx;
    psum[(size_t)blockIdx.y * NP + m] = sum;
}

__global__ __launch_bounds__(256) void col_stats_combine(const float* __restrict__ pmax,
                                                         const float* __restrict__ psum,
                                                         float* cmax, float* csum)
{
    int m = blockIdx.x * 256 + threadIdx.x;
    float mx = -INFINITY;
    for (int c = 0; c < 32; c++) mx = fmaxf(mx, pmax[(size_t)c * NP + m]);
    float sum = 0.f;
    for (int c = 0; c < 32; c++) sum += psum[(size_t)c * NP + m] * expf(pmax[(size_t)c * NP + m] - mx);
    cmax[m] = mx; csum[m] = sum;
}

// Final scores (in place) + per-row max/argmax (first-occurrence semantics)
__global__ __launch_bounds__(256) void finalize_rows(float* __restrict__ s,
    const float* __restrict__ rmax, const float* __restrict__ rsum,
    const float* __restrict__ cmax, const float* __restrict__ csum,
    float* __restrict__ confr, int* __restrict__ mir)
{
    int n = blockIdx.x;
    float rm = rmax[n], rs = rsum[n];
    size_t base = (size_t)n * NP;
    float best = -INFINITY; int bi = 0x7fffffff;
    for (int m1 = threadIdx.x; m1 < NP; m1 += 256) {
        float v = s[base + m1];
        float a = expf(v - rm) / rs;
        float b = expf(v - cmax[m1]) / csum[m1];
        float sc = a * b;
        s[base + m1] = sc;
        if (sc > best) { best = sc; bi = m1; }   // strict > keeps first occurrence
    }
    __shared__ float rv[256]; __shared__ int ri[256];
    rv[threadIdx.x] = best; ri[threadIdx.x] = bi; __syncthreads();
    for (int off = 128; off; off >>= 1) {
        if (threadIdx.x < off) {
            float v2 = rv[threadIdx.x + off]; int i2 = ri[threadIdx.x + off];
            if (v2 > rv[threadIdx.x] || (v2 == rv[threadIdx.x] && i2 < ri[threadIdx.x])) {
                rv[threadIdx.x] = v2; ri[threadIdx.x] = i2;
            }
        }
        __syncthreads();
    }
    if (threadIdx.x == 0) { confr[n] = rv[0]; mir[n] = ri[0]; }
}

// Column max/argmax over final scores (chunked)
__global__ __launch_bounds__(256) void col_argmax_partial(const float* __restrict__ s,
                                                          float* pconf, int* pmi)
{
    int m = blockIdx.x * 256 + threadIdx.x;
    int n0 = blockIdx.y * 128;
    float best = -INFINITY; int bi = 0;
    for (int n = n0; n < n0 + 128; n++) {
        float v = s[(size_t)n * NP + m];
        if (v > best) { best = v; bi = n; }
    }
    pconf[(size_t)blockIdx.y * NP + m] = best;
    pmi[(size_t)blockIdx.y * NP + m] = bi;
}

__global__ __launch_bounds__(256) void col_argmax_combine(const float* __restrict__ pconf,
                                                          const int* __restrict__ pmi,
                                                          float* confs, int* mis)
{
    int m = blockIdx.x * 256 + threadIdx.x;
    float best = -INFINITY; int bi = 0;
    for (int c = 0; c < 32; c++) {              // ascending chunks -> first max wins
        float v = pconf[(size_t)c * NP + m];
        if (v > best) { best = v; bi = pmi[(size_t)c * NP + m]; }
    }
    confs[m] = best; mis[m] = bi;
}

// Gather matched packed points: q[j] = p4[mi[j]]  (z-batched)
__global__ void gather_pts(const float4* __restrict__ p4A, const float4* __restrict__ p4B,
                           const int* __restrict__ miA, const int* __restrict__ miB,
                           float4* __restrict__ qA, float4* __restrict__ qB)
{
    const float4* p4 = blockIdx.z ? p4B : p4A;
    const int*    mi = blockIdx.z ? miB : miA;
    float4*       q  = blockIdx.z ? qB : qA;
    int j = blockIdx.x * 256 + threadIdx.x;
    if (j >= NP) return;
    q[j] = p4[mi[j]];
}

// compat[n] = mean_j relu(1 - |d(base_n, base_j) - d(q_n, q_j)| / 3)   (z-batched)
__global__ __launch_bounds__(256) void compat_kernel(
    const float4* __restrict__ baseA, const float4* __restrict__ baseB,
    const float4* __restrict__ qA, const float4* __restrict__ qB,
    float* __restrict__ o1A, float* __restrict__ o1B,
    float* __restrict__ o2A, float* __restrict__ o2B)
{
    const float4* base = blockIdx.z ? baseB : baseA;
    const float4* q    = blockIdx.z ? qB : qA;
    float* out1        = blockIdx.z ? o1B : o1A;
    float* out2        = blockIdx.z ? o2B : o2A;
    int n = blockIdx.x;
    float4 b = base[n];
    float4 a = q[n];
    float sum = 0.f;
    for (int j = threadIdx.x; j < NP; j += 256) {
        float4 p = base[j];
        float rt = b.x * p.x + b.y * p.y + b.z * p.z;
        float rd = (b.w - 2.f * rt) + p.w;
        float4 qj = q[j];
        float st = a.x * qj.x + a.y * qj.y + a.z * qj.z;
        float sd = (a.w - 2.f * st) + qj.w;
        float c = 1.f - fabsf(rd - sd) / 3.0f;
        sum += fmaxf(c, 0.f);
    }
    __shared__ float red[256];
    red[threadIdx.x] = sum; __syncthreads();
    for (int off = 128; off; off >>= 1) {
        if (threadIdx.x < off) red[threadIdx.x] += red[threadIdx.x + off];
        __syncthreads();
    }
    if (threadIdx.x == 0) { float c = red[0] * (1.0f / NP); out1[n] = c; out2[n] = c; }
}

// ---------------------------------------------------------------------------
// Seeding, parallel rank pipeline.
// w[i] = (compat[i] < max(compat)*0.5) ? conf[i]*compat[i] : 0
// rank(i) = #{ j : w[j] > w[i] || (w[j]==w[i] && j<i) }  -> out[rank] = i
// Exact jax.lax.top_k order/ties.  Split over (i-chunk, j-chunk) blocks.
// ---------------------------------------------------------------------------
// 1) per side: block-reduce max, write w[] to global
__global__ __launch_bounds__(256) void seed_prep(
    const float* __restrict__ compatA, const float* __restrict__ compatB,
    const float* __restrict__ confA, const float* __restrict__ confB,
    float* __restrict__ wA, float* __restrict__ wB)
{
    const float* compat = blockIdx.z ? compatB : compatA;
    const float* conf   = blockIdx.z ? confB : confA;
    float* w            = blockIdx.z ? wB : wA;
    __shared__ float red[256];
    int tid = threadIdx.x;
    float mx = -INFINITY;
    for (int j = tid; j < NP; j += 256) mx = fmaxf(mx, compat[j]);
    red[tid] = mx; __syncthreads();
    for (int off = 128; off; off >>= 1) {
        if (tid < off) red[tid] = fmaxf(red[tid], red[tid + off]);
        __syncthreads();
    }
    float thr = red[0] * 0.5f;
    for (int j = tid; j < NP; j += 256) {
        float c = compat[j];
        w[j] = (c < thr) ? conf[j] * c : 0.0f;
    }
}

// 2) partial ranks: block = (i-chunk 256, j-chunk JCH, side)
__global__ __launch_bounds__(256) void seed_rank_partial(
    const float* __restrict__ wA, const float* __restrict__ wB,
    int* __restrict__ rankpA, int* __restrict__ rankpB)
{
    const float* w = blockIdx.z ? wB : wA;
    int* rankp     = blockIdx.z ? rankpB : rankpA;
    int tid = threadIdx.x;
    int jc = blockIdx.y;

    __shared__ float4 wj[JCH / 4];
    if (tid < JCH / 4) wj[tid] = ((const float4*)w)[jc * (JCH / 4) + tid];
    __syncthreads();

    int i = blockIdx.x * 256 + tid;
    float wi = w[i];
    int jbase = jc * JCH;
    int r0 = 0, r1 = 0, r2 = 0, r3 = 0;
#pragma unroll 4
    for (int j4 = 0; j4 < JCH / 4; j4++) {
        float4 v = wj[j4];
        int j = jbase + j4 * 4;
        r0 += (v.x > wi || (v.x == wi && (j    ) < i));
        r1 += (v.y > wi || (v.y == wi && (j + 1) < i));
        r2 += (v.z > wi || (v.z == wi && (j + 2) < i));
        r3 += (v.w > wi || (v.w == wi && (j + 3) < i));
    }
    rankp[(size_t)jc * NP + i] = (r0 + r1) + (r2 + r3);
}

// 3) scatter: rank(i) = sum of partials; rank < SEEDN -> out[rank] = i
__global__ __launch_bounds__(256) void seed_scatter(
    const int* __restrict__ rankpA, const int* __restrict__ rankpB,
    float* __restrict__ outA, float* __restrict__ outB)
{
    const int* rankp = blockIdx.z ? rankpB : rankpA;
    float* outp      = blockIdx.z ? outB : outA;
    int i = blockIdx.x * 256 + threadIdx.x;
    int r = 0;
#pragma unroll
    for (int jc = 0; jc < NJC; jc++) r += rankp[(size_t)jc * NP + i];
    if (r < SEEDN) outp[r] = (float)i;
}

// ---------------------------------------------------------------------------
// Wave-wide bitonic sorts via shfl_xor (64 lanes, zero barriers).
// ---------------------------------------------------------------------------
__device__ __forceinline__ void bitonic64_val(float& d, int lane)
{
#pragma unroll
    for (int k = 2; k <= 64; k <<= 1)
#pragma unroll
        for (int j = k >> 1; j > 0; j >>= 1) {
            float od = __shfl_xor(d, j);
            bool lower = ((lane & j) == 0);
            bool asc   = ((lane & k) == 0);
            bool take = (lower == asc) ? (od < d) : (d < od);
            d = take ? od : d;
        }
}

__device__ __forceinline__ void bitonic64_lex(float& d, int& i, int lane)
{
#pragma unroll
    for (int k = 2; k <= 64; k <<= 1)
#pragma unroll
        for (int j = k >> 1; j > 0; j >>= 1) {
            float od = __shfl_xor(d, j);
            int   oi = __shfl_xor(i, j);
            bool lower = ((lane & j) == 0);
            bool asc   = ((lane & k) == 0);
            bool less = (od < d) || (od == d && oi < i);   // other < mine
            bool gtr  = (d < od) || (d == od && i < oi);   // mine < other
            bool take = (lower == asc) ? less : gtr;
            d = take ? od : d;
            i = take ? oi : i;
        }
}

// Merge a 64-element chunk (cd,ci) into running sorted top-KSEL (run in lanes
// 0..KSEL-1, rest +inf). Only the chunk's KSEL smallest can matter.
template<int KSEL>
__device__ __forceinline__ void merge_chunk(float& run_d, int& run_i,
                                            float cd, int ci, int lane)
{
    bitonic64_lex(cd, ci, lane);
    int src = lane - KSEL;
    int s2 = (src >= 0 && src < KSEL) ? src : 0;
    float cd2 = __shfl(cd, s2);
    int   ci2 = __shfl(ci, s2);
    float nd = (lane < KSEL) ? run_d : ((lane < 2 * KSEL) ? cd2 : INFINITY);
    int   ni = (lane < KSEL) ? run_i : ((lane < 2 * KSEL) ? ci2 : 0x7fffffff);
    bitonic64_lex(nd, ni, lane);
    run_d = nd; run_i = ni;
}

// ---------------------------------------------------------------------------
// KNN top-K via threshold pre-filter (packed float4 points).
// ---------------------------------------------------------------------------
template<int KSEL>
__global__ __launch_bounds__(256) void knn_topk(
    const float4* __restrict__ rowA, const float4* __restrict__ rowB,
    const float4* __restrict__ colA, const float4* __restrict__ colB,
    int ncols,
    int* __restrict__ outiA, int* __restrict__ outiB,
    float* __restrict__ outfA, float* __restrict__ outfB)
{
    const float4* rowp = blockIdx.z ? rowB : rowA;
    const float4* colp = blockIdx.z ? colB : colA;
    int* outi = blockIdx.z ? outiB : outiA;
    float* outf = blockIdx.z ? outfB : outfA;

    int wid = threadIdx.x >> 6, lane = threadIdx.x & 63;
    int r = blockIdx.x * 4 + wid;

    float4 p = rowp[r];

    // pass 1: per-lane min distance
    float mn = INFINITY;
    for (int j0 = 0; j0 < ncols; j0 += 64) {
        float4 c = colp[j0 + lane];
        float t = p.x * c.x + p.y * c.y + p.z * c.z;
        float d = (p.w - 2.f * t) + c.w;
        mn = fminf(mn, d);
    }
    bitonic64_val(mn, lane);
    float T = __shfl(mn, KSEL - 1) + 1e-4f;      // slack >> fp recompute jitter

    // pass 2: compact survivors into LDS queue
    __shared__ float qd[4][256];
    __shared__ int   qi[4][256];
    int cnt = 0; bool ovf = false;
    for (int j0 = 0; j0 < ncols; j0 += 64) {
        int j = j0 + lane;
        float4 c = colp[j];
        float t = p.x * c.x + p.y * c.y + p.z * c.z;
        float d = (p.w - 2.f * t) + c.w;
        bool keep = (d <= T);
        unsigned long long mask = __ballot(keep);
        int nsel = __popcll(mask);
        if (cnt + nsel > 256) { ovf = true; break; }
        if (keep) {
            int pos = cnt + (int)__popcll(mask & ((1ull << lane) - 1ull));
            qd[wid][pos] = d; qi[wid][pos] = j;
        }
        cnt += nsel;
    }

    float run_d = INFINITY; int run_i = 0x7fffffff;
    if (!ovf) {
        for (int c = 0; c < cnt; c += 64) {
            int idx = c + lane;
            float cd = (idx < cnt) ? qd[wid][idx] : INFINITY;
            int   ci = (idx < cnt) ? qi[wid][idx] : 0x7fffffff;
            merge_chunk<KSEL>(run_d, run_i, cd, ci, lane);
        }
    } else {                                     // degenerate-input fallback
        for (int j0 = 0; j0 < ncols; j0 += 64) {
            int j = j0 + lane;
            float4 c = colp[j];
            float t = p.x * c.x + p.y * c.y + p.z * c.z;
            float d = (p.w - 2.f * t) + c.w;
            merge_chunk<KSEL>(run_d, run_i, d, j, lane);
        }
    }

    if (lane < KSEL) {
        if (outi) outi[(size_t)r * KSEL + lane] = run_i;
        else      outf[(size_t)r * KSEL + lane] = (float)run_i;
    }
}

// argmin over the 512 coarse points per fine point (first-min index), z-batched
__global__ __launch_bounds__(256) void up_argmin(
    const float4* __restrict__ ptsA, const float4* __restrict__ ptsB,
    const float4* __restrict__ ptscA, const float4* __restrict__ ptscB,
    float* __restrict__ outA, float* __restrict__ outB)
{
    const float4* pts   = blockIdx.z ? ptsB : ptsA;
    const float4* pts_c = blockIdx.z ? ptscB : ptscA;
    float* out_f        = blockIdx.z ? outB : outA;
    __shared__ float4 cp[NCP];
    for (int c = threadIdx.x; c < NCP; c += 256) cp[c] = pts_c[c];
    __syncthreads();
    int n = blockIdx.x * 256 + threadIdx.x;
    float4 p = pts[n];
    float best = INFINITY; int bi = 0;
    for (int c = 0; c < NCP; c++) {
        float4 q = cp[c];
        float t = p.x * q.x + p.y * q.y + p.z * q.z;
        float d = (p.w - 2.f * t) + q.w;
        if (d < best) { best = d; bi = c; }
    }
    out_f[n] = (float)bi;
}

// spot[n,k] = idx16[mi[n]][k]   (z-batched)
__global__ void spot_gather(const int* __restrict__ idxA, const int* __restrict__ idxB,
                            const int* __restrict__ miA, const int* __restrict__ miB,
                            float* __restrict__ outA, float* __restrict__ outB)
{
    const int* idx16 = blockIdx.z ? idxB : idxA;
    const int* mi    = blockIdx.z ? miB : miA;
    float* outp      = blockIdx.z ? outB : outA;
    int t = blockIdx.x * 256 + threadIdx.x;     // 65536
    int n = t >> 4, k = t & 15;
    outp[t] = (float)idx16[(size_t)mi[n] * SPOTK + k];
}

// ---------------------------------------------------------------------------
extern "C" void kernel_launch(void* const* d_in, const int* in_sizes, int n_in,
                              void* d_out, int out_size, void* d_ws, size_t ws_size,
                              hipStream_t stream)
{
    const float* ref_points   = (const float*)d_in[0];
    const float* src_points   = (const float*)d_in[1];
    const float* ref_feats    = (const float*)d_in[2];
    const float* src_feats    = (const float*)d_in[3];
    const float* ref_points_c = (const float*)d_in[4];
    const float* src_points_c = (const float*)d_in[5];
    const float* ref_feats_c  = (const float*)d_in[6];
    const float* src_feats_c  = (const float*)d_in[7];
    const float* W1 = (const float*)d_in[8];
    const float* b1 = (const float*)d_in[9];
    const float* W2 = (const float*)d_in[10];
    const float* b2 = (const float*)d_in[11];

    // ---- d_out layout (all float32; indices written as float) ----
    float* out = (float*)d_out;
    float* o_scores = out;                       // 4096*4096
    float* o_compr  = o_scores + (size_t)NP * NP;
    float* o_comps  = o_compr + NP;
    float* o_seedr  = o_comps + NP;
    float* o_seeds  = o_seedr + SEEDN;
    float* o_spotr  = o_seeds + SEEDN;           // 4096*16
    float* o_spots  = o_spotr + (size_t)NP * SPOTK;
    float* o_hcr    = o_spots + (size_t)NP * SPOTK;   // 512*256
    float* o_hcs    = o_hcr + (size_t)NCP * HD;
    float* o_rup    = o_hcs + (size_t)NCP * HD;  // 4096
    float* o_sup    = o_rup + NP;
    float* o_rdown  = o_sup + NP;                // 512*8
    float* o_sdown  = o_rdown + (size_t)NCP * DOWNK;

    // ---- workspace layout ----
    float* ws = (float*)d_ws;
    float* hfr   = ws;                           // 4096*256
    float* hfs   = hfr + (size_t)NP * HD;
    float* rmax  = hfs + (size_t)NP * HD;        // 4096 each
    float* rsum  = rmax + NP;
    float* cmax  = rsum + NP;
    float* csum  = cmax + NP;
    float* confr = csum + NP;
    float* confs = confr + NP;
    float* compr = confs + NP;
    float* comps = compr + NP;
    int*   mir   = (int*)(comps + NP);
    int*   mis   = mir + NP;
    float* pmax  = (float*)(mis + NP);           // 32*4096 each
    float* psum  = pmax + 32 * NP;
    float* pconf = psum + 32 * NP;
    int*   pmi   = (int*)(pconf + 32 * NP);
    float4* qr   = (float4*)(pmi + 32 * NP);     // 4096 float4 each
    float4* qs   = qr + NP;
    int* ridx16  = (int*)(qs + NP);              // 4096*16 each
    int* sidx16  = ridx16 + (size_t)NP * SPOTK;
    float4* rp4  = (float4*)(sidx16 + (size_t)NP * SPOTK);  // packed points
    float4* sp4  = rp4 + NP;
    float4* rcp4 = sp4 + NP;
    float4* scp4 = rcp4 + NCP;
    float* wA    = (float*)(scp4 + NCP);         // seed weights, 4096 each
    float* wB    = wA + NP;
    int* rankpA  = (int*)(wB + NP);              // NJC*4096 each
    int* rankpB  = rankpA + NJC * NP;
    size_t ws_need = (size_t)((float*)(rankpB + NJC * NP) - ws) * 4;
    if (ws_size < ws_need) return;               // insufficient scratch -> fail loudly

    dim3 b256(256);

    // packed points (used by knn / up / compat / gather)
    pack_pts<<<dim3(NP / 256, 1, 4), b256, 0, stream>>>(
        ref_points, src_points, ref_points_c, src_points_c, rp4, sp4, rcp4, scp4);

    // coarse hc init (bias) + split-K atomic proj: 512 blocks
    init_hc<<<dim3((NCP * HD) / 256), b256, 0, stream>>>(b1, o_hcr, o_hcs);
    gemm64_atomic<<<dim3(HD / 64, NCP / 64, 16), b256, 0, stream>>>(
        ref_feats_c, src_feats_c, W1, o_hcr, o_hcs, NCP, HD, CCD, CCD / 8);

    // fine projections: 512 blocks
    gemm64<<<dim3(HD / 64, NP / 64, 2), b256, 0, stream>>>(
        ref_feats, src_feats, W2, b2, hfr, hfs, NP, HD, HD);

    // raw scores s = hfr @ hfs^T  (into d_out scores region, finalized in place)
    gemm128_bt<<<dim3(32, 32, 1), b256, 0, stream>>>(
        hfr, hfs, o_scores, NP, NP, HD);

    // KNN family (independent of scores)
    knn_topk<SPOTK><<<dim3(NP / 4, 1, 2), b256, 0, stream>>>(
        rp4, sp4, rp4, sp4, NP, ridx16, sidx16, nullptr, nullptr);
    knn_topk<DOWNK><<<dim3(NCP / 4, 1, 2), b256, 0, stream>>>(
        rcp4, scp4, rp4, sp4, NP, nullptr, nullptr, o_rdown, o_sdown);
    up_argmin<<<dim3(NP / 256, 1, 2), b256, 0, stream>>>(
        rp4, sp4, rcp4, scp4, o_rup, o_sup);

    // dual softmax
    row_stats<<<NP, b256, 0, stream>>>(o_scores, rmax, rsum);
    col_stats_partial<<<dim3(16, 32), b256, 0, stream>>>(o_scores, pmax, psum);
    col_stats_combine<<<16, b256, 0, stream>>>(pmax, psum, cmax, csum);
    finalize_rows<<<NP, b256, 0, stream>>>(o_scores, rmax, rsum, cmax, csum, confr, mir);
    col_argmax_partial<<<dim3(16, 32), b256, 0, stream>>>(o_scores, pconf, pmi);
    col_argmax_combine<<<16, b256, 0, stream>>>(pconf, pmi, confs, mis);

    // compatibility (recompute distances from packed points)
    gather_pts<<<dim3(NP / 256, 1, 2), b256, 0, stream>>>(
        sp4, rp4, mir, mis, qr, qs);
    compat_kernel<<<dim3(NP, 1, 2), b256, 0, stream>>>(
        rp4, sp4, qr, qs, o_compr, o_comps, compr, comps);

    // seeding (parallel rank pipeline)
    seed_prep<<<dim3(1, 1, 2), b256, 0, stream>>>(
        compr, comps, confr, confs, wA, wB);
    seed_rank_partial<<<dim3(NP / 256, NJC, 2), b256, 0, stream>>>(
        wA, wB, rankpA, rankpB);
    seed_scatter<<<dim3(NP / 256, 1, 2), b256, 0, stream>>>(
        rankpA, rankpB, o_seedr, o_seeds);

    // spot gathers
    spot_gather<<<dim3((NP * SPOTK) / 256, 1, 2), b256, 0, stream>>>(
        sidx16, ridx16, mir, mis, o_spotr, o_spots);
}

// Round 8
// 521.468 us; speedup vs baseline: 3.0725x; 1.0932x over previous
//
#include <hip/hip_runtime.h>
#include <math.h>

#define NP 4096      // N = M
#define NCP 512      // NC = MC
#define HD 256       // H and CF
#define CCD 1024     // CC
#define SPOTK 16
#define DOWNK 8
#define SEEDN 128
#define JCH 512      // seed rank j-chunk
#define NJC (NP / JCH)

// ---------------------------------------------------------------------------
// Scores GEMM + fused softmax partial stats.
// C[M,N] = A[M,K] @ B[N,K]^T.  128x128 tile, 256 threads, 8x8 microtile as
// 2x2 quadrants of 4x4, BK=16, LDS pad 132, register-prefetch double buffer.
// Epilogue: per-tile row (max, expsum) partials -> pmaxR/psumR[32][4096]
//           per-tile col (max, expsum) partials -> pmaxC/psumC[32][4096]
// ---------------------------------------------------------------------------
__global__ __launch_bounds__(256) void gemm128_bt(
    const float* __restrict__ A, const float* __restrict__ B,
    float* __restrict__ C,
    float* __restrict__ pmaxR, float* __restrict__ psumR,
    float* __restrict__ pmaxC, float* __restrict__ psumC,
    int M, int N, int K)
{
    const int PAD = 132;
    __shared__ float As[16 * 132];
    __shared__ float Bs[16 * 132];

    const int bm = blockIdx.y * 128, bn = blockIdx.x * 128;
    const int t = threadIdx.x;
    const int tx = t & 15, ty = t >> 4;

    float acc[2][2][4][4] = {};

    const int rowA0 = t >> 2, kcA0 = (t & 3) * 4;
    const int rowA1 = (t + 256) >> 2, kcA1 = ((t + 256) & 3) * 4;

    // prologue prefetch
    float4 pa0 = *(const float4*)&A[(size_t)(bm + rowA0) * K + kcA0];
    float4 pa1 = *(const float4*)&A[(size_t)(bm + rowA1) * K + kcA1];
    float4 pb0 = *(const float4*)&B[(size_t)(bn + rowA0) * K + kcA0];
    float4 pb1 = *(const float4*)&B[(size_t)(bn + rowA1) * K + kcA1];

    for (int k0 = 0; k0 < K; k0 += 16) {
        As[(kcA0 + 0) * PAD + rowA0] = pa0.x;
        As[(kcA0 + 1) * PAD + rowA0] = pa0.y;
        As[(kcA0 + 2) * PAD + rowA0] = pa0.z;
        As[(kcA0 + 3) * PAD + rowA0] = pa0.w;
        As[(kcA1 + 0) * PAD + rowA1] = pa1.x;
        As[(kcA1 + 1) * PAD + rowA1] = pa1.y;
        As[(kcA1 + 2) * PAD + rowA1] = pa1.z;
        As[(kcA1 + 3) * PAD + rowA1] = pa1.w;
        Bs[(kcA0 + 0) * PAD + rowA0] = pb0.x;
        Bs[(kcA0 + 1) * PAD + rowA0] = pb0.y;
        Bs[(kcA0 + 2) * PAD + rowA0] = pb0.z;
        Bs[(kcA0 + 3) * PAD + rowA0] = pb0.w;
        Bs[(kcA1 + 0) * PAD + rowA1] = pb1.x;
        Bs[(kcA1 + 1) * PAD + rowA1] = pb1.y;
        Bs[(kcA1 + 2) * PAD + rowA1] = pb1.z;
        Bs[(kcA1 + 3) * PAD + rowA1] = pb1.w;
        __syncthreads();

        if (k0 + 16 < K) {                      // prefetch next tile
            int kn = k0 + 16;
            pa0 = *(const float4*)&A[(size_t)(bm + rowA0) * K + kn + kcA0];
            pa1 = *(const float4*)&A[(size_t)(bm + rowA1) * K + kn + kcA1];
            pb0 = *(const float4*)&B[(size_t)(bn + rowA0) * K + kn + kcA0];
            pb1 = *(const float4*)&B[(size_t)(bn + rowA1) * K + kn + kcA1];
        }

#pragma unroll
        for (int kk = 0; kk < 16; kk++) {
            float4 a0 = *(const float4*)&As[kk * PAD + ty * 4];
            float4 a1 = *(const float4*)&As[kk * PAD + ty * 4 + 64];
            float4 b0 = *(const float4*)&Bs[kk * PAD + tx * 4];
            float4 b1 = *(const float4*)&Bs[kk * PAD + tx * 4 + 64];
            float ar[2][4] = {{a0.x, a0.y, a0.z, a0.w}, {a1.x, a1.y, a1.z, a1.w}};
            float br[2][4] = {{b0.x, b0.y, b0.z, b0.w}, {b1.x, b1.y, b1.z, b1.w}};
#pragma unroll
            for (int qr = 0; qr < 2; qr++)
#pragma unroll
                for (int qc = 0; qc < 2; qc++)
#pragma unroll
                    for (int i = 0; i < 4; i++)
#pragma unroll
                        for (int j = 0; j < 4; j++)
                            acc[qr][qc][i][j] = fmaf(ar[qr][i], br[qc][j], acc[qr][qc][i][j]);
        }
        __syncthreads();
    }

    // C write (unchanged order -> bitwise-identical scores)
#pragma unroll
    for (int qr = 0; qr < 2; qr++)
#pragma unroll
        for (int i = 0; i < 4; i++) {
            int m = bm + qr * 64 + ty * 4 + i;
#pragma unroll
            for (int qc = 0; qc < 2; qc++) {
                int n = bn + qc * 64 + tx * 4;
                float4 v = make_float4(acc[qr][qc][i][0], acc[qr][qc][i][1],
                                       acc[qr][qc][i][2], acc[qr][qc][i][3]);
                *(float4*)&C[(size_t)m * N + n] = v;
            }
        }

    // ---- row partials: reduce over this tile's 128 cols ----
#pragma unroll
    for (int qr = 0; qr < 2; qr++)
#pragma unroll
        for (int i = 0; i < 4; i++) {
            float m = -INFINITY;
#pragma unroll
            for (int qc = 0; qc < 2; qc++)
#pragma unroll
                for (int j = 0; j < 4; j++) m = fmaxf(m, acc[qr][qc][i][j]);
            float s = 0.f;
#pragma unroll
            for (int qc = 0; qc < 2; qc++)
#pragma unroll
                for (int j = 0; j < 4; j++) s += expf(acc[qr][qc][i][j] - m);
#pragma unroll
            for (int off = 1; off < 16; off <<= 1) {      // butterfly over tx
                float om = __shfl_xor(m, off), os = __shfl_xor(s, off);
                float Mx = fmaxf(m, om);
                s = s * expf(m - Mx) + os * expf(om - Mx);
                m = Mx;
            }
            if (tx == 0) {
                int r = bm + qr * 64 + ty * 4 + i;
                pmaxR[(size_t)blockIdx.x * NP + r] = m;
                psumR[(size_t)blockIdx.x * NP + r] = s;
            }
        }

    // ---- col partials: reduce over this tile's 128 rows ----
    float* colm = As;                                     // reuse LDS (4*132*2 floats)
    float* cols_ = Bs;
#pragma unroll
    for (int qc = 0; qc < 2; qc++)
#pragma unroll
        for (int j = 0; j < 4; j++) {
            float m = -INFINITY;
#pragma unroll
            for (int qr = 0; qr < 2; qr++)
#pragma unroll
                for (int i = 0; i < 4; i++) m = fmaxf(m, acc[qr][qc][i][j]);
            float s = 0.f;
#pragma unroll
            for (int qr = 0; qr < 2; qr++)
#pragma unroll
                for (int i = 0; i < 4; i++) s += expf(acc[qr][qc][i][j] - m);
#pragma unroll
            for (int off = 16; off < 64; off <<= 1) {     // reduce ty within wave
                float om = __shfl_xor(m, off), os = __shfl_xor(s, off);
                float Mx = fmaxf(m, om);
                s = s * expf(m - Mx) + os * expf(om - Mx);
                m = Mx;
            }
            if ((ty & 3) == 0) {                          // one lane per wave-group
                int w = ty >> 2, c = qc * 64 + tx * 4 + j;
                colm[w * 132 + c] = m;
                cols_[w * 132 + c] = s;
            }
        }
    __syncthreads();
    if (t < 128) {
        int c = t;
        float m = colm[c], s = cols_[c];
#pragma unroll
        for (int w = 1; w < 4; w++) {
            float om = colm[w * 132 + c], os = cols_[w * 132 + c];
            float Mx = fmaxf(m, om);
            s = s * expf(m - Mx) + os * expf(om - Mx);
            m = Mx;
        }
        pmaxC[(size_t)blockIdx.y * NP + bn + c] = m;
        psumC[(size_t)blockIdx.y * NP + bn + c] = s;
    }
}

// Generic partial-stats combine over 32 chunks: out(max, rescaled-sum).
__global__ __launch_bounds__(256) void combine_stats(const float* __restrict__ pmax,
                                                     const float* __restrict__ psum,
                                                     float* omax, float* osum)
{
    int m = blockIdx.x * 256 + threadIdx.x;
    float mx = -INFINITY;
    for (int c = 0; c < 32; c++) mx = fmaxf(mx, pmax[(size_t)c * NP + m]);
    float sum = 0.f;
    for (int c = 0; c < 32; c++) sum += psum[(size_t)c * NP + m] * expf(pmax[(size_t)c * NP + m] - mx);
    omax[m] = mx; osum[m] = sum;
}

// ---------------------------------------------------------------------------
// Projection GEMM, 64x64 tile, 256 threads, 4x4 microtile: C = A @ B (+bias).
// ---------------------------------------------------------------------------
__global__ __launch_bounds__(256) void gemm64(
    const float* __restrict__ A0, const float* __restrict__ A1,
    const float* __restrict__ B, const float* __restrict__ bias,
    float* __restrict__ C0, float* __restrict__ C1,
    int M, int N, int K)
{
    const float* A = blockIdx.z ? A1 : A0;
    float* C = blockIdx.z ? C1 : C0;

    const int PAD = 68;
    __shared__ float As[16 * 68];
    __shared__ float Bs[16 * 68];

    const int bm = blockIdx.y * 64, bn = blockIdx.x * 64;
    const int t = threadIdx.x;
    const int tx = t & 15, ty = t >> 4;

    float acc[4][4] = {};

    for (int k0 = 0; k0 < K; k0 += 16) {
        {
            int row = t >> 2, kc = (t & 3) * 4;
            float4 v = *(const float4*)&A[(size_t)(bm + row) * K + k0 + kc];
            As[(kc + 0) * PAD + row] = v.x;
            As[(kc + 1) * PAD + row] = v.y;
            As[(kc + 2) * PAD + row] = v.z;
            As[(kc + 3) * PAD + row] = v.w;
        }
        {
            int k = t >> 4, n4 = (t & 15) * 4;
            float4 v = *(const float4*)&B[(size_t)(k0 + k) * N + bn + n4];
            *(float4*)&Bs[k * PAD + n4] = v;
        }
        __syncthreads();
#pragma unroll
        for (int kk = 0; kk < 16; kk++) {
            float4 a4 = *(const float4*)&As[kk * PAD + ty * 4];
            float4 b4 = *(const float4*)&Bs[kk * PAD + tx * 4];
            float ar[4] = {a4.x, a4.y, a4.z, a4.w};
            float br[4] = {b4.x, b4.y, b4.z, b4.w};
#pragma unroll
            for (int i = 0; i < 4; i++)
#pragma unroll
                for (int j = 0; j < 4; j++)
                    acc[i][j] = fmaf(ar[i], br[j], acc[i][j]);
        }
        __syncthreads();
    }
    float4 b4 = *(const float4*)&bias[bn + tx * 4];
#pragma unroll
    for (int i = 0; i < 4; i++) {
        int m = bm + ty * 4 + i;
        float4 v = make_float4(acc[i][0] + b4.x, acc[i][1] + b4.y,
                               acc[i][2] + b4.z, acc[i][3] + b4.w);
        *(float4*)&C[(size_t)m * N + bn + tx * 4] = v;
    }
}

// Split-K variant: z = pair*8 + ks; each block atomicAdds a 64x64 partial
// over K-chunk KCH into C (pre-initialized with bias by init_hc).
__global__ __launch_bounds__(256) void gemm64_atomic(
    const float* __restrict__ A0, const float* __restrict__ A1,
    const float* __restrict__ B,
    float* __restrict__ C0, float* __restrict__ C1,
    int M, int N, int K, int KCH)
{
    int pair = blockIdx.z >> 3, ks = blockIdx.z & 7;
    const float* A = pair ? A1 : A0;
    float* C = pair ? C1 : C0;

    const int PAD = 68;
    __shared__ float As[16 * 68];
    __shared__ float Bs[16 * 68];

    const int bm = blockIdx.y * 64, bn = blockIdx.x * 64;
    const int t = threadIdx.x;
    const int tx = t & 15, ty = t >> 4;
    const int kbeg = ks * KCH, kend = kbeg + KCH;

    float acc[4][4] = {};

    for (int k0 = kbeg; k0 < kend; k0 += 16) {
        {
            int row = t >> 2, kc = (t & 3) * 4;
            float4 v = *(const float4*)&A[(size_t)(bm + row) * K + k0 + kc];
            As[(kc + 0) * PAD + row] = v.x;
            As[(kc + 1) * PAD + row] = v.y;
            As[(kc + 2) * PAD + row] = v.z;
            As[(kc + 3) * PAD + row] = v.w;
        }
        {
            int k = t >> 4, n4 = (t & 15) * 4;
            float4 v = *(const float4*)&B[(size_t)(k0 + k) * N + bn + n4];
            *(float4*)&Bs[k * PAD + n4] = v;
        }
        __syncthreads();
#pragma unroll
        for (int kk = 0; kk < 16; kk++) {
            float4 a4 = *(const float4*)&As[kk * PAD + ty * 4];
            float4 b4 = *(const float4*)&Bs[kk * PAD + tx * 4];
            float ar[4] = {a4.x, a4.y, a4.z, a4.w};
            float br[4] = {b4.x, b4.y, b4.z, b4.w};
#pragma unroll
            for (int i = 0; i < 4; i++)
#pragma unroll
                for (int j = 0; j < 4; j++)
                    acc[i][j] = fmaf(ar[i], br[j], acc[i][j]);
        }
        __syncthreads();
    }
#pragma unroll
    for (int i = 0; i < 4; i++) {
        int m = bm + ty * 4 + i;
#pragma unroll
        for (int j = 0; j < 4; j++)
            atomicAdd(&C[(size_t)m * N + bn + tx * 4 + j], acc[i][j]);
    }
}

// Pre-fill hc outputs with bias (atomic split-K accumulates on top).
__global__ void init_hc(const float* __restrict__ b1,
                        float* __restrict__ o_hcr, float* __restrict__ o_hcs)
{
    int idx = blockIdx.x * 256 + threadIdx.x;     // 512*256
    float b = b1[idx & (HD - 1)];
    o_hcr[idx] = b; o_hcs[idx] = b;
}

// ---------------------------------------------------------------------------
// Pack points to float4(x,y,z,|p|^2): z = 0..3 -> {refN, srcN, refC, srcC}
// ---------------------------------------------------------------------------
__global__ void pack_pts(const float* __restrict__ p0, const float* __restrict__ p1,
                         const float* __restrict__ p2, const float* __restrict__ p3,
                         float4* o0, float4* o1, float4* o2, float4* o3)
{
    int z = blockIdx.z;
    const float* p = (z == 0) ? p0 : (z == 1) ? p1 : (z == 2) ? p2 : p3;
    float4* o      = (z == 0) ? o0 : (z == 1) ? o1 : (z == 2) ? o2 : o3;
    int n = (z < 2) ? NP : NCP;
    int i = blockIdx.x * 256 + threadIdx.x;
    if (i >= n) return;
    float x = p[i * 3], y = p[i * 3 + 1], zz = p[i * 3 + 2];
    o[i] = make_float4(x, y, zz, x * x + y * y + zz * zz);
}

// Final scores (in place) + per-row max/argmax (first-occurrence semantics)
__global__ __launch_bounds__(256) void finalize_rows(float* __restrict__ s,
    const float* __restrict__ rmax, const float* __restrict__ rsum,
    const float* __restrict__ cmax, const float* __restrict__ csum,
    float* __restrict__ confr, int* __restrict__ mir)
{
    int n = blockIdx.x;
    float rm = rmax[n], rs = rsum[n];
    size_t base = (size_t)n * NP;
    float best = -INFINITY; int bi = 0x7fffffff;
    for (int m1 = threadIdx.x; m1 < NP; m1 += 256) {
        float v = s[base + m1];
        float a = expf(v - rm) / rs;
        float b = expf(v - cmax[m1]) / csum[m1];
        float sc = a * b;
        s[base + m1] = sc;
        if (sc > best) { best = sc; bi = m1; }   // strict > keeps first occurrence
    }
    __shared__ float rv[256]; __shared__ int ri[256];
    rv[threadIdx.x] = best; ri[threadIdx.x] = bi; __syncthreads();
    for (int off = 128; off; off >>= 1) {
        if (threadIdx.x < off) {
            float v2 = rv[threadIdx.x + off]; int i2 = ri[threadIdx.x + off];
            if (v2 > rv[threadIdx.x] || (v2 == rv[threadIdx.x] && i2 < ri[threadIdx.x])) {
                rv[threadIdx.x] = v2; ri[threadIdx.x] = i2;
            }
        }
        __syncthreads();
    }
    if (threadIdx.x == 0) { confr[n] = rv[0]; mir[n] = ri[0]; }
}

// Column max/argmax over final scores (chunked)
__global__ __launch_bounds__(256) void col_argmax_partial(const float* __restrict__ s,
                                                          float* pconf, int* pmi)
{
    int m = blockIdx.x * 256 + threadIdx.x;
    int n0 = blockIdx.y * 128;
    float best = -INFINITY; int bi = 0;
    for (int n = n0; n < n0 + 128; n++) {
        float v = s[(size_t)n * NP + m];
        if (v > best) { best = v; bi = n; }
    }
    pconf[(size_t)blockIdx.y * NP + m] = best;
    pmi[(size_t)blockIdx.y * NP + m] = bi;
}

__global__ __launch_bounds__(256) void col_argmax_combine(const float* __restrict__ pconf,
                                                          const int* __restrict__ pmi,
                                                          float* confs, int* mis)
{
    int m = blockIdx.x * 256 + threadIdx.x;
    float best = -INFINITY; int bi = 0;
    for (int c = 0; c < 32; c++) {              // ascending chunks -> first max wins
        float v = pconf[(size_t)c * NP + m];
        if (v > best) { best = v; bi = pmi[(size_t)c * NP + m]; }
    }
    confs[m] = best; mis[m] = bi;
}

// Gather matched packed points: q[j] = p4[mi[j]]  (z-batched)
__global__ void gather_pts(const float4* __restrict__ p4A, const float4* __restrict__ p4B,
                           const int* __restrict__ miA, const int* __restrict__ miB,
                           float4* __restrict__ qA, float4* __restrict__ qB)
{
    const float4* p4 = blockIdx.z ? p4B : p4A;
    const int*    mi = blockIdx.z ? miB : miA;
    float4*       q  = blockIdx.z ? qB : qA;
    int j = blockIdx.x * 256 + threadIdx.x;
    if (j >= NP) return;
    q[j] = p4[mi[j]];
}

// compat[n] = mean_j relu(1 - |d(base_n, base_j) - d(q_n, q_j)| / 3)   (z-batched)
__global__ __launch_bounds__(256) void compat_kernel(
    const float4* __restrict__ baseA, const float4* __restrict__ baseB,
    const float4* __restrict__ qA, const float4* __restrict__ qB,
    float* __restrict__ o1A, float* __restrict__ o1B,
    float* __restrict__ o2A, float* __restrict__ o2B)
{
    const float4* base = blockIdx.z ? baseB : baseA;
    const float4* q    = blockIdx.z ? qB : qA;
    float* out1        = blockIdx.z ? o1B : o1A;
    float* out2        = blockIdx.z ? o2B : o2A;
    int n = blockIdx.x;
    float4 b = base[n];
    float4 a = q[n];
    float sum = 0.f;
    for (int j = threadIdx.x; j < NP; j += 256) {
        float4 p = base[j];
        float rt = b.x * p.x + b.y * p.y + b.z * p.z;
        float rd = (b.w - 2.f * rt) + p.w;
        float4 qj = q[j];
        float st = a.x * qj.x + a.y * qj.y + a.z * qj.z;
        float sd = (a.w - 2.f * st) + qj.w;
        float c = 1.f - fabsf(rd - sd) / 3.0f;
        sum += fmaxf(c, 0.f);
    }
    __shared__ float red[256];
    red[threadIdx.x] = sum; __syncthreads();
    for (int off = 128; off; off >>= 1) {
        if (threadIdx.x < off) red[threadIdx.x] += red[threadIdx.x + off];
        __syncthreads();
    }
    if (threadIdx.x == 0) { float c = red[0] * (1.0f / NP); out1[n] = c; out2[n] = c; }
}

// ---------------------------------------------------------------------------
// Seeding, parallel rank pipeline (exact jax.lax.top_k order/ties).
// ---------------------------------------------------------------------------
__global__ __launch_bounds__(256) void seed_prep(
    const float* __restrict__ compatA, const float* __restrict__ compatB,
    const float* __restrict__ confA, const float* __restrict__ confB,
    float* __restrict__ wA, float* __restrict__ wB)
{
    const float* compat = blockIdx.z ? compatB : compatA;
    const float* conf   = blockIdx.z ? confB : confA;
    float* w            = blockIdx.z ? wB : wA;
    __shared__ float red[256];
    int tid = threadIdx.x;
    float mx = -INFINITY;
    for (int j = tid; j < NP; j += 256) mx = fmaxf(mx, compat[j]);
    red[tid] = mx; __syncthreads();
    for (int off = 128; off; off >>= 1) {
        if (tid < off) red[tid] = fmaxf(red[tid], red[tid + off]);
        __syncthreads();
    }
    float thr = red[0] * 0.5f;
    for (int j = tid; j < NP; j += 256) {
        float c = compat[j];
        w[j] = (c < thr) ? conf[j] * c : 0.0f;
    }
}

__global__ __launch_bounds__(256) void seed_rank_partial(
    const float* __restrict__ wA, const float* __restrict__ wB,
    int* __restrict__ rankpA, int* __restrict__ rankpB)
{
    const float* w = blockIdx.z ? wB : wA;
    int* rankp     = blockIdx.z ? rankpB : rankpA;
    int tid = threadIdx.x;
    int jc = blockIdx.y;

    __shared__ float4 wj[JCH / 4];
    if (tid < JCH / 4) wj[tid] = ((const float4*)w)[jc * (JCH / 4) + tid];
    __syncthreads();

    int i = blockIdx.x * 256 + tid;
    float wi = w[i];
    int jbase = jc * JCH;
    int r0 = 0, r1 = 0, r2 = 0, r3 = 0;
#pragma unroll 4
    for (int j4 = 0; j4 < JCH / 4; j4++) {
        float4 v = wj[j4];
        int j = jbase + j4 * 4;
        r0 += (v.x > wi || (v.x == wi && (j    ) < i));
        r1 += (v.y > wi || (v.y == wi && (j + 1) < i));
        r2 += (v.z > wi || (v.z == wi && (j + 2) < i));
        r3 += (v.w > wi || (v.w == wi && (j + 3) < i));
    }
    rankp[(size_t)jc * NP + i] = (r0 + r1) + (r2 + r3);
}

__global__ __launch_bounds__(256) void seed_scatter(
    const int* __restrict__ rankpA, const int* __restrict__ rankpB,
    float* __restrict__ outA, float* __restrict__ outB)
{
    const int* rankp = blockIdx.z ? rankpB : rankpA;
    float* outp      = blockIdx.z ? outB : outA;
    int i = blockIdx.x * 256 + threadIdx.x;
    int r = 0;
#pragma unroll
    for (int jc = 0; jc < NJC; jc++) r += rankp[(size_t)jc * NP + i];
    if (r < SEEDN) outp[r] = (float)i;
}

// ---------------------------------------------------------------------------
// Wave-wide bitonic sorts via shfl_xor (64 lanes, zero barriers).
// ---------------------------------------------------------------------------
__device__ __forceinline__ void bitonic64_val(float& d, int lane)
{
#pragma unroll
    for (int k = 2; k <= 64; k <<= 1)
#pragma unroll
        for (int j = k >> 1; j > 0; j >>= 1) {
            float od = __shfl_xor(d, j);
            bool lower = ((lane & j) == 0);
            bool asc   = ((lane & k) == 0);
            bool take = (lower == asc) ? (od < d) : (d < od);
            d = take ? od : d;
        }
}

__device__ __forceinline__ void bitonic64_lex(float& d, int& i, int lane)
{
#pragma unroll
    for (int k = 2; k <= 64; k <<= 1)
#pragma unroll
        for (int j = k >> 1; j > 0; j >>= 1) {
            float od = __shfl_xor(d, j);
            int   oi = __shfl_xor(i, j);
            bool lower = ((lane & j) == 0);
            bool asc   = ((lane & k) == 0);
            bool less = (od < d) || (od == d && oi < i);   // other < mine
            bool gtr  = (d < od) || (d == od && i < oi);   // mine < other
            bool take = (lower == asc) ? less : gtr;
            d = take ? od : d;
            i = take ? oi : i;
        }
}

template<int KSEL>
__device__ __forceinline__ void merge_chunk(float& run_d, int& run_i,
                                            float cd, int ci, int lane)
{
    bitonic64_lex(cd, ci, lane);
    int src = lane - KSEL;
    int s2 = (src >= 0 && src < KSEL) ? src : 0;
    float cd2 = __shfl(cd, s2);
    int   ci2 = __shfl(ci, s2);
    float nd = (lane < KSEL) ? run_d : ((lane < 2 * KSEL) ? cd2 : INFINITY);
    int   ni = (lane < KSEL) ? run_i : ((lane < 2 * KSEL) ? ci2 : 0x7fffffff);
    bitonic64_lex(nd, ni, lane);
    run_d = nd; run_i = ni;
}

// ---------------------------------------------------------------------------
// KNN top-K via threshold pre-filter (packed float4 points).
// ---------------------------------------------------------------------------
template<int KSEL>
__global__ __launch_bounds__(256) void knn_topk(
    const float4* __restrict__ rowA, const float4* __restrict__ rowB,
    const float4* __restrict__ colA, const float4* __restrict__ colB,
    int ncols,
    int* __restrict__ outiA, int* __restrict__ outiB,
    float* __restrict__ outfA, float* __restrict__ outfB)
{
    const float4* rowp = blockIdx.z ? rowB : rowA;
    const float4* colp = blockIdx.z ? colB : colA;
    int* outi = blockIdx.z ? outiB : outiA;
    float* outf = blockIdx.z ? outfB : outfA;

    int wid = threadIdx.x >> 6, lane = threadIdx.x & 63;
    int r = blockIdx.x * 4 + wid;

    float4 p = rowp[r];

    float mn = INFINITY;
    for (int j0 = 0; j0 < ncols; j0 += 64) {
        float4 c = colp[j0 + lane];
        float t = p.x * c.x + p.y * c.y + p.z * c.z;
        float d = (p.w - 2.f * t) + c.w;
        mn = fminf(mn, d);
    }
    bitonic64_val(mn, lane);
    float T = __shfl(mn, KSEL - 1) + 1e-4f;

    __shared__ float qd[4][256];
    __shared__ int   qi[4][256];
    int cnt = 0; bool ovf = false;
    for (int j0 = 0; j0 < ncols; j0 += 64) {
        int j = j0 + lane;
        float4 c = colp[j];
        float t = p.x * c.x + p.y * c.y + p.z * c.z;
        float d = (p.w - 2.f * t) + c.w;
        bool keep = (d <= T);
        unsigned long long mask = __ballot(keep);
        int nsel = __popcll(mask);
        if (cnt + nsel > 256) { ovf = true; break; }
        if (keep) {
            int pos = cnt + (int)__popcll(mask & ((1ull << lane) - 1ull));
            qd[wid][pos] = d; qi[wid][pos] = j;
        }
        cnt += nsel;
    }

    float run_d = INFINITY; int run_i = 0x7fffffff;
    if (!ovf) {
        for (int c = 0; c < cnt; c += 64) {
            int idx = c + lane;
            float cd = (idx < cnt) ? qd[wid][idx] : INFINITY;
            int   ci = (idx < cnt) ? qi[wid][idx] : 0x7fffffff;
            merge_chunk<KSEL>(run_d, run_i, cd, ci, lane);
        }
    } else {
        for (int j0 = 0; j0 < ncols; j0 += 64) {
            int j = j0 + lane;
            float4 c = colp[j];
            float t = p.x * c.x + p.y * c.y + p.z * c.z;
            float d = (p.w - 2.f * t) + c.w;
            merge_chunk<KSEL>(run_d, run_i, d, j, lane);
        }
    }

    if (lane < KSEL) {
        if (outi) outi[(size_t)r * KSEL + lane] = run_i;
        else      outf[(size_t)r * KSEL + lane] = (float)run_i;
    }
}

// argmin over the 512 coarse points per fine point (first-min index), z-batched
__global__ __launch_bounds__(256) void up_argmin(
    const float4* __restrict__ ptsA, const float4* __restrict__ ptsB,
    const float4* __restrict__ ptscA, const float4* __restrict__ ptscB,
    float* __restrict__ outA, float* __restrict__ outB)
{
    const float4* pts   = blockIdx.z ? ptsB : ptsA;
    const float4* pts_c = blockIdx.z ? ptscB : ptscA;
    float* out_f        = blockIdx.z ? outB : outA;
    __shared__ float4 cp[NCP];
    for (int c = threadIdx.x; c < NCP; c += 256) cp[c] = pts_c[c];
    __syncthreads();
    int n = blockIdx.x * 256 + threadIdx.x;
    float4 p = pts[n];
    float best = INFINITY; int bi = 0;
    for (int c = 0; c < NCP; c++) {
        float4 q = cp[c];
        float t = p.x * q.x + p.y * q.y + p.z * q.z;
        float d = (p.w - 2.f * t) + q.w;
        if (d < best) { best = d; bi = c; }
    }
    out_f[n] = (float)bi;
}

// spot[n,k] = idx16[mi[n]][k]   (z-batched)
__global__ void spot_gather(const int* __restrict__ idxA, const int* __restrict__ idxB,
                            const int* __restrict__ miA, const int* __restrict__ miB,
                            float* __restrict__ outA, float* __restrict__ outB)
{
    const int* idx16 = blockIdx.z ? idxB : idxA;
    const int* mi    = blockIdx.z ? miB : miA;
    float* outp      = blockIdx.z ? outB : outA;
    int t = blockIdx.x * 256 + threadIdx.x;     // 65536
    int n = t >> 4, k = t & 15;
    outp[t] = (float)idx16[(size_t)mi[n] * SPOTK + k];
}

// ---------------------------------------------------------------------------
extern "C" void kernel_launch(void* const* d_in, const int* in_sizes, int n_in,
                              void* d_out, int out_size, void* d_ws, size_t ws_size,
                              hipStream_t stream)
{
    const float* ref_points   = (const float*)d_in[0];
    const float* src_points   = (const float*)d_in[1];
    const float* ref_feats    = (const float*)d_in[2];
    const float* src_feats    = (const float*)d_in[3];
    const float* ref_points_c = (const float*)d_in[4];
    const float* src_points_c = (const float*)d_in[5];
    const float* ref_feats_c  = (const float*)d_in[6];
    const float* src_feats_c  = (const float*)d_in[7];
    const float* W1 = (const float*)d_in[8];
    const float* b1 = (const float*)d_in[9];
    const float* W2 = (const float*)d_in[10];
    const float* b2 = (const float*)d_in[11];

    // ---- d_out layout (all float32; indices written as float) ----
    float* out = (float*)d_out;
    float* o_scores = out;                       // 4096*4096
    float* o_compr  = o_scores + (size_t)NP * NP;
    float* o_comps  = o_compr + NP;
    float* o_seedr  = o_comps + NP;
    float* o_seeds  = o_seedr + SEEDN;
    float* o_spotr  = o_seeds + SEEDN;           // 4096*16
    float* o_spots  = o_spotr + (size_t)NP * SPOTK;
    float* o_hcr    = o_spots + (size_t)NP * SPOTK;   // 512*256
    float* o_hcs    = o_hcr + (size_t)NCP * HD;
    float* o_rup    = o_hcs + (size_t)NCP * HD;  // 4096
    float* o_sup    = o_rup + NP;
    float* o_rdown  = o_sup + NP;                // 512*8
    float* o_sdown  = o_rdown + (size_t)NCP * DOWNK;

    // ---- workspace layout ----
    float* ws = (float*)d_ws;
    float* hfr   = ws;                           // 4096*256
    float* hfs   = hfr + (size_t)NP * HD;
    float* rmax  = hfs + (size_t)NP * HD;        // 4096 each
    float* rsum  = rmax + NP;
    float* cmax  = rsum + NP;
    float* csum  = cmax + NP;
    float* confr = csum + NP;
    float* confs = confr + NP;
    float* compr = confs + NP;
    float* comps = compr + NP;
    int*   mir   = (int*)(comps + NP);
    int*   mis   = mir + NP;
    float* pmax  = (float*)(mis + NP);           // 32*4096 each (col stats partials)
    float* psum  = pmax + 32 * NP;
    float* pconf = psum + 32 * NP;               // col argmax partials; ALSO row
    int*   pmi   = (int*)(pconf + 32 * NP);      //   stats partials (disjoint lifetime)
    float4* qr   = (float4*)(pmi + 32 * NP);     // 4096 float4 each
    float4* qs   = qr + NP;
    int* ridx16  = (int*)(qs + NP);              // 4096*16 each
    int* sidx16  = ridx16 + (size_t)NP * SPOTK;
    float4* rp4  = (float4*)(sidx16 + (size_t)NP * SPOTK);  // packed points
    float4* sp4  = rp4 + NP;
    float4* rcp4 = sp4 + NP;
    float4* scp4 = rcp4 + NCP;
    float* wA    = (float*)(scp4 + NCP);         // seed weights, 4096 each
    float* wB    = wA + NP;
    int* rankpA  = (int*)(wB + NP);              // NJC*4096 each
    int* rankpB  = rankpA + NJC * NP;
    size_t ws_need = (size_t)((float*)(rankpB + NJC * NP) - ws) * 4;
    if (ws_size < ws_need) return;               // insufficient scratch -> fail loudly

    float* pmaxR = pconf;                        // row-stats partials alias
    float* psumR = (float*)pmi;                  //   (consumed before col_argmax)

    dim3 b256(256);

    // packed points (used by knn / up / compat / gather)
    pack_pts<<<dim3(NP / 256, 1, 4), b256, 0, stream>>>(
        ref_points, src_points, ref_points_c, src_points_c, rp4, sp4, rcp4, scp4);

    // coarse hc init (bias) + split-K atomic proj: 512 blocks
    init_hc<<<dim3((NCP * HD) / 256), b256, 0, stream>>>(b1, o_hcr, o_hcs);
    gemm64_atomic<<<dim3(HD / 64, NCP / 64, 16), b256, 0, stream>>>(
        ref_feats_c, src_feats_c, W1, o_hcr, o_hcs, NCP, HD, CCD, CCD / 8);

    // fine projections: 512 blocks
    gemm64<<<dim3(HD / 64, NP / 64, 2), b256, 0, stream>>>(
        ref_feats, src_feats, W2, b2, hfr, hfs, NP, HD, HD);

    // raw scores + fused row/col softmax partials
    gemm128_bt<<<dim3(32, 32, 1), b256, 0, stream>>>(
        hfr, hfs, o_scores, pmaxR, psumR, pmax, psum, NP, NP, HD);
    combine_stats<<<16, b256, 0, stream>>>(pmaxR, psumR, rmax, rsum);
    combine_stats<<<16, b256, 0, stream>>>(pmax, psum, cmax, csum);

    // KNN family (independent of scores)
    knn_topk<SPOTK><<<dim3(NP / 4, 1, 2), b256, 0, stream>>>(
        rp4, sp4, rp4, sp4, NP, ridx16, sidx16, nullptr, nullptr);
    knn_topk<DOWNK><<<dim3(NCP / 4, 1, 2), b256, 0, stream>>>(
        rcp4, scp4, rp4, sp4, NP, nullptr, nullptr, o_rdown, o_sdown);
    up_argmin<<<dim3(NP / 256, 1, 2), b256, 0, stream>>>(
        rp4, sp4, rcp4, scp4, o_rup, o_sup);

    // dual softmax finalize + argmaxes
    finalize_rows<<<NP, b256, 0, stream>>>(o_scores, rmax, rsum, cmax, csum, confr, mir);
    col_argmax_partial<<<dim3(16, 32), b256, 0, stream>>>(o_scores, pconf, pmi);
    col_argmax_combine<<<16, b256, 0, stream>>>(pconf, pmi, confs, mis);

    // compatibility (recompute distances from packed points)
    gather_pts<<<dim3(NP / 256, 1, 2), b256, 0, stream>>>(
        sp4, rp4, mir, mis, qr, qs);
    compat_kernel<<<dim3(NP, 1, 2), b256, 0, stream>>>(
        rp4, sp4, qr, qs, o_compr, o_comps, compr, comps);

    // seeding (parallel rank pipeline)
    seed_prep<<<dim3(1, 1, 2), b256, 0, stream>>>(
        compr, comps, confr, confs, wA, wB);
    seed_rank_partial<<<dim3(NP / 256, NJC, 2), b256, 0, stream>>>(
        wA, wB, rankpA, rankpB);
    seed_scatter<<<dim3(NP / 256, 1, 2), b256, 0, stream>>>(
        rankpA, rankpB, o_seedr, o_seeds);

    // spot gathers
    spot_gather<<<dim3((NP * SPOTK) / 256, 1, 2), b256, 0, stream>>>(
        sidx16, ridx16, mir, mis, o_spotr, o_spots);
}